// Round 5
// baseline (1747.947 us; speedup 1.0000x reference)
//
#include <hip/hip_runtime.h>
#include <float.h>
#include <math.h>

#define NB 4            // graphs per batch
#define N0 40962        // nodes per graph at input
#define E0 983088       // total directed edges (fixed across layers; dead edges have w=0)
#define PCHUNKS 40      // stage-1 pooling blocks per graph

// ---------------- helpers ----------------

static __device__ __forceinline__ unsigned long long key64_of(float s, int li) {
    unsigned u = __float_as_uint(s);
    u = (u & 0x80000000u) ? ~u : (u | 0x80000000u);
    unsigned low = ~(unsigned)li;
    return ((unsigned long long)u << 32) | (unsigned long long)low;
}

// ---------------- kernels ----------------

__global__ void k_edges_init(const int* __restrict__ ei, int* __restrict__ esrc,
                             int* __restrict__ edst, float* __restrict__ ew) {
    int e = blockIdx.x * blockDim.x + threadIdx.x;
    if (e >= E0) return;
    esrc[e] = ei[e];
    edst[e] = ei[E0 + e];
    ew[e] = 1.0f;
}

__global__ void k_zero_int(int* __restrict__ a, int n) {
    int i = blockIdx.x * blockDim.x + threadIdx.x;
    if (i < n) a[i] = 0;
}

// count live in-edges per dst node
__global__ void k_deg_count(const int* __restrict__ edst, const float* __restrict__ ew,
                            int* __restrict__ degi) {
    int e = blockIdx.x * blockDim.x + threadIdx.x;
    if (e >= E0) return;
    if (ew[e] != 0.f) atomicAdd(&degi[edst[e]], 1);
}

// exclusive scan, stage 1: 1024 elements per block (256 threads x 4)
__global__ void k_scan1(const int* __restrict__ in, int* __restrict__ out,
                        int* __restrict__ bsum, int M) {
    __shared__ int s[256];
    int t = threadIdx.x;
    int base = blockIdx.x * 1024 + t * 4;
    int d0 = (base + 0 < M) ? in[base + 0] : 0;
    int d1 = (base + 1 < M) ? in[base + 1] : 0;
    int d2 = (base + 2 < M) ? in[base + 2] : 0;
    int d3 = (base + 3 < M) ? in[base + 3] : 0;
    int tsum = d0 + d1 + d2 + d3;
    s[t] = tsum;
    __syncthreads();
    for (int off = 1; off < 256; off <<= 1) {
        int v = (t >= off) ? s[t - off] : 0;
        __syncthreads();
        s[t] += v;
        __syncthreads();
    }
    int texcl = s[t] - tsum;
    if (base + 0 < M) out[base + 0] = texcl;
    if (base + 1 < M) out[base + 1] = texcl + d0;
    if (base + 2 < M) out[base + 2] = texcl + d0 + d1;
    if (base + 3 < M) out[base + 3] = texcl + d0 + d1 + d2;
    if (t == 255) bsum[blockIdx.x] = s[255];
}

// stage 2: single block exclusive scan of block sums (nb <= 256); bsum[nb] = total
__global__ void k_scan2(int* __restrict__ bsum, int nb) {
    __shared__ int s[256];
    int t = threadIdx.x;
    int v = (t < nb) ? bsum[t] : 0;
    s[t] = v;
    __syncthreads();
    for (int off = 1; off < 256; off <<= 1) {
        int u = (t >= off) ? s[t - off] : 0;
        __syncthreads();
        s[t] += u;
        __syncthreads();
    }
    if (t < nb) bsum[t] = s[t] - v;
    if (t == 255) bsum[nb] = s[255];
}

// stage 3: add block offsets; init cursor; write rowptr[M]
__global__ void k_scan3(int* __restrict__ rowptr, const int* __restrict__ bsum,
                        int* __restrict__ cursor, int M, int nb) {
    int i = blockIdx.x * 256 + threadIdx.x;
    if (i < M) {
        int v = rowptr[i] + bsum[i >> 10];
        rowptr[i] = v;
        cursor[i] = v;
    }
    if (i == 0) rowptr[M] = bsum[nb];
}

// dinv[m] = rsqrt(in_deg + 1)
__global__ void k_dinv(const int* __restrict__ rowptr, float* __restrict__ dinv, int M) {
    int m = blockIdx.x * blockDim.x + threadIdx.x;
    if (m >= M) return;
    dinv[m] = rsqrtf((float)(rowptr[m + 1] - rowptr[m]) + 1.0f);
}

// place live edges into CSR buckets (arbitrary order within bucket)
__global__ void k_csr_fill(const int* __restrict__ esrc, const int* __restrict__ edst,
                           const float* __restrict__ ew, int* __restrict__ cursor,
                           int* __restrict__ col) {
    int e = blockIdx.x * blockDim.x + threadIdx.x;
    if (e >= E0) return;
    if (ew[e] != 0.f) {
        int d = edst[e];
        int pos = atomicAdd(&cursor[d], 1);
        col[pos] = esrc[e];
    }
}

// aggregate input features (FI=4): one row per thread, float4 loads.
// ax[d] = sum_in x[s]*dinv_s*dinv_d + x[d]/deg_d
__global__ void k_gather_x4(const float* __restrict__ x, const int* __restrict__ rowptr,
                            const int* __restrict__ col, const float* __restrict__ dinv,
                            float* __restrict__ ax, int M) {
    int row = blockIdx.x * blockDim.x + threadIdx.x;
    if (row >= M) return;
    int rp0 = rowptr[row], rp1 = rowptr[row + 1];
    float dd = dinv[row];
    float invdeg = dd * dd;
    float4 xs = ((const float4*)x)[row];
    float4 acc;
    acc.x = xs.x * invdeg; acc.y = xs.y * invdeg;
    acc.z = xs.z * invdeg; acc.w = xs.w * invdeg;
    for (int j = rp0; j < rp1; ++j) {
        int s = col[j];
        float nrm = dd * dinv[s];
        float4 v = ((const float4*)x)[s];
        acc.x = fmaf(v.x, nrm, acc.x);
        acc.y = fmaf(v.y, nrm, acc.y);
        acc.z = fmaf(v.z, nrm, acc.z);
        acc.w = fmaf(v.w, nrm, acc.w);
    }
    ((float4*)ax)[row] = acc;
}

// aggregate input features (FI = 32/64/128): sub-wave per row, coalesced feature reads
template <int FI>
__global__ void k_gather_x(const float* __restrict__ x, const int* __restrict__ rowptr,
                           const int* __restrict__ col, const float* __restrict__ dinv,
                           float* __restrict__ ax, int M) {
    constexpr int LPR = (FI < 64) ? FI : 64;   // lanes per row
    constexpr int VPL = FI / LPR;              // floats per lane (1 or 2)
    constexpr int RPW = 64 / LPR;              // rows per wave
    int wave = (blockIdx.x * blockDim.x + threadIdx.x) >> 6;
    int lane = threadIdx.x & 63;
    int sub = lane / LPR;
    int f = lane % LPR;
    int row = wave * RPW + sub;
    if (row >= M) return;
    int rp0 = rowptr[row], rp1 = rowptr[row + 1];
    float dd = dinv[row];
    float invdeg = dd * dd;
    float acc[VPL];
#pragma unroll
    for (int v = 0; v < VPL; ++v)
        acc[v] = x[(size_t)row * FI + f * VPL + v] * invdeg;
    for (int j = rp0; j < rp1; ++j) {
        int s = col[j];
        float nrm = dd * dinv[s];
#pragma unroll
        for (int v = 0; v < VPL; ++v)
            acc[v] = fmaf(x[(size_t)s * FI + f * VPL + v], nrm, acc[v]);
    }
#pragma unroll
    for (int v = 0; v < VPL; ++v)
        ax[(size_t)row * FI + f * VPL + v] = acc[v];
}

// fused dense layer: y = relu(ax @ W + bias); score = dot(y, p)/|p|
// W staged in LDS; thread = 2 rows x 4 cols; QN = FO/4 threads per row-pair.
template <int FI, int FO>
__global__ void k_mm(const float* __restrict__ ax, const float* __restrict__ W,
                     const float* __restrict__ bias, const float* __restrict__ pvec,
                     float* __restrict__ y, float* __restrict__ score, int M) {
    constexpr int QN = FO / 4;           // 8 / 16 / 32
    constexpr int RPB = 2 * (256 / QN);  // rows per block: 64 / 32 / 16
    __shared__ float Ws[FI * FO];
    for (int i = threadIdx.x; i < FI * FO / 4; i += 256)
        ((float4*)Ws)[i] = ((const float4*)W)[i];
    __syncthreads();
    int q = threadIdx.x % QN;
    int r = threadIdx.x / QN;
    int row0 = blockIdx.x * RPB + 2 * r;
    int row1 = row0 + 1;
    bool v0 = row0 < M, v1 = row1 < M;
    float4 acc0 = {0.f, 0.f, 0.f, 0.f}, acc1 = {0.f, 0.f, 0.f, 0.f};
    const float4* ax40 = (const float4*)(ax + (size_t)row0 * FI);
    const float4* ax41 = (const float4*)(ax + (size_t)row1 * FI);
#pragma unroll
    for (int c = 0; c < FI / 4; ++c) {
        float4 x0 = v0 ? ax40[c] : float4{0.f, 0.f, 0.f, 0.f};
        float4 x1 = v1 ? ax41[c] : float4{0.f, 0.f, 0.f, 0.f};
        float xs0[4] = {x0.x, x0.y, x0.z, x0.w};
        float xs1[4] = {x1.x, x1.y, x1.z, x1.w};
#pragma unroll
        for (int j = 0; j < 4; ++j) {
            float4 w4 = ((const float4*)Ws)[(c * 4 + j) * QN + q];
            acc0.x = fmaf(xs0[j], w4.x, acc0.x);
            acc0.y = fmaf(xs0[j], w4.y, acc0.y);
            acc0.z = fmaf(xs0[j], w4.z, acc0.z);
            acc0.w = fmaf(xs0[j], w4.w, acc0.w);
            acc1.x = fmaf(xs1[j], w4.x, acc1.x);
            acc1.y = fmaf(xs1[j], w4.y, acc1.y);
            acc1.z = fmaf(xs1[j], w4.z, acc1.z);
            acc1.w = fmaf(xs1[j], w4.w, acc1.w);
        }
    }
    float4 b4 = ((const float4*)bias)[q];
    float4 o0, o1;
    o0.x = fmaxf(acc0.x + b4.x, 0.f); o0.y = fmaxf(acc0.y + b4.y, 0.f);
    o0.z = fmaxf(acc0.z + b4.z, 0.f); o0.w = fmaxf(acc0.w + b4.w, 0.f);
    o1.x = fmaxf(acc1.x + b4.x, 0.f); o1.y = fmaxf(acc1.y + b4.y, 0.f);
    o1.z = fmaxf(acc1.z + b4.z, 0.f); o1.w = fmaxf(acc1.w + b4.w, 0.f);
    if (v0) ((float4*)(y + (size_t)row0 * FO))[q] = o0;
    if (v1) ((float4*)(y + (size_t)row1 * FO))[q] = o1;
    float4 p4 = ((const float4*)pvec)[q];
    float d0 = o0.x * p4.x + o0.y * p4.y + o0.z * p4.z + o0.w * p4.w;
    float d1 = o1.x * p4.x + o1.y * p4.y + o1.z * p4.z + o1.w * p4.w;
    float pn = p4.x * p4.x + p4.y * p4.y + p4.z * p4.z + p4.w * p4.w;
#pragma unroll
    for (int off = QN / 2; off > 0; off >>= 1) {
        d0 += __shfl_xor(d0, off, 64);
        d1 += __shfl_xor(d1, off, 64);
        pn += __shfl_xor(pn, off, 64);
    }
    if (q == 0) {
        float inv = rsqrtf(pn);
        if (v0) score[row0] = d0 * inv;
        if (v1) score[row1] = d1 * inv;
    }
}

// one block (1024 threads) per graph: radix-select the k-th largest composite key -> T64[b]
__global__ void k_topk_thresh(const float* __restrict__ score, unsigned long long* __restrict__ T64,
                              int* __restrict__ cnt, int n, int k) {
    int b = blockIdx.x;
    const float* sc = score + (size_t)b * n;
    __shared__ unsigned int hist[256];
    __shared__ unsigned long long s_prefix;
    __shared__ int s_r;
    __shared__ int s_done;
    if (threadIdx.x == 0) { s_prefix = 0ULL; s_r = k; s_done = 0; }
    __syncthreads();
    for (int shift = 56; shift >= 0; shift -= 8) {
        if (s_done) break;
        for (int i = threadIdx.x; i < 256; i += blockDim.x) hist[i] = 0u;
        __syncthreads();
        unsigned long long prefix = s_prefix;
        int hs = shift + 8;
        for (int i = threadIdx.x; i < n; i += blockDim.x) {
            unsigned long long key = key64_of(sc[i], i);
            bool match = (hs >= 64) || ((key >> hs) == (prefix >> hs));
            if (match) {
                unsigned d = (unsigned)((key >> shift) & 255ULL);
                atomicAdd(&hist[d], 1u);
            }
        }
        __syncthreads();
        if (threadIdx.x == 0) {
            int r = s_r;
            unsigned long long pfx = s_prefix;
            for (int d = 255; d >= 0; --d) {
                int c = (int)hist[d];
                if (r <= c) {
                    pfx |= ((unsigned long long)d) << shift;
                    if (r == c) s_done = 1;
                    break;
                }
                r -= c;
            }
            s_prefix = pfx;
            s_r = r;
        }
        __syncthreads();
    }
    if (threadIdx.x == 0) { T64[b] = s_prefix; cnt[b] = 0; }
}

// phase A: keep flag -> new index via wave-aggregated block atomic; score := tanh(score) for kept
__global__ void k_select_idx(float* __restrict__ score,
                             const unsigned long long* __restrict__ T64, int* __restrict__ cnt,
                             int* __restrict__ remap, int n, int k) {
    int b = blockIdx.y;
    int i = blockIdx.x * 256 + threadIdx.x;
    int m = b * n + i;
    bool keep = false;
    float s = 0.f;
    if (i < n) {
        s = score[m];
        keep = key64_of(s, i) >= T64[b];
    }
    unsigned long long mask = __ballot(keep);
    int lane = threadIdx.x & 63;
    int wv = threadIdx.x >> 6;
    int lp = __popcll(mask & ((1ULL << lane) - 1ULL));
    __shared__ int woff[4];
    __shared__ int blockBase;
    if (lane == 0) woff[wv] = __popcll(mask);
    __syncthreads();
    if (threadIdx.x == 0) {
        int t0 = woff[0], t1 = woff[1], t2 = woff[2], t3 = woff[3];
        woff[0] = 0; woff[1] = t0; woff[2] = t0 + t1; woff[3] = t0 + t1 + t2;
        blockBase = atomicAdd(&cnt[b], t0 + t1 + t2 + t3);
    }
    __syncthreads();
    if (i < n) {
        if (keep) {
            remap[m] = b * k + blockBase + woff[wv] + lp;
            score[m] = tanhf(s);
        } else {
            remap[m] = -1;
        }
    }
}

// phase B: coalesced float4 row copy, xout[remap[m]] = y[m] * score[m] (score holds tanh)
__global__ void k_select_copy(const float* __restrict__ y, const float* __restrict__ score,
                              const int* __restrict__ remap, float* __restrict__ xout,
                              int M, int Fo4) {
    int t = blockIdx.x * blockDim.x + threadIdx.x;
    if (t >= M * Fo4) return;
    int m = t / Fo4, c = t - m * Fo4;
    int ni = remap[m];
    if (ni < 0) return;
    float4 v = ((const float4*)y)[(size_t)m * Fo4 + c];
    float s = score[m];
    float4 o; o.x = v.x * s; o.y = v.y * s; o.z = v.z * s; o.w = v.w * s;
    ((float4*)xout)[(size_t)ni * Fo4 + c] = o;
}

__global__ void k_edge_remap(int* __restrict__ esrc, int* __restrict__ edst,
                             float* __restrict__ ew, const int* __restrict__ remap) {
    int e = blockIdx.x * blockDim.x + threadIdx.x;
    if (e >= E0) return;
    float w = ew[e];
    if (w != 0.f) {
        int ns = remap[esrc[e]];
        int nd = remap[edst[e]];
        if (ns >= 0 && nd >= 0) { esrc[e] = ns; edst[e] = nd; return; }
    }
    esrc[e] = 0; edst[e] = 0; ew[e] = 0.f;
}

// stage 1 of final pooling: grid (PCHUNKS, NB), block 128.
__global__ void k_pool_partial(const float* __restrict__ x, float* __restrict__ pmax,
                               float* __restrict__ psum, int K3, int chunk) {
    int b = blockIdx.y, c = blockIdx.x, f = threadIdx.x;
    int i0 = c * chunk;
    int i1 = min(K3, i0 + chunk);
    const float* xb = x + (size_t)b * K3 * 128;
    float mx = -FLT_MAX, sm = 0.f;
    for (int i = i0; i < i1; ++i) {
        float v = xb[(size_t)i * 128 + f];
        mx = fmaxf(mx, v);
        sm += v;
    }
    int o = (b * PCHUNKS + c) * 128 + f;
    pmax[o] = mx;
    psum[o] = sm;
}

// stage 2: one block (128 threads) per graph: combine partials + metadata conv + fc + fc2
__global__ void k_final2(const float* __restrict__ pmax, const float* __restrict__ psum,
                         const float* __restrict__ metadata,
                         const float* __restrict__ convm_w, const float* __restrict__ convm_b,
                         const float* __restrict__ fc_w, const float* __restrict__ fc_b,
                         const float* __restrict__ fc2_w, const float* __restrict__ fc2_b,
                         float* __restrict__ out, int K3) {
    int b = blockIdx.x;
    int f = threadIdx.x;   // 0..127
    __shared__ float xc[260];
    __shared__ float red[128];
    float mx = -FLT_MAX, sm = 0.f;
    for (int c = 0; c < PCHUNKS; ++c) {
        int o = (b * PCHUNKS + c) * 128 + f;
        mx = fmaxf(mx, pmax[o]);
        sm += psum[o];
    }
    xc[f] = mx;
    xc[128 + f] = sm / (float)K3;
    if (f < 4) {
        float mv = metadata[b] * convm_w[f] + convm_b[f];
        xc[256 + f] = mv > 0.f ? mv : 0.f;
    }
    __syncthreads();
    float acc = fc_b[f];
    for (int i = 0; i < 260; ++i) acc = fmaf(xc[i], fc_w[i * 128 + f], acc);
    acc = acc > 0.f ? acc : 0.f;
    red[f] = acc * fc2_w[f];
    __syncthreads();
    for (int s2 = 64; s2 > 0; s2 >>= 1) {
        if (f < s2) red[f] += red[f + s2];
        __syncthreads();
    }
    if (f == 0) out[b] = red[0] + fc2_b[0];
}

// ---------------- launch ----------------

extern "C" void kernel_launch(void* const* d_in, const int* in_sizes, int n_in,
                              void* d_out, int out_size, void* d_ws, size_t ws_size,
                              hipStream_t stream) {
    const float* x0       = (const float*)d_in[0];
    const int*   ei       = (const int*)d_in[1];
    const float* metadata = (const float*)d_in[2];
    const float* W[4]  = {(const float*)d_in[3], (const float*)d_in[6],
                          (const float*)d_in[9], (const float*)d_in[12]};
    const float* bs[4] = {(const float*)d_in[4], (const float*)d_in[7],
                          (const float*)d_in[10], (const float*)d_in[13]};
    const float* pv[4] = {(const float*)d_in[5], (const float*)d_in[8],
                          (const float*)d_in[11], (const float*)d_in[14]};
    const float* convm_w = (const float*)d_in[15];
    const float* convm_b = (const float*)d_in[16];
    const float* fc_w    = (const float*)d_in[17];
    const float* fc_b    = (const float*)d_in[18];
    const float* fc2_w   = (const float*)d_in[19];
    const float* fc2_b   = (const float*)d_in[20];

    // workspace bump allocation
    const size_t HMAX = 5243392;   // generous per-buffer size (max M*Fo)
    const size_t XMAX = 2621952;   // max pooled-x size (layer 3 out: 20484*128)
    const size_t MMAX = NB * (size_t)N0;   // 163848

    char* p = (char*)d_ws;
    size_t off = 0;
    auto alloc = [&](size_t bytes) -> char* {
        char* r = p + off;
        off = (off + bytes + 255) & ~(size_t)255;
        return r;
    };
    float* ax    = (float*)alloc(HMAX * 4);   // aggregated input features [M, FI]
    float* y     = (float*)alloc(HMAX * 4);   // layer output [M, FO]
    float* xb0   = (float*)alloc(XMAX * 4);
    float* xb1   = (float*)alloc(XMAX * 4);
    float* dinv  = (float*)alloc(MMAX * 4);
    float* score = (float*)alloc(MMAX * 4);
    int*   remap = (int*)alloc(MMAX * 4);
    int*   degi  = (int*)alloc(MMAX * 4);
    int*   rowptr= (int*)alloc((MMAX + 1) * 4);
    int*   cursor= (int*)alloc(MMAX * 4);
    int*   col   = (int*)alloc(E0 * 4);
    int*   bsum  = (int*)alloc(260 * 4);
    int*   esrc  = (int*)alloc(E0 * 4);
    int*   edst  = (int*)alloc(E0 * 4);
    float* ew    = (float*)alloc(E0 * 4);
    float* pmax  = (float*)alloc(NB * PCHUNKS * 128 * 4);
    float* psum  = (float*)alloc(NB * PCHUNKS * 128 * 4);
    unsigned long long* T64 = (unsigned long long*)alloc(NB * 8);
    int*   cnt   = (int*)alloc(NB * 4);
    (void)ws_size; (void)n_in; (void)in_sizes; (void)out_size;

    const int Fo[4] = {32, 64, 128, 128};
    const int Kk[4] = {20481, 10241, 5121, 2561};

    const int TB = 256;
    const int EG = (E0 + TB - 1) / TB;
    k_edges_init<<<EG, TB, 0, stream>>>(ei, esrc, edst, ew);

    int M = NB * N0;
    const float* xin = x0;
    float* xbufs[2] = {xb0, xb1};

    for (int L = 0; L < 4; ++L) {
        int fo = Fo[L];

        // ---- CSR build ----
        k_zero_int<<<(M + TB - 1) / TB, TB, 0, stream>>>(degi, M);
        k_deg_count<<<EG, TB, 0, stream>>>(edst, ew, degi);
        int nb = (M + 1023) / 1024;
        k_scan1<<<nb, 256, 0, stream>>>(degi, rowptr, bsum, M);
        k_scan2<<<1, 256, 0, stream>>>(bsum, nb);
        k_scan3<<<(M + 255) / 256, 256, 0, stream>>>(rowptr, bsum, cursor, M, nb);
        k_dinv<<<(M + TB - 1) / TB, TB, 0, stream>>>(rowptr, dinv, M);
        k_csr_fill<<<EG, TB, 0, stream>>>(esrc, edst, ew, cursor, col);

        // ---- aggregate input features (linear, so agg before matmul) ----
        if (L == 0) {
            k_gather_x4<<<(M + TB - 1) / TB, TB, 0, stream>>>(xin, rowptr, col, dinv, ax, M);
        } else if (L == 1) {
            int rpb = 8;   // 4 waves x 2 rows
            k_gather_x<32><<<(M + rpb - 1) / rpb, 256, 0, stream>>>(xin, rowptr, col, dinv, ax, M);
        } else if (L == 2) {
            int rpb = 4;
            k_gather_x<64><<<(M + rpb - 1) / rpb, 256, 0, stream>>>(xin, rowptr, col, dinv, ax, M);
        } else {
            int rpb = 4;
            k_gather_x<128><<<(M + rpb - 1) / rpb, 256, 0, stream>>>(xin, rowptr, col, dinv, ax, M);
        }

        // ---- fused matmul + bias + relu + score ----
        if (L == 0)
            k_mm<4, 32><<<(M + 63) / 64, 256, 0, stream>>>(ax, W[L], bs[L], pv[L], y, score, M);
        else if (L == 1)
            k_mm<32, 64><<<(M + 31) / 32, 256, 0, stream>>>(ax, W[L], bs[L], pv[L], y, score, M);
        else if (L == 2)
            k_mm<64, 128><<<(M + 15) / 16, 256, 0, stream>>>(ax, W[L], bs[L], pv[L], y, score, M);
        else
            k_mm<128, 128><<<(M + 15) / 16, 256, 0, stream>>>(ax, W[L], bs[L], pv[L], y, score, M);

        // ---- top-k pooling ----
        int n = M / NB, kk = Kk[L];
        k_topk_thresh<<<NB, 1024, 0, stream>>>(score, T64, cnt, n, kk);
        dim3 gsel((n + 255) / 256, NB);
        k_select_idx<<<gsel, 256, 0, stream>>>(score, T64, cnt, remap, n, kk);
        float* xout = xbufs[L & 1];
        int ctot = M * (fo / 4);
        k_select_copy<<<(ctot + TB - 1) / TB, TB, 0, stream>>>(y, score, remap, xout,
                                                               M, fo / 4);
        if (L < 3)
            k_edge_remap<<<EG, TB, 0, stream>>>(esrc, edst, ew, remap);

        M = NB * kk;
        xin = xout;
    }

    int K3 = Kk[3];
    int chunk = (K3 + PCHUNKS - 1) / PCHUNKS;
    dim3 gpool(PCHUNKS, NB);
    k_pool_partial<<<gpool, 128, 0, stream>>>(xin, pmax, psum, K3, chunk);
    k_final2<<<NB, 128, 0, stream>>>(pmax, psum, metadata, convm_w, convm_b,
                                     fc_w, fc_b, fc2_w, fc2_b, (float*)d_out, K3);
}

// Round 6
// 751.686 us; speedup vs baseline: 2.3254x; 2.3254x over previous
//
#include <hip/hip_runtime.h>
#include <float.h>
#include <math.h>

#define NB 4            // graphs per batch
#define N0 40962        // nodes per graph at input
#define E0 983088       // total directed edges (fixed across layers; dead edges have w=0)
#define PCHUNKS 40      // stage-1 pooling blocks per graph

// ---------------- helpers ----------------

static __device__ __forceinline__ unsigned long long key64_of(float s, int li) {
    unsigned u = __float_as_uint(s);
    u = (u & 0x80000000u) ? ~u : (u | 0x80000000u);
    unsigned low = ~(unsigned)li;
    return ((unsigned long long)u << 32) | (unsigned long long)low;
}

// ---------------- kernels ----------------

__global__ void k_edges_init(const int* __restrict__ ei, int* __restrict__ esrc,
                             int* __restrict__ edst, float* __restrict__ ew) {
    int e = blockIdx.x * blockDim.x + threadIdx.x;
    if (e >= E0) return;
    esrc[e] = ei[e];
    edst[e] = ei[E0 + e];
    ew[e] = 1.0f;
}

__global__ void k_zero_int(int* __restrict__ a, int n) {
    int i = blockIdx.x * blockDim.x + threadIdx.x;
    if (i < n) a[i] = 0;
}

// count live in-edges per dst node
__global__ void k_deg_count(const int* __restrict__ edst, const float* __restrict__ ew,
                            int* __restrict__ degi) {
    int e = blockIdx.x * blockDim.x + threadIdx.x;
    if (e >= E0) return;
    if (ew[e] != 0.f) atomicAdd(&degi[edst[e]], 1);
}

// exclusive scan, stage 1: 1024 elements per block (256 threads x 4)
__global__ void k_scan1(const int* __restrict__ in, int* __restrict__ out,
                        int* __restrict__ bsum, int M) {
    __shared__ int s[256];
    int t = threadIdx.x;
    int base = blockIdx.x * 1024 + t * 4;
    int d0 = (base + 0 < M) ? in[base + 0] : 0;
    int d1 = (base + 1 < M) ? in[base + 1] : 0;
    int d2 = (base + 2 < M) ? in[base + 2] : 0;
    int d3 = (base + 3 < M) ? in[base + 3] : 0;
    int tsum = d0 + d1 + d2 + d3;
    s[t] = tsum;
    __syncthreads();
    for (int off = 1; off < 256; off <<= 1) {
        int v = (t >= off) ? s[t - off] : 0;
        __syncthreads();
        s[t] += v;
        __syncthreads();
    }
    int texcl = s[t] - tsum;
    if (base + 0 < M) out[base + 0] = texcl;
    if (base + 1 < M) out[base + 1] = texcl + d0;
    if (base + 2 < M) out[base + 2] = texcl + d0 + d1;
    if (base + 3 < M) out[base + 3] = texcl + d0 + d1 + d2;
    if (t == 255) bsum[blockIdx.x] = s[255];
}

// stage 2: single block exclusive scan of block sums (nb <= 256); bsum[nb] = total
__global__ void k_scan2(int* __restrict__ bsum, int nb) {
    __shared__ int s[256];
    int t = threadIdx.x;
    int v = (t < nb) ? bsum[t] : 0;
    s[t] = v;
    __syncthreads();
    for (int off = 1; off < 256; off <<= 1) {
        int u = (t >= off) ? s[t - off] : 0;
        __syncthreads();
        s[t] += u;
        __syncthreads();
    }
    if (t < nb) bsum[t] = s[t] - v;
    if (t == 255) bsum[nb] = s[255];
}

// stage 3: add block offsets; init cursor; write rowptr[M]
__global__ void k_scan3(int* __restrict__ rowptr, const int* __restrict__ bsum,
                        int* __restrict__ cursor, int M, int nb) {
    int i = blockIdx.x * 256 + threadIdx.x;
    if (i < M) {
        int v = rowptr[i] + bsum[i >> 10];
        rowptr[i] = v;
        cursor[i] = v;
    }
    if (i == 0) rowptr[M] = bsum[nb];
}

// dinv[m] = rsqrt(in_deg + 1)
__global__ void k_dinv(const int* __restrict__ rowptr, float* __restrict__ dinv, int M) {
    int m = blockIdx.x * blockDim.x + threadIdx.x;
    if (m >= M) return;
    dinv[m] = rsqrtf((float)(rowptr[m + 1] - rowptr[m]) + 1.0f);
}

// place live edges into CSR buckets (arbitrary order within bucket)
__global__ void k_csr_fill(const int* __restrict__ esrc, const int* __restrict__ edst,
                           const float* __restrict__ ew, int* __restrict__ cursor,
                           int* __restrict__ col) {
    int e = blockIdx.x * blockDim.x + threadIdx.x;
    if (e >= E0) return;
    if (ew[e] != 0.f) {
        int d = edst[e];
        int pos = atomicAdd(&cursor[d], 1);
        col[pos] = esrc[e];
    }
}

// aggregate input features (FI=4): one row per thread, float4 loads.
__global__ void k_gather_x4(const float* __restrict__ x, const int* __restrict__ rowptr,
                            const int* __restrict__ col, const float* __restrict__ dinv,
                            float* __restrict__ ax, int M) {
    int row = blockIdx.x * blockDim.x + threadIdx.x;
    if (row >= M) return;
    int rp0 = rowptr[row], rp1 = rowptr[row + 1];
    float dd = dinv[row];
    float invdeg = dd * dd;
    float4 xs = ((const float4*)x)[row];
    float4 acc;
    acc.x = xs.x * invdeg; acc.y = xs.y * invdeg;
    acc.z = xs.z * invdeg; acc.w = xs.w * invdeg;
    for (int j = rp0; j < rp1; ++j) {
        int s = col[j];
        float nrm = dd * dinv[s];
        float4 v = ((const float4*)x)[s];
        acc.x = fmaf(v.x, nrm, acc.x);
        acc.y = fmaf(v.y, nrm, acc.y);
        acc.z = fmaf(v.z, nrm, acc.z);
        acc.w = fmaf(v.w, nrm, acc.w);
    }
    ((float4*)ax)[row] = acc;
}

// aggregate input features (FI = 32/64/128): sub-wave per row, coalesced feature reads
template <int FI>
__global__ void k_gather_x(const float* __restrict__ x, const int* __restrict__ rowptr,
                           const int* __restrict__ col, const float* __restrict__ dinv,
                           float* __restrict__ ax, int M) {
    constexpr int LPR = (FI < 64) ? FI : 64;   // lanes per row
    constexpr int VPL = FI / LPR;              // floats per lane (1 or 2)
    constexpr int RPW = 64 / LPR;              // rows per wave
    int wave = (blockIdx.x * blockDim.x + threadIdx.x) >> 6;
    int lane = threadIdx.x & 63;
    int sub = lane / LPR;
    int f = lane % LPR;
    int row = wave * RPW + sub;
    if (row >= M) return;
    int rp0 = rowptr[row], rp1 = rowptr[row + 1];
    float dd = dinv[row];
    float invdeg = dd * dd;
    float acc[VPL];
#pragma unroll
    for (int v = 0; v < VPL; ++v)
        acc[v] = x[(size_t)row * FI + f * VPL + v] * invdeg;
    for (int j = rp0; j < rp1; ++j) {
        int s = col[j];
        float nrm = dd * dinv[s];
#pragma unroll
        for (int v = 0; v < VPL; ++v)
            acc[v] = fmaf(x[(size_t)s * FI + f * VPL + v], nrm, acc[v]);
    }
#pragma unroll
    for (int v = 0; v < VPL; ++v)
        ax[(size_t)row * FI + f * VPL + v] = acc[v];
}

// fused dense layer: y = relu(ax @ W + bias); score = dot(y, p)/|p|
// LDS-free, low register footprint. Thread = 2 rows x 4 cols; Q = FO/4 lanes per row-pair.
// M is always even here (163848/81924/40964/20484). #pragma unroll 2 keeps the c-loop a
// loop — full unroll caused ~2.5 KB/thread scratch spill (R5: 1.55 GB HBM traffic/dispatch).
template <int FI, int FO>
__global__ void __launch_bounds__(256) k_mm(const float* __restrict__ ax,
                                            const float* __restrict__ W,
                                            const float* __restrict__ bias,
                                            const float* __restrict__ pvec,
                                            float* __restrict__ y,
                                            float* __restrict__ score, int M) {
    constexpr int Q = FO / 4;   // 8 / 16 / 32 lanes per row-pair
    int t = blockIdx.x * blockDim.x + threadIdx.x;
    int rp = t / Q;
    int q = t % Q;
    int row0 = rp * 2, row1 = row0 + 1;
    if (row0 >= M) return;
    const float4* x0 = (const float4*)(ax + (size_t)row0 * FI);
    const float4* x1 = (const float4*)(ax + (size_t)row1 * FI);
    const float4* W4 = (const float4*)W;
    float4 acc0 = {0.f, 0.f, 0.f, 0.f}, acc1 = {0.f, 0.f, 0.f, 0.f};
#pragma unroll 2
    for (int c = 0; c < FI / 4; ++c) {
        float4 a = x0[c];
        float4 b = x1[c];
        const float4* wr = W4 + (size_t)(c * 4) * Q + q;
        float4 w;
        w = wr[0 * Q];
        acc0.x = fmaf(a.x, w.x, acc0.x); acc0.y = fmaf(a.x, w.y, acc0.y);
        acc0.z = fmaf(a.x, w.z, acc0.z); acc0.w = fmaf(a.x, w.w, acc0.w);
        acc1.x = fmaf(b.x, w.x, acc1.x); acc1.y = fmaf(b.x, w.y, acc1.y);
        acc1.z = fmaf(b.x, w.z, acc1.z); acc1.w = fmaf(b.x, w.w, acc1.w);
        w = wr[1 * Q];
        acc0.x = fmaf(a.y, w.x, acc0.x); acc0.y = fmaf(a.y, w.y, acc0.y);
        acc0.z = fmaf(a.y, w.z, acc0.z); acc0.w = fmaf(a.y, w.w, acc0.w);
        acc1.x = fmaf(b.y, w.x, acc1.x); acc1.y = fmaf(b.y, w.y, acc1.y);
        acc1.z = fmaf(b.y, w.z, acc1.z); acc1.w = fmaf(b.y, w.w, acc1.w);
        w = wr[2 * Q];
        acc0.x = fmaf(a.z, w.x, acc0.x); acc0.y = fmaf(a.z, w.y, acc0.y);
        acc0.z = fmaf(a.z, w.z, acc0.z); acc0.w = fmaf(a.z, w.w, acc0.w);
        acc1.x = fmaf(b.z, w.x, acc1.x); acc1.y = fmaf(b.z, w.y, acc1.y);
        acc1.z = fmaf(b.z, w.z, acc1.z); acc1.w = fmaf(b.z, w.w, acc1.w);
        w = wr[3 * Q];
        acc0.x = fmaf(a.w, w.x, acc0.x); acc0.y = fmaf(a.w, w.y, acc0.y);
        acc0.z = fmaf(a.w, w.z, acc0.z); acc0.w = fmaf(a.w, w.w, acc0.w);
        acc1.x = fmaf(b.w, w.x, acc1.x); acc1.y = fmaf(b.w, w.y, acc1.y);
        acc1.z = fmaf(b.w, w.z, acc1.z); acc1.w = fmaf(b.w, w.w, acc1.w);
    }
    float4 b4 = ((const float4*)bias)[q];
    float4 o0, o1;
    o0.x = fmaxf(acc0.x + b4.x, 0.f); o0.y = fmaxf(acc0.y + b4.y, 0.f);
    o0.z = fmaxf(acc0.z + b4.z, 0.f); o0.w = fmaxf(acc0.w + b4.w, 0.f);
    o1.x = fmaxf(acc1.x + b4.x, 0.f); o1.y = fmaxf(acc1.y + b4.y, 0.f);
    o1.z = fmaxf(acc1.z + b4.z, 0.f); o1.w = fmaxf(acc1.w + b4.w, 0.f);
    ((float4*)(y + (size_t)row0 * FO))[q] = o0;
    ((float4*)(y + (size_t)row1 * FO))[q] = o1;
    float4 p4 = ((const float4*)pvec)[q];
    float d0 = o0.x * p4.x + o0.y * p4.y + o0.z * p4.z + o0.w * p4.w;
    float d1 = o1.x * p4.x + o1.y * p4.y + o1.z * p4.z + o1.w * p4.w;
    float pn = p4.x * p4.x + p4.y * p4.y + p4.z * p4.z + p4.w * p4.w;
#pragma unroll
    for (int off = Q / 2; off > 0; off >>= 1) {
        d0 += __shfl_xor(d0, off, 64);
        d1 += __shfl_xor(d1, off, 64);
        pn += __shfl_xor(pn, off, 64);
    }
    if (q == 0) {
        float inv = rsqrtf(pn);
        score[row0] = d0 * inv;
        score[row1] = d1 * inv;
    }
}

// one block (1024 threads) per graph: radix-select the k-th largest composite key -> T64[b]
__global__ void k_topk_thresh(const float* __restrict__ score, unsigned long long* __restrict__ T64,
                              int* __restrict__ cnt, int n, int k) {
    int b = blockIdx.x;
    const float* sc = score + (size_t)b * n;
    __shared__ unsigned int hist[256];
    __shared__ unsigned long long s_prefix;
    __shared__ int s_r;
    __shared__ int s_done;
    if (threadIdx.x == 0) { s_prefix = 0ULL; s_r = k; s_done = 0; }
    __syncthreads();
    for (int shift = 56; shift >= 0; shift -= 8) {
        if (s_done) break;
        for (int i = threadIdx.x; i < 256; i += blockDim.x) hist[i] = 0u;
        __syncthreads();
        unsigned long long prefix = s_prefix;
        int hs = shift + 8;
        for (int i = threadIdx.x; i < n; i += blockDim.x) {
            unsigned long long key = key64_of(sc[i], i);
            bool match = (hs >= 64) || ((key >> hs) == (prefix >> hs));
            if (match) {
                unsigned d = (unsigned)((key >> shift) & 255ULL);
                atomicAdd(&hist[d], 1u);
            }
        }
        __syncthreads();
        if (threadIdx.x == 0) {
            int r = s_r;
            unsigned long long pfx = s_prefix;
            for (int d = 255; d >= 0; --d) {
                int c = (int)hist[d];
                if (r <= c) {
                    pfx |= ((unsigned long long)d) << shift;
                    if (r == c) s_done = 1;
                    break;
                }
                r -= c;
            }
            s_prefix = pfx;
            s_r = r;
        }
        __syncthreads();
    }
    if (threadIdx.x == 0) { T64[b] = s_prefix; cnt[b] = 0; }
}

// phase A: keep flag -> new index via wave-aggregated block atomic; score := tanh(score) for kept
__global__ void k_select_idx(float* __restrict__ score,
                             const unsigned long long* __restrict__ T64, int* __restrict__ cnt,
                             int* __restrict__ remap, int n, int k) {
    int b = blockIdx.y;
    int i = blockIdx.x * 256 + threadIdx.x;
    int m = b * n + i;
    bool keep = false;
    float s = 0.f;
    if (i < n) {
        s = score[m];
        keep = key64_of(s, i) >= T64[b];
    }
    unsigned long long mask = __ballot(keep);
    int lane = threadIdx.x & 63;
    int wv = threadIdx.x >> 6;
    int lp = __popcll(mask & ((1ULL << lane) - 1ULL));
    __shared__ int woff[4];
    __shared__ int blockBase;
    if (lane == 0) woff[wv] = __popcll(mask);
    __syncthreads();
    if (threadIdx.x == 0) {
        int t0 = woff[0], t1 = woff[1], t2 = woff[2], t3 = woff[3];
        woff[0] = 0; woff[1] = t0; woff[2] = t0 + t1; woff[3] = t0 + t1 + t2;
        blockBase = atomicAdd(&cnt[b], t0 + t1 + t2 + t3);
    }
    __syncthreads();
    if (i < n) {
        if (keep) {
            remap[m] = b * k + blockBase + woff[wv] + lp;
            score[m] = tanhf(s);
        } else {
            remap[m] = -1;
        }
    }
}

// phase B: coalesced float4 row copy, xout[remap[m]] = y[m] * score[m] (score holds tanh)
__global__ void k_select_copy(const float* __restrict__ y, const float* __restrict__ score,
                              const int* __restrict__ remap, float* __restrict__ xout,
                              int M, int Fo4) {
    int t = blockIdx.x * blockDim.x + threadIdx.x;
    if (t >= M * Fo4) return;
    int m = t / Fo4, c = t - m * Fo4;
    int ni = remap[m];
    if (ni < 0) return;
    float4 v = ((const float4*)y)[(size_t)m * Fo4 + c];
    float s = score[m];
    float4 o; o.x = v.x * s; o.y = v.y * s; o.z = v.z * s; o.w = v.w * s;
    ((float4*)xout)[(size_t)ni * Fo4 + c] = o;
}

__global__ void k_edge_remap(int* __restrict__ esrc, int* __restrict__ edst,
                             float* __restrict__ ew, const int* __restrict__ remap) {
    int e = blockIdx.x * blockDim.x + threadIdx.x;
    if (e >= E0) return;
    float w = ew[e];
    if (w != 0.f) {
        int ns = remap[esrc[e]];
        int nd = remap[edst[e]];
        if (ns >= 0 && nd >= 0) { esrc[e] = ns; edst[e] = nd; return; }
    }
    esrc[e] = 0; edst[e] = 0; ew[e] = 0.f;
}

// stage 1 of final pooling: grid (PCHUNKS, NB), block 128.
__global__ void k_pool_partial(const float* __restrict__ x, float* __restrict__ pmax,
                               float* __restrict__ psum, int K3, int chunk) {
    int b = blockIdx.y, c = blockIdx.x, f = threadIdx.x;
    int i0 = c * chunk;
    int i1 = min(K3, i0 + chunk);
    const float* xb = x + (size_t)b * K3 * 128;
    float mx = -FLT_MAX, sm = 0.f;
    for (int i = i0; i < i1; ++i) {
        float v = xb[(size_t)i * 128 + f];
        mx = fmaxf(mx, v);
        sm += v;
    }
    int o = (b * PCHUNKS + c) * 128 + f;
    pmax[o] = mx;
    psum[o] = sm;
}

// stage 2: one block (128 threads) per graph: combine partials + metadata conv + fc + fc2
__global__ void k_final2(const float* __restrict__ pmax, const float* __restrict__ psum,
                         const float* __restrict__ metadata,
                         const float* __restrict__ convm_w, const float* __restrict__ convm_b,
                         const float* __restrict__ fc_w, const float* __restrict__ fc_b,
                         const float* __restrict__ fc2_w, const float* __restrict__ fc2_b,
                         float* __restrict__ out, int K3) {
    int b = blockIdx.x;
    int f = threadIdx.x;   // 0..127
    __shared__ float xc[260];
    __shared__ float red[128];
    float mx = -FLT_MAX, sm = 0.f;
    for (int c = 0; c < PCHUNKS; ++c) {
        int o = (b * PCHUNKS + c) * 128 + f;
        mx = fmaxf(mx, pmax[o]);
        sm += psum[o];
    }
    xc[f] = mx;
    xc[128 + f] = sm / (float)K3;
    if (f < 4) {
        float mv = metadata[b] * convm_w[f] + convm_b[f];
        xc[256 + f] = mv > 0.f ? mv : 0.f;
    }
    __syncthreads();
    float acc = fc_b[f];
    for (int i = 0; i < 260; ++i) acc = fmaf(xc[i], fc_w[i * 128 + f], acc);
    acc = acc > 0.f ? acc : 0.f;
    red[f] = acc * fc2_w[f];
    __syncthreads();
    for (int s2 = 64; s2 > 0; s2 >>= 1) {
        if (f < s2) red[f] += red[f + s2];
        __syncthreads();
    }
    if (f == 0) out[b] = red[0] + fc2_b[0];
}

// ---------------- launch ----------------

extern "C" void kernel_launch(void* const* d_in, const int* in_sizes, int n_in,
                              void* d_out, int out_size, void* d_ws, size_t ws_size,
                              hipStream_t stream) {
    const float* x0       = (const float*)d_in[0];
    const int*   ei       = (const int*)d_in[1];
    const float* metadata = (const float*)d_in[2];
    const float* W[4]  = {(const float*)d_in[3], (const float*)d_in[6],
                          (const float*)d_in[9], (const float*)d_in[12]};
    const float* bs[4] = {(const float*)d_in[4], (const float*)d_in[7],
                          (const float*)d_in[10], (const float*)d_in[13]};
    const float* pv[4] = {(const float*)d_in[5], (const float*)d_in[8],
                          (const float*)d_in[11], (const float*)d_in[14]};
    const float* convm_w = (const float*)d_in[15];
    const float* convm_b = (const float*)d_in[16];
    const float* fc_w    = (const float*)d_in[17];
    const float* fc_b    = (const float*)d_in[18];
    const float* fc2_w   = (const float*)d_in[19];
    const float* fc2_b   = (const float*)d_in[20];

    // workspace bump allocation
    const size_t HMAX = 5243392;   // generous per-buffer size (max M*Fo)
    const size_t XMAX = 2621952;   // max pooled-x size (layer 3 out: 20484*128)
    const size_t MMAX = NB * (size_t)N0;   // 163848

    char* p = (char*)d_ws;
    size_t off = 0;
    auto alloc = [&](size_t bytes) -> char* {
        char* r = p + off;
        off = (off + bytes + 255) & ~(size_t)255;
        return r;
    };
    float* ax    = (float*)alloc(HMAX * 4);   // aggregated input features [M, FI]
    float* y     = (float*)alloc(HMAX * 4);   // layer output [M, FO]
    float* xb0   = (float*)alloc(XMAX * 4);
    float* xb1   = (float*)alloc(XMAX * 4);
    float* dinv  = (float*)alloc(MMAX * 4);
    float* score = (float*)alloc(MMAX * 4);
    int*   remap = (int*)alloc(MMAX * 4);
    int*   degi  = (int*)alloc(MMAX * 4);
    int*   rowptr= (int*)alloc((MMAX + 1) * 4);
    int*   cursor= (int*)alloc(MMAX * 4);
    int*   col   = (int*)alloc(E0 * 4);
    int*   bsum  = (int*)alloc(260 * 4);
    int*   esrc  = (int*)alloc(E0 * 4);
    int*   edst  = (int*)alloc(E0 * 4);
    float* ew    = (float*)alloc(E0 * 4);
    float* pmax  = (float*)alloc(NB * PCHUNKS * 128 * 4);
    float* psum  = (float*)alloc(NB * PCHUNKS * 128 * 4);
    unsigned long long* T64 = (unsigned long long*)alloc(NB * 8);
    int*   cnt   = (int*)alloc(NB * 4);
    (void)ws_size; (void)n_in; (void)in_sizes; (void)out_size;

    const int Fo[4] = {32, 64, 128, 128};
    const int Kk[4] = {20481, 10241, 5121, 2561};

    const int TB = 256;
    const int EG = (E0 + TB - 1) / TB;
    k_edges_init<<<EG, TB, 0, stream>>>(ei, esrc, edst, ew);

    int M = NB * N0;
    const float* xin = x0;
    float* xbufs[2] = {xb0, xb1};

    for (int L = 0; L < 4; ++L) {
        int fo = Fo[L];

        // ---- CSR build ----
        k_zero_int<<<(M + TB - 1) / TB, TB, 0, stream>>>(degi, M);
        k_deg_count<<<EG, TB, 0, stream>>>(edst, ew, degi);
        int nb = (M + 1023) / 1024;
        k_scan1<<<nb, 256, 0, stream>>>(degi, rowptr, bsum, M);
        k_scan2<<<1, 256, 0, stream>>>(bsum, nb);
        k_scan3<<<(M + 255) / 256, 256, 0, stream>>>(rowptr, bsum, cursor, M, nb);
        k_dinv<<<(M + TB - 1) / TB, TB, 0, stream>>>(rowptr, dinv, M);
        k_csr_fill<<<EG, TB, 0, stream>>>(esrc, edst, ew, cursor, col);

        // ---- aggregate input features (linear, so agg before matmul) ----
        if (L == 0) {
            k_gather_x4<<<(M + TB - 1) / TB, TB, 0, stream>>>(xin, rowptr, col, dinv, ax, M);
        } else if (L == 1) {
            int rpb = 8;   // 4 waves x 2 rows
            k_gather_x<32><<<(M + rpb - 1) / rpb, 256, 0, stream>>>(xin, rowptr, col, dinv, ax, M);
        } else if (L == 2) {
            int rpb = 4;
            k_gather_x<64><<<(M + rpb - 1) / rpb, 256, 0, stream>>>(xin, rowptr, col, dinv, ax, M);
        } else {
            int rpb = 4;
            k_gather_x<128><<<(M + rpb - 1) / rpb, 256, 0, stream>>>(xin, rowptr, col, dinv, ax, M);
        }

        // ---- fused matmul + bias + relu + score ----
        // threads = (M/2) * (FO/4); M is even at every layer
        if (L == 0) {
            int nt = (M / 2) * 8;
            k_mm<4, 32><<<(nt + 255) / 256, 256, 0, stream>>>(ax, W[L], bs[L], pv[L], y, score, M);
        } else if (L == 1) {
            int nt = (M / 2) * 16;
            k_mm<32, 64><<<(nt + 255) / 256, 256, 0, stream>>>(ax, W[L], bs[L], pv[L], y, score, M);
        } else if (L == 2) {
            int nt = (M / 2) * 32;
            k_mm<64, 128><<<(nt + 255) / 256, 256, 0, stream>>>(ax, W[L], bs[L], pv[L], y, score, M);
        } else {
            int nt = (M / 2) * 32;
            k_mm<128, 128><<<(nt + 255) / 256, 256, 0, stream>>>(ax, W[L], bs[L], pv[L], y, score, M);
        }

        // ---- top-k pooling ----
        int n = M / NB, kk = Kk[L];
        k_topk_thresh<<<NB, 1024, 0, stream>>>(score, T64, cnt, n, kk);
        dim3 gsel((n + 255) / 256, NB);
        k_select_idx<<<gsel, 256, 0, stream>>>(score, T64, cnt, remap, n, kk);
        float* xout = xbufs[L & 1];
        int ctot = M * (fo / 4);
        k_select_copy<<<(ctot + TB - 1) / TB, TB, 0, stream>>>(y, score, remap, xout,
                                                               M, fo / 4);
        if (L < 3)
            k_edge_remap<<<EG, TB, 0, stream>>>(esrc, edst, ew, remap);

        M = NB * kk;
        xin = xout;
    }

    int K3 = Kk[3];
    int chunk = (K3 + PCHUNKS - 1) / PCHUNKS;
    dim3 gpool(PCHUNKS, NB);
    k_pool_partial<<<gpool, 128, 0, stream>>>(xin, pmax, psum, K3, chunk);
    k_final2<<<NB, 128, 0, stream>>>(pmax, psum, metadata, convm_w, convm_b,
                                     fc_w, fc_b, fc2_w, fc2_b, (float*)d_out, K3);
}

// Round 7
// 734.369 us; speedup vs baseline: 2.3802x; 1.0236x over previous
//
#include <hip/hip_runtime.h>
#include <float.h>
#include <math.h>

#define NB 4            // graphs per batch
#define N0 40962        // nodes per graph at input
#define E0 983088       // total directed edges (fixed across layers; dead edges have w=0)
#define PCHUNKS 40      // stage-1 pooling blocks per graph
#define TK_CAP 6144     // candidate capacity for fine top-k select (48 KB LDS)

// ---------------- helpers ----------------

static __device__ __forceinline__ unsigned key32_of(float s) {
    unsigned u = __float_as_uint(s);
    return (u & 0x80000000u) ? ~u : (u | 0x80000000u);
}

static __device__ __forceinline__ unsigned long long key64_of(float s, int li) {
    unsigned u = key32_of(s);
    unsigned low = ~(unsigned)li;   // ties broken by smaller local index
    return ((unsigned long long)u << 32) | (unsigned long long)low;
}

// ---------------- kernels ----------------

// L0: copy edge list + count in-degrees (degi pre-zeroed)
__global__ void k_edges_init_count(const int* __restrict__ ei, int* __restrict__ esrc,
                                   int* __restrict__ edst, float* __restrict__ ew,
                                   int* __restrict__ degi) {
    int e = blockIdx.x * blockDim.x + threadIdx.x;
    if (e >= E0) return;
    int s = ei[e], d = ei[E0 + e];
    esrc[e] = s;
    edst[e] = d;
    ew[e] = 1.0f;
    atomicAdd(&degi[d], 1);
}

// layer end: remap surviving edges to new ids AND count next layer's in-degrees
__global__ void k_edge_remap_count(int* __restrict__ esrc, int* __restrict__ edst,
                                   float* __restrict__ ew, const int* __restrict__ remap,
                                   int* __restrict__ degi) {
    int e = blockIdx.x * blockDim.x + threadIdx.x;
    if (e >= E0) return;
    float w = ew[e];
    if (w != 0.f) {
        int ns = remap[esrc[e]];
        int nd = remap[edst[e]];
        if (ns >= 0 && nd >= 0) {
            esrc[e] = ns; edst[e] = nd;
            atomicAdd(&degi[nd], 1);
            return;
        }
    }
    esrc[e] = 0; edst[e] = 0; ew[e] = 0.f;
}

// exclusive scan, stage 1: 1024 elements per block (256 threads x 4)
__global__ void k_scan1(const int* __restrict__ in, int* __restrict__ out,
                        int* __restrict__ bsum, int M) {
    __shared__ int s[256];
    int t = threadIdx.x;
    int base = blockIdx.x * 1024 + t * 4;
    int d0 = (base + 0 < M) ? in[base + 0] : 0;
    int d1 = (base + 1 < M) ? in[base + 1] : 0;
    int d2 = (base + 2 < M) ? in[base + 2] : 0;
    int d3 = (base + 3 < M) ? in[base + 3] : 0;
    int tsum = d0 + d1 + d2 + d3;
    s[t] = tsum;
    __syncthreads();
    for (int off = 1; off < 256; off <<= 1) {
        int v = (t >= off) ? s[t - off] : 0;
        __syncthreads();
        s[t] += v;
        __syncthreads();
    }
    int texcl = s[t] - tsum;
    if (base + 0 < M) out[base + 0] = texcl;
    if (base + 1 < M) out[base + 1] = texcl + d0;
    if (base + 2 < M) out[base + 2] = texcl + d0 + d1;
    if (base + 3 < M) out[base + 3] = texcl + d0 + d1 + d2;
    if (t == 255) bsum[blockIdx.x] = s[255];
}

// stage 2: single block exclusive scan of block sums (nb <= 256); bsum[nb] = total
__global__ void k_scan2(int* __restrict__ bsum, int nb) {
    __shared__ int s[256];
    int t = threadIdx.x;
    int v = (t < nb) ? bsum[t] : 0;
    s[t] = v;
    __syncthreads();
    for (int off = 1; off < 256; off <<= 1) {
        int u = (t >= off) ? s[t - off] : 0;
        __syncthreads();
        s[t] += u;
        __syncthreads();
    }
    if (t < nb) bsum[t] = s[t] - v;
    if (t == 255) bsum[nb] = s[255];
}

// stage 3: add block offsets; init cursor; write rowptr[M]; dinv = rsqrt(deg+1)
__global__ void k_scan3(int* __restrict__ rowptr, const int* __restrict__ bsum,
                        int* __restrict__ cursor, const int* __restrict__ degi,
                        float* __restrict__ dinv, int M, int nb) {
    int i = blockIdx.x * 256 + threadIdx.x;
    if (i < M) {
        int v = rowptr[i] + bsum[i >> 10];
        rowptr[i] = v;
        cursor[i] = v;
        dinv[i] = rsqrtf((float)degi[i] + 1.0f);
    }
    if (i == 0) rowptr[M] = bsum[nb];
}

// place live edges into CSR buckets (arbitrary order within bucket)
__global__ void k_csr_fill(const int* __restrict__ esrc, const int* __restrict__ edst,
                           const float* __restrict__ ew, int* __restrict__ cursor,
                           int* __restrict__ col) {
    int e = blockIdx.x * blockDim.x + threadIdx.x;
    if (e >= E0) return;
    if (ew[e] != 0.f) {
        int d = edst[e];
        int pos = atomicAdd(&cursor[d], 1);
        col[pos] = esrc[e];
    }
}

// aggregate input features (FI=4): one row per thread, float4 loads.
__global__ void k_gather_x4(const float* __restrict__ x, const int* __restrict__ rowptr,
                            const int* __restrict__ col, const float* __restrict__ dinv,
                            float* __restrict__ ax, int M) {
    int row = blockIdx.x * blockDim.x + threadIdx.x;
    if (row >= M) return;
    int rp0 = rowptr[row], rp1 = rowptr[row + 1];
    float dd = dinv[row];
    float invdeg = dd * dd;
    float4 xs = ((const float4*)x)[row];
    float4 acc;
    acc.x = xs.x * invdeg; acc.y = xs.y * invdeg;
    acc.z = xs.z * invdeg; acc.w = xs.w * invdeg;
    for (int j = rp0; j < rp1; ++j) {
        int s = col[j];
        float nrm = dd * dinv[s];
        float4 v = ((const float4*)x)[s];
        acc.x = fmaf(v.x, nrm, acc.x);
        acc.y = fmaf(v.y, nrm, acc.y);
        acc.z = fmaf(v.z, nrm, acc.z);
        acc.w = fmaf(v.w, nrm, acc.w);
    }
    ((float4*)ax)[row] = acc;
}

// aggregate input features (FI = 32/64/128): sub-wave per row, coalesced feature reads
template <int FI>
__global__ void k_gather_x(const float* __restrict__ x, const int* __restrict__ rowptr,
                           const int* __restrict__ col, const float* __restrict__ dinv,
                           float* __restrict__ ax, int M) {
    constexpr int LPR = (FI < 64) ? FI : 64;   // lanes per row
    constexpr int VPL = FI / LPR;              // floats per lane (1 or 2)
    constexpr int RPW = 64 / LPR;              // rows per wave
    int wave = (blockIdx.x * blockDim.x + threadIdx.x) >> 6;
    int lane = threadIdx.x & 63;
    int sub = lane / LPR;
    int f = lane % LPR;
    int row = wave * RPW + sub;
    if (row >= M) return;
    int rp0 = rowptr[row], rp1 = rowptr[row + 1];
    float dd = dinv[row];
    float invdeg = dd * dd;
    float acc[VPL];
#pragma unroll
    for (int v = 0; v < VPL; ++v)
        acc[v] = x[(size_t)row * FI + f * VPL + v] * invdeg;
    for (int j = rp0; j < rp1; ++j) {
        int s = col[j];
        float nrm = dd * dinv[s];
#pragma unroll
        for (int v = 0; v < VPL; ++v)
            acc[v] = fmaf(x[(size_t)s * FI + f * VPL + v], nrm, acc[v]);
    }
#pragma unroll
    for (int v = 0; v < VPL; ++v)
        ax[(size_t)row * FI + f * VPL + v] = acc[v];
}

// fused dense layer: y = relu(ax @ W + bias); score = dot(y, p)/|p|; ghist 16-bit digit count.
// LDS-free, low register footprint. #pragma unroll 2 keeps the c-loop a loop — full unroll
// caused ~2.5 KB/thread scratch spill (R5: 1.55 GB HBM traffic/dispatch).
template <int FI, int FO>
__global__ void __launch_bounds__(256) k_mm(const float* __restrict__ ax,
                                            const float* __restrict__ W,
                                            const float* __restrict__ bias,
                                            const float* __restrict__ pvec,
                                            float* __restrict__ y,
                                            float* __restrict__ score,
                                            unsigned int* __restrict__ ghist,
                                            int M, int n) {
    constexpr int Q = FO / 4;   // 8 / 16 / 32 lanes per row-pair
    int t = blockIdx.x * blockDim.x + threadIdx.x;
    int rp = t / Q;
    int q = t % Q;
    int row0 = rp * 2, row1 = row0 + 1;
    if (row0 >= M) return;   // M always even
    const float4* x0 = (const float4*)(ax + (size_t)row0 * FI);
    const float4* x1 = (const float4*)(ax + (size_t)row1 * FI);
    const float4* W4 = (const float4*)W;
    float4 acc0 = {0.f, 0.f, 0.f, 0.f}, acc1 = {0.f, 0.f, 0.f, 0.f};
#pragma unroll 2
    for (int c = 0; c < FI / 4; ++c) {
        float4 a = x0[c];
        float4 b = x1[c];
        const float4* wr = W4 + (size_t)(c * 4) * Q + q;
        float4 w;
        w = wr[0 * Q];
        acc0.x = fmaf(a.x, w.x, acc0.x); acc0.y = fmaf(a.x, w.y, acc0.y);
        acc0.z = fmaf(a.x, w.z, acc0.z); acc0.w = fmaf(a.x, w.w, acc0.w);
        acc1.x = fmaf(b.x, w.x, acc1.x); acc1.y = fmaf(b.x, w.y, acc1.y);
        acc1.z = fmaf(b.x, w.z, acc1.z); acc1.w = fmaf(b.x, w.w, acc1.w);
        w = wr[1 * Q];
        acc0.x = fmaf(a.y, w.x, acc0.x); acc0.y = fmaf(a.y, w.y, acc0.y);
        acc0.z = fmaf(a.y, w.z, acc0.z); acc0.w = fmaf(a.y, w.w, acc0.w);
        acc1.x = fmaf(b.y, w.x, acc1.x); acc1.y = fmaf(b.y, w.y, acc1.y);
        acc1.z = fmaf(b.y, w.z, acc1.z); acc1.w = fmaf(b.y, w.w, acc1.w);
        w = wr[2 * Q];
        acc0.x = fmaf(a.z, w.x, acc0.x); acc0.y = fmaf(a.z, w.y, acc0.y);
        acc0.z = fmaf(a.z, w.z, acc0.z); acc0.w = fmaf(a.z, w.w, acc0.w);
        acc1.x = fmaf(b.z, w.x, acc1.x); acc1.y = fmaf(b.z, w.y, acc1.y);
        acc1.z = fmaf(b.z, w.z, acc1.z); acc1.w = fmaf(b.z, w.w, acc1.w);
        w = wr[3 * Q];
        acc0.x = fmaf(a.w, w.x, acc0.x); acc0.y = fmaf(a.w, w.y, acc0.y);
        acc0.z = fmaf(a.w, w.z, acc0.z); acc0.w = fmaf(a.w, w.w, acc0.w);
        acc1.x = fmaf(b.w, w.x, acc1.x); acc1.y = fmaf(b.w, w.y, acc1.y);
        acc1.z = fmaf(b.w, w.z, acc1.z); acc1.w = fmaf(b.w, w.w, acc1.w);
    }
    float4 b4 = ((const float4*)bias)[q];
    float4 o0, o1;
    o0.x = fmaxf(acc0.x + b4.x, 0.f); o0.y = fmaxf(acc0.y + b4.y, 0.f);
    o0.z = fmaxf(acc0.z + b4.z, 0.f); o0.w = fmaxf(acc0.w + b4.w, 0.f);
    o1.x = fmaxf(acc1.x + b4.x, 0.f); o1.y = fmaxf(acc1.y + b4.y, 0.f);
    o1.z = fmaxf(acc1.z + b4.z, 0.f); o1.w = fmaxf(acc1.w + b4.w, 0.f);
    ((float4*)(y + (size_t)row0 * FO))[q] = o0;
    ((float4*)(y + (size_t)row1 * FO))[q] = o1;
    float4 p4 = ((const float4*)pvec)[q];
    float d0 = o0.x * p4.x + o0.y * p4.y + o0.z * p4.z + o0.w * p4.w;
    float d1 = o1.x * p4.x + o1.y * p4.y + o1.z * p4.z + o1.w * p4.w;
    float pn = p4.x * p4.x + p4.y * p4.y + p4.z * p4.z + p4.w * p4.w;
#pragma unroll
    for (int off = Q / 2; off > 0; off >>= 1) {
        d0 += __shfl_xor(d0, off, 64);
        d1 += __shfl_xor(d1, off, 64);
        pn += __shfl_xor(pn, off, 64);
    }
    if (q == 0) {
        float inv = rsqrtf(pn);
        float s0 = d0 * inv, s1 = d1 * inv;
        score[row0] = s0;
        score[row1] = s1;
        int b0 = row0 / n, b1 = row1 / n;
        atomicAdd(&ghist[((size_t)b0 << 16) | (key32_of(s0) >> 16)], 1u);
        atomicAdd(&ghist[((size_t)b1 << 16) | (key32_of(s1) >> 16)], 1u);
    }
}

// one block (1024 threads) per graph: exact k-th largest key64 from the 16-bit coarse
// histogram + one filtered candidate pass + in-LDS radix on the remaining 48 bits.
// Zeroes ghist for the next layer; zeroes cnt for select_idx.
__global__ void __launch_bounds__(1024) k_topk_fine(
        const float* __restrict__ score, unsigned int* __restrict__ ghist,
        unsigned long long* __restrict__ T64, int* __restrict__ cnt, int n, int k) {
    int b = blockIdx.x;
    int t = threadIdx.x;
    const float* sc = score + (size_t)b * n;
    unsigned int* gh = ghist + ((size_t)b << 16);
    __shared__ int chunkSum[1024];
    __shared__ int chunkScan[1024];
    __shared__ unsigned long long cand[TK_CAP];
    __shared__ unsigned int hist[256];
    __shared__ int s_P16, s_r, s_c, s_rr, s_done, s_cc;
    __shared__ unsigned long long s_prefix;

    // ---- Step A: coarse pick from 65536-bin hist (descending) ----
    {
        int base = t << 6;   // thread t sums bins [64t .. 64t+63]
        int sum = 0;
        for (int j = 0; j < 64; ++j) sum += (int)gh[base + j];
        chunkSum[t] = sum;
        chunkScan[t] = sum;
    }
    __syncthreads();
    // suffix (from-top) inclusive scan: chunkScan[t] = sum of chunks t..1023
    for (int off = 1; off < 1024; off <<= 1) {
        int v = (t + off < 1024) ? chunkScan[t + off] : 0;
        __syncthreads();
        chunkScan[t] += v;
        __syncthreads();
    }
    {
        int cumAbove = chunkScan[t] - chunkSum[t];   // sum of chunks strictly above t
        if (cumAbove < k && chunkScan[t] >= k) {     // threshold lies in chunk t
            int cum = cumAbove;
            int base = t << 6;
            for (int j = 63; j >= 0; --j) {          // bins descending within chunk
                int cb = (int)gh[base + j];
                cum += cb;
                if (cum >= k) {
                    s_P16 = base + j;
                    s_r = k - (cum - cb);   // 1-based rank within bucket
                    s_c = cb;
                    break;
                }
            }
        }
    }
    if (t == 0) s_cc = 0;
    __syncthreads();
    int P16 = s_P16, r = s_r, c = s_c;

    // ---- Step B: collect bucket candidates into LDS ----
    if (c <= TK_CAP) {
        for (int i = t; i < n; i += 1024) {
            unsigned u = key32_of(sc[i]);
            if ((int)(u >> 16) == P16) {
                int pos = atomicAdd(&s_cc, 1);
                cand[pos] = ((unsigned long long)u << 32) |
                            (unsigned long long)(~(unsigned)i);
            }
        }
    }
    if (t == 0) {
        s_prefix = ((unsigned long long)(unsigned)P16) << 48;
        s_rr = r;
        s_done = 0;
    }
    __syncthreads();

    // ---- Step C: radix over remaining 48 bits ----
    if (c <= TK_CAP) {
        for (int shift = 40; shift >= 0; shift -= 8) {
            if (s_done) break;
            for (int i = t; i < 256; i += 1024) hist[i] = 0u;
            __syncthreads();
            unsigned long long prefix = s_prefix;
            int hs = shift + 8;
            for (int i = t; i < c; i += 1024) {
                unsigned long long key = cand[i];
                if ((key >> hs) == (prefix >> hs))
                    atomicAdd(&hist[(unsigned)((key >> shift) & 255ULL)], 1u);
            }
            __syncthreads();
            if (t == 0) {
                int rr = s_rr;
                unsigned long long pfx = s_prefix;
                for (int d = 255; d >= 0; --d) {
                    int cb = (int)hist[d];
                    if (rr <= cb) {
                        pfx |= ((unsigned long long)d) << shift;
                        if (rr == cb) s_done = 1;
                        break;
                    }
                    rr -= cb;
                }
                s_prefix = pfx;
                s_rr = rr;
            }
            __syncthreads();
        }
    } else {
        // fallback (pathological tie mass): radix over global data, P16 known
        for (int shift = 40; shift >= 0; shift -= 8) {
            if (s_done) break;
            for (int i = t; i < 256; i += 1024) hist[i] = 0u;
            __syncthreads();
            unsigned long long prefix = s_prefix;
            int hs = shift + 8;
            for (int i = t; i < n; i += 1024) {
                unsigned long long key = key64_of(sc[i], i);
                if ((key >> hs) == (prefix >> hs))
                    atomicAdd(&hist[(unsigned)((key >> shift) & 255ULL)], 1u);
            }
            __syncthreads();
            if (t == 0) {
                int rr = s_rr;
                unsigned long long pfx = s_prefix;
                for (int d = 255; d >= 0; --d) {
                    int cb = (int)hist[d];
                    if (rr <= cb) {
                        pfx |= ((unsigned long long)d) << shift;
                        if (rr == cb) s_done = 1;
                        break;
                    }
                    rr -= cb;
                }
                s_prefix = pfx;
                s_rr = rr;
            }
            __syncthreads();
        }
    }
    __syncthreads();
    if (t == 0) { T64[b] = s_prefix; cnt[b] = 0; }
    // zero this graph's hist bins for the next layer's k_mm
    for (int i = t; i < 65536; i += 1024) gh[i] = 0u;
}

// phase A: keep flag -> new index via wave-aggregated block atomic; score := tanh(score) for kept
__global__ void k_select_idx(float* __restrict__ score,
                             const unsigned long long* __restrict__ T64, int* __restrict__ cnt,
                             int* __restrict__ remap, int n, int k) {
    int b = blockIdx.y;
    int i = blockIdx.x * 256 + threadIdx.x;
    int m = b * n + i;
    bool keep = false;
    float s = 0.f;
    if (i < n) {
        s = score[m];
        keep = key64_of(s, i) >= T64[b];
    }
    unsigned long long mask = __ballot(keep);
    int lane = threadIdx.x & 63;
    int wv = threadIdx.x >> 6;
    int lp = __popcll(mask & ((1ULL << lane) - 1ULL));
    __shared__ int woff[4];
    __shared__ int blockBase;
    if (lane == 0) woff[wv] = __popcll(mask);
    __syncthreads();
    if (threadIdx.x == 0) {
        int t0 = woff[0], t1 = woff[1], t2 = woff[2], t3 = woff[3];
        woff[0] = 0; woff[1] = t0; woff[2] = t0 + t1; woff[3] = t0 + t1 + t2;
        blockBase = atomicAdd(&cnt[b], t0 + t1 + t2 + t3);
    }
    __syncthreads();
    if (i < n) {
        if (keep) {
            remap[m] = b * k + blockBase + woff[wv] + lp;
            score[m] = tanhf(s);
        } else {
            remap[m] = -1;
        }
    }
}

// phase B: coalesced float4 row copy, xout[remap[m]] = y[m] * score[m] (score holds tanh)
__global__ void k_select_copy(const float* __restrict__ y, const float* __restrict__ score,
                              const int* __restrict__ remap, float* __restrict__ xout,
                              int M, int Fo4) {
    int t = blockIdx.x * blockDim.x + threadIdx.x;
    if (t >= M * Fo4) return;
    int m = t / Fo4, c = t - m * Fo4;
    int ni = remap[m];
    if (ni < 0) return;
    float4 v = ((const float4*)y)[(size_t)m * Fo4 + c];
    float s = score[m];
    float4 o; o.x = v.x * s; o.y = v.y * s; o.z = v.z * s; o.w = v.w * s;
    ((float4*)xout)[(size_t)ni * Fo4 + c] = o;
}

// stage 1 of final pooling: grid (PCHUNKS, NB), block 128.
__global__ void k_pool_partial(const float* __restrict__ x, float* __restrict__ pmax,
                               float* __restrict__ psum, int K3, int chunk) {
    int b = blockIdx.y, c = blockIdx.x, f = threadIdx.x;
    int i0 = c * chunk;
    int i1 = min(K3, i0 + chunk);
    const float* xb = x + (size_t)b * K3 * 128;
    float mx = -FLT_MAX, sm = 0.f;
    for (int i = i0; i < i1; ++i) {
        float v = xb[(size_t)i * 128 + f];
        mx = fmaxf(mx, v);
        sm += v;
    }
    int o = (b * PCHUNKS + c) * 128 + f;
    pmax[o] = mx;
    psum[o] = sm;
}

// stage 2: one block (128 threads) per graph: combine partials + metadata conv + fc + fc2
__global__ void k_final2(const float* __restrict__ pmax, const float* __restrict__ psum,
                         const float* __restrict__ metadata,
                         const float* __restrict__ convm_w, const float* __restrict__ convm_b,
                         const float* __restrict__ fc_w, const float* __restrict__ fc_b,
                         const float* __restrict__ fc2_w, const float* __restrict__ fc2_b,
                         float* __restrict__ out, int K3) {
    int b = blockIdx.x;
    int f = threadIdx.x;   // 0..127
    __shared__ float xc[260];
    __shared__ float red[128];
    float mx = -FLT_MAX, sm = 0.f;
    for (int c = 0; c < PCHUNKS; ++c) {
        int o = (b * PCHUNKS + c) * 128 + f;
        mx = fmaxf(mx, pmax[o]);
        sm += psum[o];
    }
    xc[f] = mx;
    xc[128 + f] = sm / (float)K3;
    if (f < 4) {
        float mv = metadata[b] * convm_w[f] + convm_b[f];
        xc[256 + f] = mv > 0.f ? mv : 0.f;
    }
    __syncthreads();
    float acc = fc_b[f];
    for (int i = 0; i < 260; ++i) acc = fmaf(xc[i], fc_w[i * 128 + f], acc);
    acc = acc > 0.f ? acc : 0.f;
    red[f] = acc * fc2_w[f];
    __syncthreads();
    for (int s2 = 64; s2 > 0; s2 >>= 1) {
        if (f < s2) red[f] += red[f + s2];
        __syncthreads();
    }
    if (f == 0) out[b] = red[0] + fc2_b[0];
}

// ---------------- launch ----------------

extern "C" void kernel_launch(void* const* d_in, const int* in_sizes, int n_in,
                              void* d_out, int out_size, void* d_ws, size_t ws_size,
                              hipStream_t stream) {
    const float* x0       = (const float*)d_in[0];
    const int*   ei       = (const int*)d_in[1];
    const float* metadata = (const float*)d_in[2];
    const float* W[4]  = {(const float*)d_in[3], (const float*)d_in[6],
                          (const float*)d_in[9], (const float*)d_in[12]};
    const float* bs[4] = {(const float*)d_in[4], (const float*)d_in[7],
                          (const float*)d_in[10], (const float*)d_in[13]};
    const float* pv[4] = {(const float*)d_in[5], (const float*)d_in[8],
                          (const float*)d_in[11], (const float*)d_in[14]};
    const float* convm_w = (const float*)d_in[15];
    const float* convm_b = (const float*)d_in[16];
    const float* fc_w    = (const float*)d_in[17];
    const float* fc_b    = (const float*)d_in[18];
    const float* fc2_w   = (const float*)d_in[19];
    const float* fc2_b   = (const float*)d_in[20];

    // workspace bump allocation
    const size_t HMAX = 5243392;
    const size_t XMAX = 2621952;
    const size_t MMAX = NB * (size_t)N0;   // 163848

    char* p = (char*)d_ws;
    size_t off = 0;
    auto alloc = [&](size_t bytes) -> char* {
        char* r = p + off;
        off = (off + bytes + 255) & ~(size_t)255;
        return r;
    };
    float* ax    = (float*)alloc(HMAX * 4);
    float* y     = (float*)alloc(HMAX * 4);
    float* xb0   = (float*)alloc(XMAX * 4);
    float* xb1   = (float*)alloc(XMAX * 4);
    float* dinv  = (float*)alloc(MMAX * 4);
    float* score = (float*)alloc(MMAX * 4);
    int*   remap = (int*)alloc(MMAX * 4);
    int*   degi  = (int*)alloc(MMAX * 4);
    int*   rowptr= (int*)alloc((MMAX + 1) * 4);
    int*   cursor= (int*)alloc(MMAX * 4);
    int*   col   = (int*)alloc(E0 * 4);
    int*   bsum  = (int*)alloc(260 * 4);
    int*   esrc  = (int*)alloc(E0 * 4);
    int*   edst  = (int*)alloc(E0 * 4);
    float* ew    = (float*)alloc(E0 * 4);
    float* pmax  = (float*)alloc(NB * PCHUNKS * 128 * 4);
    float* psum  = (float*)alloc(NB * PCHUNKS * 128 * 4);
    unsigned int* ghist = (unsigned int*)alloc(NB * 65536 * 4);
    unsigned long long* T64 = (unsigned long long*)alloc(NB * 8);
    int*   cnt   = (int*)alloc(NB * 4);
    (void)ws_size; (void)n_in; (void)in_sizes; (void)out_size;

    const int Fo[4] = {32, 64, 128, 128};
    const int Kk[4] = {20481, 10241, 5121, 2561};

    const int TB = 256;
    const int EG = (E0 + TB - 1) / TB;

    hipMemsetAsync(ghist, 0, (size_t)NB * 65536 * 4, stream);
    hipMemsetAsync(degi, 0, MMAX * 4, stream);
    k_edges_init_count<<<EG, TB, 0, stream>>>(ei, esrc, edst, ew, degi);

    int M = NB * N0;
    const float* xin = x0;
    float* xbufs[2] = {xb0, xb1};

    for (int L = 0; L < 4; ++L) {
        int fo = Fo[L];
        int n = M / NB, kk = Kk[L];

        // ---- CSR build (degi already counted) ----
        int nb = (M + 1023) / 1024;
        k_scan1<<<nb, 256, 0, stream>>>(degi, rowptr, bsum, M);
        k_scan2<<<1, 256, 0, stream>>>(bsum, nb);
        k_scan3<<<(M + 255) / 256, 256, 0, stream>>>(rowptr, bsum, cursor, degi, dinv, M, nb);
        k_csr_fill<<<EG, TB, 0, stream>>>(esrc, edst, ew, cursor, col);

        // ---- aggregate input features (linear, so agg before matmul) ----
        if (L == 0) {
            k_gather_x4<<<(M + TB - 1) / TB, TB, 0, stream>>>(xin, rowptr, col, dinv, ax, M);
        } else if (L == 1) {
            int rpb = 8;
            k_gather_x<32><<<(M + rpb - 1) / rpb, 256, 0, stream>>>(xin, rowptr, col, dinv, ax, M);
        } else if (L == 2) {
            int rpb = 4;
            k_gather_x<64><<<(M + rpb - 1) / rpb, 256, 0, stream>>>(xin, rowptr, col, dinv, ax, M);
        } else {
            int rpb = 4;
            k_gather_x<128><<<(M + rpb - 1) / rpb, 256, 0, stream>>>(xin, rowptr, col, dinv, ax, M);
        }

        // ---- fused matmul + bias + relu + score + coarse hist ----
        if (L == 0) {
            int nt = (M / 2) * 8;
            k_mm<4, 32><<<(nt + 255) / 256, 256, 0, stream>>>(ax, W[L], bs[L], pv[L], y, score, ghist, M, n);
        } else if (L == 1) {
            int nt = (M / 2) * 16;
            k_mm<32, 64><<<(nt + 255) / 256, 256, 0, stream>>>(ax, W[L], bs[L], pv[L], y, score, ghist, M, n);
        } else if (L == 2) {
            int nt = (M / 2) * 32;
            k_mm<64, 128><<<(nt + 255) / 256, 256, 0, stream>>>(ax, W[L], bs[L], pv[L], y, score, ghist, M, n);
        } else {
            int nt = (M / 2) * 32;
            k_mm<128, 128><<<(nt + 255) / 256, 256, 0, stream>>>(ax, W[L], bs[L], pv[L], y, score, ghist, M, n);
        }

        // ---- top-k pooling ----
        k_topk_fine<<<NB, 1024, 0, stream>>>(score, ghist, T64, cnt, n, kk);
        dim3 gsel((n + 255) / 256, NB);
        k_select_idx<<<gsel, 256, 0, stream>>>(score, T64, cnt, remap, n, kk);
        float* xout = xbufs[L & 1];
        int ctot = M * (fo / 4);
        k_select_copy<<<(ctot + TB - 1) / TB, TB, 0, stream>>>(y, score, remap, xout,
                                                               M, fo / 4);
        if (L < 3) {
            hipMemsetAsync(degi, 0, (size_t)NB * kk * 4, stream);
            k_edge_remap_count<<<EG, TB, 0, stream>>>(esrc, edst, ew, remap, degi);
        }

        M = NB * kk;
        xin = xout;
    }

    int K3 = Kk[3];
    int chunk = (K3 + PCHUNKS - 1) / PCHUNKS;
    dim3 gpool(PCHUNKS, NB);
    k_pool_partial<<<gpool, 128, 0, stream>>>(xin, pmax, psum, K3, chunk);
    k_final2<<<NB, 128, 0, stream>>>(pmax, psum, metadata, convm_w, convm_b,
                                     fc_w, fc_b, fc2_w, fc2_b, (float*)d_out, K3);
}

// Round 8
// 711.420 us; speedup vs baseline: 2.4570x; 1.0323x over previous
//
#include <hip/hip_runtime.h>
#include <float.h>
#include <math.h>

#define NB 4            // graphs per batch
#define N0 40962        // nodes per graph at input
#define E0 983088       // total directed edges (fixed across layers; dead edges have w=0)
#define PCHUNKS 40      // stage-1 pooling blocks per graph
#define TK_CAP 6144     // candidate capacity for fine top-k select (48 KB LDS)

// ---------------- helpers ----------------

static __device__ __forceinline__ unsigned key32_of(float s) {
    unsigned u = __float_as_uint(s);
    return (u & 0x80000000u) ? ~u : (u | 0x80000000u);
}

static __device__ __forceinline__ unsigned long long key64_of(float s, int li) {
    unsigned u = key32_of(s);
    unsigned low = ~(unsigned)li;   // ties broken by smaller local index
    return ((unsigned long long)u << 32) | (unsigned long long)low;
}

static __device__ __forceinline__ float4 fma4(float s, float4 w, float4 a) {
    a.x = fmaf(s, w.x, a.x); a.y = fmaf(s, w.y, a.y);
    a.z = fmaf(s, w.z, a.z); a.w = fmaf(s, w.w, a.w);
    return a;
}

// ---------------- kernels ----------------

// L0: copy edge list + count in-degrees (degi pre-zeroed)
__global__ void k_edges_init_count(const int* __restrict__ ei, int* __restrict__ esrc,
                                   int* __restrict__ edst, float* __restrict__ ew,
                                   int* __restrict__ degi) {
    int e = blockIdx.x * blockDim.x + threadIdx.x;
    if (e >= E0) return;
    int s = ei[e], d = ei[E0 + e];
    esrc[e] = s;
    edst[e] = d;
    ew[e] = 1.0f;
    atomicAdd(&degi[d], 1);
}

// layer end: remap surviving edges to new ids AND count next layer's in-degrees
__global__ void k_edge_remap_count(int* __restrict__ esrc, int* __restrict__ edst,
                                   float* __restrict__ ew, const int* __restrict__ remap,
                                   int* __restrict__ degi) {
    int e = blockIdx.x * blockDim.x + threadIdx.x;
    if (e >= E0) return;
    float w = ew[e];
    if (w != 0.f) {
        int ns = remap[esrc[e]];
        int nd = remap[edst[e]];
        if (ns >= 0 && nd >= 0) {
            esrc[e] = ns; edst[e] = nd;
            atomicAdd(&degi[nd], 1);
            return;
        }
    }
    esrc[e] = 0; edst[e] = 0; ew[e] = 0.f;
}

// exclusive scan, stage 1: 1024 elements per block (256 threads x 4)
__global__ void k_scan1(const int* __restrict__ in, int* __restrict__ out,
                        int* __restrict__ bsum, int M) {
    __shared__ int s[256];
    int t = threadIdx.x;
    int base = blockIdx.x * 1024 + t * 4;
    int d0 = (base + 0 < M) ? in[base + 0] : 0;
    int d1 = (base + 1 < M) ? in[base + 1] : 0;
    int d2 = (base + 2 < M) ? in[base + 2] : 0;
    int d3 = (base + 3 < M) ? in[base + 3] : 0;
    int tsum = d0 + d1 + d2 + d3;
    s[t] = tsum;
    __syncthreads();
    for (int off = 1; off < 256; off <<= 1) {
        int v = (t >= off) ? s[t - off] : 0;
        __syncthreads();
        s[t] += v;
        __syncthreads();
    }
    int texcl = s[t] - tsum;
    if (base + 0 < M) out[base + 0] = texcl;
    if (base + 1 < M) out[base + 1] = texcl + d0;
    if (base + 2 < M) out[base + 2] = texcl + d0 + d1;
    if (base + 3 < M) out[base + 3] = texcl + d0 + d1 + d2;
    if (t == 255) bsum[blockIdx.x] = s[255];
}

// stage 2: single block exclusive scan of block sums (nb <= 256); bsum[nb] = total
__global__ void k_scan2(int* __restrict__ bsum, int nb) {
    __shared__ int s[256];
    int t = threadIdx.x;
    int v = (t < nb) ? bsum[t] : 0;
    s[t] = v;
    __syncthreads();
    for (int off = 1; off < 256; off <<= 1) {
        int u = (t >= off) ? s[t - off] : 0;
        __syncthreads();
        s[t] += u;
        __syncthreads();
    }
    if (t < nb) bsum[t] = s[t] - v;
    if (t == 255) bsum[nb] = s[255];
}

// stage 3: add block offsets; init cursor; write rowptr[M]; dinv = rsqrt(deg+1)
__global__ void k_scan3(int* __restrict__ rowptr, const int* __restrict__ bsum,
                        int* __restrict__ cursor, const int* __restrict__ degi,
                        float* __restrict__ dinv, int M, int nb) {
    int i = blockIdx.x * 256 + threadIdx.x;
    if (i < M) {
        int v = rowptr[i] + bsum[i >> 10];
        rowptr[i] = v;
        cursor[i] = v;
        dinv[i] = rsqrtf((float)degi[i] + 1.0f);
    }
    if (i == 0) rowptr[M] = bsum[nb];
}

// place live edges into CSR buckets (arbitrary order within bucket)
__global__ void k_csr_fill(const int* __restrict__ esrc, const int* __restrict__ edst,
                           const float* __restrict__ ew, int* __restrict__ cursor,
                           int* __restrict__ col) {
    int e = blockIdx.x * blockDim.x + threadIdx.x;
    if (e >= E0) return;
    if (ew[e] != 0.f) {
        int d = edst[e];
        int pos = atomicAdd(&cursor[d], 1);
        col[pos] = esrc[e];
    }
}

// aggregate input features (FI=4): one row per thread, float4 loads.
__global__ void k_gather_x4(const float* __restrict__ x, const int* __restrict__ rowptr,
                            const int* __restrict__ col, const float* __restrict__ dinv,
                            float* __restrict__ ax, int M) {
    int row = blockIdx.x * blockDim.x + threadIdx.x;
    if (row >= M) return;
    int rp0 = rowptr[row], rp1 = rowptr[row + 1];
    float dd = dinv[row];
    float invdeg = dd * dd;
    float4 xs = ((const float4*)x)[row];
    float4 acc;
    acc.x = xs.x * invdeg; acc.y = xs.y * invdeg;
    acc.z = xs.z * invdeg; acc.w = xs.w * invdeg;
    for (int j = rp0; j < rp1; ++j) {
        int s = col[j];
        float nrm = dd * dinv[s];
        float4 v = ((const float4*)x)[s];
        acc.x = fmaf(v.x, nrm, acc.x);
        acc.y = fmaf(v.y, nrm, acc.y);
        acc.z = fmaf(v.z, nrm, acc.z);
        acc.w = fmaf(v.w, nrm, acc.w);
    }
    ((float4*)ax)[row] = acc;
}

// aggregate input features (FI = 32/64/128): sub-wave per row, coalesced feature reads
template <int FI>
__global__ void k_gather_x(const float* __restrict__ x, const int* __restrict__ rowptr,
                           const int* __restrict__ col, const float* __restrict__ dinv,
                           float* __restrict__ ax, int M) {
    constexpr int LPR = (FI < 64) ? FI : 64;   // lanes per row
    constexpr int VPL = FI / LPR;              // floats per lane (1 or 2)
    constexpr int RPW = 64 / LPR;              // rows per wave
    int wave = (blockIdx.x * blockDim.x + threadIdx.x) >> 6;
    int lane = threadIdx.x & 63;
    int sub = lane / LPR;
    int f = lane % LPR;
    int row = wave * RPW + sub;
    if (row >= M) return;
    int rp0 = rowptr[row], rp1 = rowptr[row + 1];
    float dd = dinv[row];
    float invdeg = dd * dd;
    float acc[VPL];
#pragma unroll
    for (int v = 0; v < VPL; ++v)
        acc[v] = x[(size_t)row * FI + f * VPL + v] * invdeg;
    for (int j = rp0; j < rp1; ++j) {
        int s = col[j];
        float nrm = dd * dinv[s];
#pragma unroll
        for (int v = 0; v < VPL; ++v)
            acc[v] = fmaf(x[(size_t)s * FI + f * VPL + v], nrm, acc[v]);
    }
#pragma unroll
    for (int v = 0; v < VPL; ++v)
        ax[(size_t)row * FI + f * VPL + v] = acc[v];
}

// fused dense layer: y = relu(ax @ W + bias); score = dot(y, p)/|p|; ghist 16-bit digit count.
// 4 rows x 4 cols per thread (R7 was 2x4 and measured pure latency-bound: VALUBusy 4.4% ==
// required VALU cycles; doubling arithmetic per load-group halves the stall bill).
// Outer c-loop kept rolled (#pragma unroll 2) — full unroll spilled ~2.5 KB/thread (R5).
// All layer Ms are divisible by 4.
template <int FI, int FO>
__global__ void __launch_bounds__(256) k_mm(const float* __restrict__ ax,
                                            const float* __restrict__ W,
                                            const float* __restrict__ bias,
                                            const float* __restrict__ pvec,
                                            float* __restrict__ y,
                                            float* __restrict__ score,
                                            unsigned int* __restrict__ ghist,
                                            int M, int n) {
    constexpr int Q = FO / 4;   // 8 / 16 / 32 lanes per row-quad
    int t = blockIdx.x * blockDim.x + threadIdx.x;
    int g = t / Q;
    int q = t % Q;
    int row = g * 4;
    if (row >= M) return;
    const float4* x0 = (const float4*)(ax + (size_t)(row + 0) * FI);
    const float4* x1 = (const float4*)(ax + (size_t)(row + 1) * FI);
    const float4* x2 = (const float4*)(ax + (size_t)(row + 2) * FI);
    const float4* x3 = (const float4*)(ax + (size_t)(row + 3) * FI);
    const float4* W4 = (const float4*)W;
    float4 a0 = {0.f, 0.f, 0.f, 0.f}, a1 = {0.f, 0.f, 0.f, 0.f};
    float4 a2 = {0.f, 0.f, 0.f, 0.f}, a3 = {0.f, 0.f, 0.f, 0.f};
#pragma unroll 2
    for (int c = 0; c < FI / 4; ++c) {
        float4 v0 = x0[c], v1 = x1[c], v2 = x2[c], v3 = x3[c];
        const float4* wr = W4 + (size_t)(c * 4) * Q + q;
        float4 w;
        w = wr[0 * Q];
        a0 = fma4(v0.x, w, a0); a1 = fma4(v1.x, w, a1);
        a2 = fma4(v2.x, w, a2); a3 = fma4(v3.x, w, a3);
        w = wr[1 * Q];
        a0 = fma4(v0.y, w, a0); a1 = fma4(v1.y, w, a1);
        a2 = fma4(v2.y, w, a2); a3 = fma4(v3.y, w, a3);
        w = wr[2 * Q];
        a0 = fma4(v0.z, w, a0); a1 = fma4(v1.z, w, a1);
        a2 = fma4(v2.z, w, a2); a3 = fma4(v3.z, w, a3);
        w = wr[3 * Q];
        a0 = fma4(v0.w, w, a0); a1 = fma4(v1.w, w, a1);
        a2 = fma4(v2.w, w, a2); a3 = fma4(v3.w, w, a3);
    }
    float4 b4 = ((const float4*)bias)[q];
    float4 o0, o1, o2, o3;
    o0.x = fmaxf(a0.x + b4.x, 0.f); o0.y = fmaxf(a0.y + b4.y, 0.f);
    o0.z = fmaxf(a0.z + b4.z, 0.f); o0.w = fmaxf(a0.w + b4.w, 0.f);
    o1.x = fmaxf(a1.x + b4.x, 0.f); o1.y = fmaxf(a1.y + b4.y, 0.f);
    o1.z = fmaxf(a1.z + b4.z, 0.f); o1.w = fmaxf(a1.w + b4.w, 0.f);
    o2.x = fmaxf(a2.x + b4.x, 0.f); o2.y = fmaxf(a2.y + b4.y, 0.f);
    o2.z = fmaxf(a2.z + b4.z, 0.f); o2.w = fmaxf(a2.w + b4.w, 0.f);
    o3.x = fmaxf(a3.x + b4.x, 0.f); o3.y = fmaxf(a3.y + b4.y, 0.f);
    o3.z = fmaxf(a3.z + b4.z, 0.f); o3.w = fmaxf(a3.w + b4.w, 0.f);
    ((float4*)(y + (size_t)(row + 0) * FO))[q] = o0;
    ((float4*)(y + (size_t)(row + 1) * FO))[q] = o1;
    ((float4*)(y + (size_t)(row + 2) * FO))[q] = o2;
    ((float4*)(y + (size_t)(row + 3) * FO))[q] = o3;
    float4 p4 = ((const float4*)pvec)[q];
    float d0 = o0.x * p4.x + o0.y * p4.y + o0.z * p4.z + o0.w * p4.w;
    float d1 = o1.x * p4.x + o1.y * p4.y + o1.z * p4.z + o1.w * p4.w;
    float d2 = o2.x * p4.x + o2.y * p4.y + o2.z * p4.z + o2.w * p4.w;
    float d3 = o3.x * p4.x + o3.y * p4.y + o3.z * p4.z + o3.w * p4.w;
    float pn = p4.x * p4.x + p4.y * p4.y + p4.z * p4.z + p4.w * p4.w;
#pragma unroll
    for (int off = Q / 2; off > 0; off >>= 1) {
        d0 += __shfl_xor(d0, off, 64);
        d1 += __shfl_xor(d1, off, 64);
        d2 += __shfl_xor(d2, off, 64);
        d3 += __shfl_xor(d3, off, 64);
        pn += __shfl_xor(pn, off, 64);
    }
    if (q == 0) {
        float inv = rsqrtf(pn);
        float s0 = d0 * inv, s1 = d1 * inv, s2 = d2 * inv, s3 = d3 * inv;
        score[row + 0] = s0;
        score[row + 1] = s1;
        score[row + 2] = s2;
        score[row + 3] = s3;
        atomicAdd(&ghist[((size_t)((row + 0) / n) << 16) | (key32_of(s0) >> 16)], 1u);
        atomicAdd(&ghist[((size_t)((row + 1) / n) << 16) | (key32_of(s1) >> 16)], 1u);
        atomicAdd(&ghist[((size_t)((row + 2) / n) << 16) | (key32_of(s2) >> 16)], 1u);
        atomicAdd(&ghist[((size_t)((row + 3) / n) << 16) | (key32_of(s3) >> 16)], 1u);
    }
}

// one block (1024 threads) per graph: exact k-th largest key64 from the 16-bit coarse
// histogram + one filtered candidate pass + in-LDS radix on the remaining 48 bits.
// Zeroes ghist for the next layer; zeroes cnt for select_idx.
__global__ void __launch_bounds__(1024) k_topk_fine(
        const float* __restrict__ score, unsigned int* __restrict__ ghist,
        unsigned long long* __restrict__ T64, int* __restrict__ cnt, int n, int k) {
    int b = blockIdx.x;
    int t = threadIdx.x;
    const float* sc = score + (size_t)b * n;
    unsigned int* gh = ghist + ((size_t)b << 16);
    __shared__ int chunkSum[1024];
    __shared__ int chunkScan[1024];
    __shared__ unsigned long long cand[TK_CAP];
    __shared__ unsigned int hist[256];
    __shared__ int s_P16, s_r, s_c, s_rr, s_done, s_cc;
    __shared__ unsigned long long s_prefix;

    // ---- Step A: coarse pick from 65536-bin hist (descending) ----
    {
        int base = t << 6;   // thread t sums bins [64t .. 64t+63]
        int sum = 0;
        for (int j = 0; j < 64; ++j) sum += (int)gh[base + j];
        chunkSum[t] = sum;
        chunkScan[t] = sum;
    }
    __syncthreads();
    // suffix (from-top) inclusive scan: chunkScan[t] = sum of chunks t..1023
    for (int off = 1; off < 1024; off <<= 1) {
        int v = (t + off < 1024) ? chunkScan[t + off] : 0;
        __syncthreads();
        chunkScan[t] += v;
        __syncthreads();
    }
    {
        int cumAbove = chunkScan[t] - chunkSum[t];   // sum of chunks strictly above t
        if (cumAbove < k && chunkScan[t] >= k) {     // threshold lies in chunk t
            int cum = cumAbove;
            int base = t << 6;
            for (int j = 63; j >= 0; --j) {          // bins descending within chunk
                int cb = (int)gh[base + j];
                cum += cb;
                if (cum >= k) {
                    s_P16 = base + j;
                    s_r = k - (cum - cb);   // 1-based rank within bucket
                    s_c = cb;
                    break;
                }
            }
        }
    }
    if (t == 0) s_cc = 0;
    __syncthreads();
    int P16 = s_P16, r = s_r, c = s_c;

    // ---- Step B: collect bucket candidates into LDS ----
    if (c <= TK_CAP) {
        for (int i = t; i < n; i += 1024) {
            unsigned u = key32_of(sc[i]);
            if ((int)(u >> 16) == P16) {
                int pos = atomicAdd(&s_cc, 1);
                cand[pos] = ((unsigned long long)u << 32) |
                            (unsigned long long)(~(unsigned)i);
            }
        }
    }
    if (t == 0) {
        s_prefix = ((unsigned long long)(unsigned)P16) << 48;
        s_rr = r;
        s_done = 0;
    }
    __syncthreads();

    // ---- Step C: radix over remaining 48 bits ----
    if (c <= TK_CAP) {
        for (int shift = 40; shift >= 0; shift -= 8) {
            if (s_done) break;
            for (int i = t; i < 256; i += 1024) hist[i] = 0u;
            __syncthreads();
            unsigned long long prefix = s_prefix;
            int hs = shift + 8;
            for (int i = t; i < c; i += 1024) {
                unsigned long long key = cand[i];
                if ((key >> hs) == (prefix >> hs))
                    atomicAdd(&hist[(unsigned)((key >> shift) & 255ULL)], 1u);
            }
            __syncthreads();
            if (t == 0) {
                int rr = s_rr;
                unsigned long long pfx = s_prefix;
                for (int d = 255; d >= 0; --d) {
                    int cb = (int)hist[d];
                    if (rr <= cb) {
                        pfx |= ((unsigned long long)d) << shift;
                        if (rr == cb) s_done = 1;
                        break;
                    }
                    rr -= cb;
                }
                s_prefix = pfx;
                s_rr = rr;
            }
            __syncthreads();
        }
    } else {
        // fallback (pathological tie mass): radix over global data, P16 known
        for (int shift = 40; shift >= 0; shift -= 8) {
            if (s_done) break;
            for (int i = t; i < 256; i += 1024) hist[i] = 0u;
            __syncthreads();
            unsigned long long prefix = s_prefix;
            int hs = shift + 8;
            for (int i = t; i < n; i += 1024) {
                unsigned long long key = key64_of(sc[i], i);
                if ((key >> hs) == (prefix >> hs))
                    atomicAdd(&hist[(unsigned)((key >> shift) & 255ULL)], 1u);
            }
            __syncthreads();
            if (t == 0) {
                int rr = s_rr;
                unsigned long long pfx = s_prefix;
                for (int d = 255; d >= 0; --d) {
                    int cb = (int)hist[d];
                    if (rr <= cb) {
                        pfx |= ((unsigned long long)d) << shift;
                        if (rr == cb) s_done = 1;
                        break;
                    }
                    rr -= cb;
                }
                s_prefix = pfx;
                s_rr = rr;
            }
            __syncthreads();
        }
    }
    __syncthreads();
    if (t == 0) { T64[b] = s_prefix; cnt[b] = 0; }
    // zero this graph's hist bins for the next layer's k_mm
    for (int i = t; i < 65536; i += 1024) gh[i] = 0u;
}

// phase A: keep flag -> new index via wave-aggregated block atomic; score := tanh(score) for kept
__global__ void k_select_idx(float* __restrict__ score,
                             const unsigned long long* __restrict__ T64, int* __restrict__ cnt,
                             int* __restrict__ remap, int n, int k) {
    int b = blockIdx.y;
    int i = blockIdx.x * 256 + threadIdx.x;
    int m = b * n + i;
    bool keep = false;
    float s = 0.f;
    if (i < n) {
        s = score[m];
        keep = key64_of(s, i) >= T64[b];
    }
    unsigned long long mask = __ballot(keep);
    int lane = threadIdx.x & 63;
    int wv = threadIdx.x >> 6;
    int lp = __popcll(mask & ((1ULL << lane) - 1ULL));
    __shared__ int woff[4];
    __shared__ int blockBase;
    if (lane == 0) woff[wv] = __popcll(mask);
    __syncthreads();
    if (threadIdx.x == 0) {
        int t0 = woff[0], t1 = woff[1], t2 = woff[2], t3 = woff[3];
        woff[0] = 0; woff[1] = t0; woff[2] = t0 + t1; woff[3] = t0 + t1 + t2;
        blockBase = atomicAdd(&cnt[b], t0 + t1 + t2 + t3);
    }
    __syncthreads();
    if (i < n) {
        if (keep) {
            remap[m] = b * k + blockBase + woff[wv] + lp;
            score[m] = tanhf(s);
        } else {
            remap[m] = -1;
        }
    }
}

// phase B: coalesced float4 row copy, xout[remap[m]] = y[m] * score[m] (score holds tanh)
__global__ void k_select_copy(const float* __restrict__ y, const float* __restrict__ score,
                              const int* __restrict__ remap, float* __restrict__ xout,
                              int M, int Fo4) {
    int t = blockIdx.x * blockDim.x + threadIdx.x;
    if (t >= M * Fo4) return;
    int m = t / Fo4, c = t - m * Fo4;
    int ni = remap[m];
    if (ni < 0) return;
    float4 v = ((const float4*)y)[(size_t)m * Fo4 + c];
    float s = score[m];
    float4 o; o.x = v.x * s; o.y = v.y * s; o.z = v.z * s; o.w = v.w * s;
    ((float4*)xout)[(size_t)ni * Fo4 + c] = o;
}

// stage 1 of final pooling: grid (PCHUNKS, NB), block 128.
__global__ void k_pool_partial(const float* __restrict__ x, float* __restrict__ pmax,
                               float* __restrict__ psum, int K3, int chunk) {
    int b = blockIdx.y, c = blockIdx.x, f = threadIdx.x;
    int i0 = c * chunk;
    int i1 = min(K3, i0 + chunk);
    const float* xb = x + (size_t)b * K3 * 128;
    float mx = -FLT_MAX, sm = 0.f;
    for (int i = i0; i < i1; ++i) {
        float v = xb[(size_t)i * 128 + f];
        mx = fmaxf(mx, v);
        sm += v;
    }
    int o = (b * PCHUNKS + c) * 128 + f;
    pmax[o] = mx;
    psum[o] = sm;
}

// stage 2: one block (128 threads) per graph: combine partials + metadata conv + fc + fc2
__global__ void k_final2(const float* __restrict__ pmax, const float* __restrict__ psum,
                         const float* __restrict__ metadata,
                         const float* __restrict__ convm_w, const float* __restrict__ convm_b,
                         const float* __restrict__ fc_w, const float* __restrict__ fc_b,
                         const float* __restrict__ fc2_w, const float* __restrict__ fc2_b,
                         float* __restrict__ out, int K3) {
    int b = blockIdx.x;
    int f = threadIdx.x;   // 0..127
    __shared__ float xc[260];
    __shared__ float red[128];
    float mx = -FLT_MAX, sm = 0.f;
    for (int c = 0; c < PCHUNKS; ++c) {
        int o = (b * PCHUNKS + c) * 128 + f;
        mx = fmaxf(mx, pmax[o]);
        sm += psum[o];
    }
    xc[f] = mx;
    xc[128 + f] = sm / (float)K3;
    if (f < 4) {
        float mv = metadata[b] * convm_w[f] + convm_b[f];
        xc[256 + f] = mv > 0.f ? mv : 0.f;
    }
    __syncthreads();
    float acc = fc_b[f];
    for (int i = 0; i < 260; ++i) acc = fmaf(xc[i], fc_w[i * 128 + f], acc);
    acc = acc > 0.f ? acc : 0.f;
    red[f] = acc * fc2_w[f];
    __syncthreads();
    for (int s2 = 64; s2 > 0; s2 >>= 1) {
        if (f < s2) red[f] += red[f + s2];
        __syncthreads();
    }
    if (f == 0) out[b] = red[0] + fc2_b[0];
}

// ---------------- launch ----------------

extern "C" void kernel_launch(void* const* d_in, const int* in_sizes, int n_in,
                              void* d_out, int out_size, void* d_ws, size_t ws_size,
                              hipStream_t stream) {
    const float* x0       = (const float*)d_in[0];
    const int*   ei       = (const int*)d_in[1];
    const float* metadata = (const float*)d_in[2];
    const float* W[4]  = {(const float*)d_in[3], (const float*)d_in[6],
                          (const float*)d_in[9], (const float*)d_in[12]};
    const float* bs[4] = {(const float*)d_in[4], (const float*)d_in[7],
                          (const float*)d_in[10], (const float*)d_in[13]};
    const float* pv[4] = {(const float*)d_in[5], (const float*)d_in[8],
                          (const float*)d_in[11], (const float*)d_in[14]};
    const float* convm_w = (const float*)d_in[15];
    const float* convm_b = (const float*)d_in[16];
    const float* fc_w    = (const float*)d_in[17];
    const float* fc_b    = (const float*)d_in[18];
    const float* fc2_w   = (const float*)d_in[19];
    const float* fc2_b   = (const float*)d_in[20];

    // workspace bump allocation
    const size_t HMAX = 5243392;
    const size_t XMAX = 2621952;
    const size_t MMAX = NB * (size_t)N0;   // 163848

    char* p = (char*)d_ws;
    size_t off = 0;
    auto alloc = [&](size_t bytes) -> char* {
        char* r = p + off;
        off = (off + bytes + 255) & ~(size_t)255;
        return r;
    };
    float* ax    = (float*)alloc(HMAX * 4);
    float* y     = (float*)alloc(HMAX * 4);
    float* xb0   = (float*)alloc(XMAX * 4);
    float* xb1   = (float*)alloc(XMAX * 4);
    float* dinv  = (float*)alloc(MMAX * 4);
    float* score = (float*)alloc(MMAX * 4);
    int*   remap = (int*)alloc(MMAX * 4);
    int*   degi  = (int*)alloc(MMAX * 4);
    int*   rowptr= (int*)alloc((MMAX + 1) * 4);
    int*   cursor= (int*)alloc(MMAX * 4);
    int*   col   = (int*)alloc(E0 * 4);
    int*   bsum  = (int*)alloc(260 * 4);
    int*   esrc  = (int*)alloc(E0 * 4);
    int*   edst  = (int*)alloc(E0 * 4);
    float* ew    = (float*)alloc(E0 * 4);
    float* pmax  = (float*)alloc(NB * PCHUNKS * 128 * 4);
    float* psum  = (float*)alloc(NB * PCHUNKS * 128 * 4);
    unsigned int* ghist = (unsigned int*)alloc(NB * 65536 * 4);
    unsigned long long* T64 = (unsigned long long*)alloc(NB * 8);
    int*   cnt   = (int*)alloc(NB * 4);
    (void)ws_size; (void)n_in; (void)in_sizes; (void)out_size;

    const int Fo[4] = {32, 64, 128, 128};
    const int Kk[4] = {20481, 10241, 5121, 2561};

    const int TB = 256;
    const int EG = (E0 + TB - 1) / TB;

    hipMemsetAsync(ghist, 0, (size_t)NB * 65536 * 4, stream);
    hipMemsetAsync(degi, 0, MMAX * 4, stream);
    k_edges_init_count<<<EG, TB, 0, stream>>>(ei, esrc, edst, ew, degi);

    int M = NB * N0;
    const float* xin = x0;
    float* xbufs[2] = {xb0, xb1};

    for (int L = 0; L < 4; ++L) {
        int fo = Fo[L];
        int n = M / NB, kk = Kk[L];

        // ---- CSR build (degi already counted) ----
        int nb = (M + 1023) / 1024;
        k_scan1<<<nb, 256, 0, stream>>>(degi, rowptr, bsum, M);
        k_scan2<<<1, 256, 0, stream>>>(bsum, nb);
        k_scan3<<<(M + 255) / 256, 256, 0, stream>>>(rowptr, bsum, cursor, degi, dinv, M, nb);
        k_csr_fill<<<EG, TB, 0, stream>>>(esrc, edst, ew, cursor, col);

        // ---- aggregate input features (linear, so agg before matmul) ----
        if (L == 0) {
            k_gather_x4<<<(M + TB - 1) / TB, TB, 0, stream>>>(xin, rowptr, col, dinv, ax, M);
        } else if (L == 1) {
            int rpb = 8;
            k_gather_x<32><<<(M + rpb - 1) / rpb, 256, 0, stream>>>(xin, rowptr, col, dinv, ax, M);
        } else if (L == 2) {
            int rpb = 4;
            k_gather_x<64><<<(M + rpb - 1) / rpb, 256, 0, stream>>>(xin, rowptr, col, dinv, ax, M);
        } else {
            int rpb = 4;
            k_gather_x<128><<<(M + rpb - 1) / rpb, 256, 0, stream>>>(xin, rowptr, col, dinv, ax, M);
        }

        // ---- fused matmul + bias + relu + score + coarse hist ----
        // threads = (M/4) * (FO/4); M divisible by 4 at every layer
        if (L == 0) {
            int nt = (M / 4) * 8;
            k_mm<4, 32><<<(nt + 255) / 256, 256, 0, stream>>>(ax, W[L], bs[L], pv[L], y, score, ghist, M, n);
        } else if (L == 1) {
            int nt = (M / 4) * 16;
            k_mm<32, 64><<<(nt + 255) / 256, 256, 0, stream>>>(ax, W[L], bs[L], pv[L], y, score, ghist, M, n);
        } else if (L == 2) {
            int nt = (M / 4) * 32;
            k_mm<64, 128><<<(nt + 255) / 256, 256, 0, stream>>>(ax, W[L], bs[L], pv[L], y, score, ghist, M, n);
        } else {
            int nt = (M / 4) * 32;
            k_mm<128, 128><<<(nt + 255) / 256, 256, 0, stream>>>(ax, W[L], bs[L], pv[L], y, score, ghist, M, n);
        }

        // ---- top-k pooling ----
        k_topk_fine<<<NB, 1024, 0, stream>>>(score, ghist, T64, cnt, n, kk);
        dim3 gsel((n + 255) / 256, NB);
        k_select_idx<<<gsel, 256, 0, stream>>>(score, T64, cnt, remap, n, kk);
        float* xout = xbufs[L & 1];
        int ctot = M * (fo / 4);
        k_select_copy<<<(ctot + TB - 1) / TB, TB, 0, stream>>>(y, score, remap, xout,
                                                               M, fo / 4);
        if (L < 3) {
            hipMemsetAsync(degi, 0, (size_t)NB * kk * 4, stream);
            k_edge_remap_count<<<EG, TB, 0, stream>>>(esrc, edst, ew, remap, degi);
        }

        M = NB * kk;
        xin = xout;
    }

    int K3 = Kk[3];
    int chunk = (K3 + PCHUNKS - 1) / PCHUNKS;
    dim3 gpool(PCHUNKS, NB);
    k_pool_partial<<<gpool, 128, 0, stream>>>(xin, pmax, psum, K3, chunk);
    k_final2<<<NB, 128, 0, stream>>>(pmax, psum, metadata, convm_w, convm_b,
                                     fc_w, fc_b, fc2_w, fc2_b, (float*)d_out, K3);
}

// Round 9
// 646.278 us; speedup vs baseline: 2.7046x; 1.1008x over previous
//
#include <hip/hip_runtime.h>
#include <float.h>
#include <math.h>

#define NB 4            // graphs per batch
#define N0 40962        // nodes per graph at input
#define E0 983088       // total directed edges (fixed across layers; dead edges have w=0)
#define PCHUNKS 40      // stage-1 pooling blocks per graph
#define TK_CAP 6144     // candidate capacity for fine top-k select (48 KB LDS)
#define HBITS 12        // coarse histogram bits (4096 bins; LDS-privatized)

// ---------------- helpers ----------------

static __device__ __forceinline__ unsigned key32_of(float s) {
    unsigned u = __float_as_uint(s);
    return (u & 0x80000000u) ? ~u : (u | 0x80000000u);
}

static __device__ __forceinline__ unsigned long long key64_of(float s, int li) {
    unsigned u = key32_of(s);
    unsigned low = ~(unsigned)li;   // ties broken by smaller local index
    return ((unsigned long long)u << 32) | (unsigned long long)low;
}

static __device__ __forceinline__ float4 fma4(float s, float4 w, float4 a) {
    a.x = fmaf(s, w.x, a.x); a.y = fmaf(s, w.y, a.y);
    a.z = fmaf(s, w.z, a.z); a.w = fmaf(s, w.w, a.w);
    return a;
}

// ---------------- kernels ----------------

// L0: copy edge list + count in-degrees (degi pre-zeroed)
__global__ void k_edges_init_count(const int* __restrict__ ei, int* __restrict__ esrc,
                                   int* __restrict__ edst, float* __restrict__ ew,
                                   int* __restrict__ degi) {
    int e = blockIdx.x * blockDim.x + threadIdx.x;
    if (e >= E0) return;
    int s = ei[e], d = ei[E0 + e];
    esrc[e] = s;
    edst[e] = d;
    ew[e] = 1.0f;
    atomicAdd(&degi[d], 1);
}

// layer end: remap surviving edges to new ids AND count next layer's in-degrees
__global__ void k_edge_remap_count(int* __restrict__ esrc, int* __restrict__ edst,
                                   float* __restrict__ ew, const int* __restrict__ remap,
                                   int* __restrict__ degi) {
    int e = blockIdx.x * blockDim.x + threadIdx.x;
    if (e >= E0) return;
    float w = ew[e];
    if (w != 0.f) {
        int ns = remap[esrc[e]];
        int nd = remap[edst[e]];
        if (ns >= 0 && nd >= 0) {
            esrc[e] = ns; edst[e] = nd;
            atomicAdd(&degi[nd], 1);
            return;
        }
    }
    esrc[e] = 0; edst[e] = 0; ew[e] = 0.f;
}

// exclusive scan, stage 1: 1024 elements per block (256 threads x 4)
__global__ void k_scan1(const int* __restrict__ in, int* __restrict__ out,
                        int* __restrict__ bsum, int M) {
    __shared__ int s[256];
    int t = threadIdx.x;
    int base = blockIdx.x * 1024 + t * 4;
    int d0 = (base + 0 < M) ? in[base + 0] : 0;
    int d1 = (base + 1 < M) ? in[base + 1] : 0;
    int d2 = (base + 2 < M) ? in[base + 2] : 0;
    int d3 = (base + 3 < M) ? in[base + 3] : 0;
    int tsum = d0 + d1 + d2 + d3;
    s[t] = tsum;
    __syncthreads();
    for (int off = 1; off < 256; off <<= 1) {
        int v = (t >= off) ? s[t - off] : 0;
        __syncthreads();
        s[t] += v;
        __syncthreads();
    }
    int texcl = s[t] - tsum;
    if (base + 0 < M) out[base + 0] = texcl;
    if (base + 1 < M) out[base + 1] = texcl + d0;
    if (base + 2 < M) out[base + 2] = texcl + d0 + d1;
    if (base + 3 < M) out[base + 3] = texcl + d0 + d1 + d2;
    if (t == 255) bsum[blockIdx.x] = s[255];
}

// stage 2: single block exclusive scan of block sums (nb <= 256); bsum[nb] = total
__global__ void k_scan2(int* __restrict__ bsum, int nb) {
    __shared__ int s[256];
    int t = threadIdx.x;
    int v = (t < nb) ? bsum[t] : 0;
    s[t] = v;
    __syncthreads();
    for (int off = 1; off < 256; off <<= 1) {
        int u = (t >= off) ? s[t - off] : 0;
        __syncthreads();
        s[t] += u;
        __syncthreads();
    }
    if (t < nb) bsum[t] = s[t] - v;
    if (t == 255) bsum[nb] = s[255];
}

// stage 3: add block offsets; init cursor; write rowptr[M]; dinv = rsqrt(deg+1)
__global__ void k_scan3(int* __restrict__ rowptr, const int* __restrict__ bsum,
                        int* __restrict__ cursor, const int* __restrict__ degi,
                        float* __restrict__ dinv, int M, int nb) {
    int i = blockIdx.x * 256 + threadIdx.x;
    if (i < M) {
        int v = rowptr[i] + bsum[i >> 10];
        rowptr[i] = v;
        cursor[i] = v;
        dinv[i] = rsqrtf((float)degi[i] + 1.0f);
    }
    if (i == 0) rowptr[M] = bsum[nb];
}

// place live edges into CSR buckets (arbitrary order within bucket)
__global__ void k_csr_fill(const int* __restrict__ esrc, const int* __restrict__ edst,
                           const float* __restrict__ ew, int* __restrict__ cursor,
                           int* __restrict__ col) {
    int e = blockIdx.x * blockDim.x + threadIdx.x;
    if (e >= E0) return;
    if (ew[e] != 0.f) {
        int d = edst[e];
        int pos = atomicAdd(&cursor[d], 1);
        col[pos] = esrc[e];
    }
}

// aggregate input features (FI=4): one row per thread, float4 loads.
__global__ void k_gather_x4(const float* __restrict__ x, const int* __restrict__ rowptr,
                            const int* __restrict__ col, const float* __restrict__ dinv,
                            float* __restrict__ ax, int M) {
    int row = blockIdx.x * blockDim.x + threadIdx.x;
    if (row >= M) return;
    int rp0 = rowptr[row], rp1 = rowptr[row + 1];
    float dd = dinv[row];
    float invdeg = dd * dd;
    float4 xs = ((const float4*)x)[row];
    float4 acc;
    acc.x = xs.x * invdeg; acc.y = xs.y * invdeg;
    acc.z = xs.z * invdeg; acc.w = xs.w * invdeg;
    for (int j = rp0; j < rp1; ++j) {
        int s = col[j];
        float nrm = dd * dinv[s];
        float4 v = ((const float4*)x)[s];
        acc.x = fmaf(v.x, nrm, acc.x);
        acc.y = fmaf(v.y, nrm, acc.y);
        acc.z = fmaf(v.z, nrm, acc.z);
        acc.w = fmaf(v.w, nrm, acc.w);
    }
    ((float4*)ax)[row] = acc;
}

// aggregate input features (FI = 32/64/128): sub-wave per row, coalesced feature reads
template <int FI>
__global__ void k_gather_x(const float* __restrict__ x, const int* __restrict__ rowptr,
                           const int* __restrict__ col, const float* __restrict__ dinv,
                           float* __restrict__ ax, int M) {
    constexpr int LPR = (FI < 64) ? FI : 64;   // lanes per row
    constexpr int VPL = FI / LPR;              // floats per lane (1 or 2)
    constexpr int RPW = 64 / LPR;              // rows per wave
    int wave = (blockIdx.x * blockDim.x + threadIdx.x) >> 6;
    int lane = threadIdx.x & 63;
    int sub = lane / LPR;
    int f = lane % LPR;
    int row = wave * RPW + sub;
    if (row >= M) return;
    int rp0 = rowptr[row], rp1 = rowptr[row + 1];
    float dd = dinv[row];
    float invdeg = dd * dd;
    float acc[VPL];
#pragma unroll
    for (int v = 0; v < VPL; ++v)
        acc[v] = x[(size_t)row * FI + f * VPL + v] * invdeg;
    for (int j = rp0; j < rp1; ++j) {
        int s = col[j];
        float nrm = dd * dinv[s];
#pragma unroll
        for (int v = 0; v < VPL; ++v)
            acc[v] = fmaf(x[(size_t)s * FI + f * VPL + v], nrm, acc[v]);
    }
#pragma unroll
    for (int v = 0; v < VPL; ++v)
        ax[(size_t)row * FI + f * VPL + v] = acc[v];
}

// fused dense layer: y = relu(ax @ W + bias); score = dot(y, p)/|p|.
// 4 rows x 4 cols per thread. NO global atomics here — R8 showed the fused ghist
// atomicAdd cost ~25-30 µs/dispatch (WRITE_SIZE excess = 64 B x n_atomics, line bounce).
// Outer c-loop kept rolled (#pragma unroll 2) — full unroll spilled ~2.5 KB/thread (R5).
template <int FI, int FO>
__global__ void __launch_bounds__(256) k_mm(const float* __restrict__ ax,
                                            const float* __restrict__ W,
                                            const float* __restrict__ bias,
                                            const float* __restrict__ pvec,
                                            float* __restrict__ y,
                                            float* __restrict__ score, int M) {
    constexpr int Q = FO / 4;   // 8 / 16 / 32 lanes per row-quad
    int t = blockIdx.x * blockDim.x + threadIdx.x;
    int g = t / Q;
    int q = t % Q;
    int row = g * 4;
    if (row >= M) return;   // M divisible by 4 at every layer
    const float4* x0 = (const float4*)(ax + (size_t)(row + 0) * FI);
    const float4* x1 = (const float4*)(ax + (size_t)(row + 1) * FI);
    const float4* x2 = (const float4*)(ax + (size_t)(row + 2) * FI);
    const float4* x3 = (const float4*)(ax + (size_t)(row + 3) * FI);
    const float4* W4 = (const float4*)W;
    float4 a0 = {0.f, 0.f, 0.f, 0.f}, a1 = {0.f, 0.f, 0.f, 0.f};
    float4 a2 = {0.f, 0.f, 0.f, 0.f}, a3 = {0.f, 0.f, 0.f, 0.f};
#pragma unroll 2
    for (int c = 0; c < FI / 4; ++c) {
        float4 v0 = x0[c], v1 = x1[c], v2 = x2[c], v3 = x3[c];
        const float4* wr = W4 + (size_t)(c * 4) * Q + q;
        float4 w;
        w = wr[0 * Q];
        a0 = fma4(v0.x, w, a0); a1 = fma4(v1.x, w, a1);
        a2 = fma4(v2.x, w, a2); a3 = fma4(v3.x, w, a3);
        w = wr[1 * Q];
        a0 = fma4(v0.y, w, a0); a1 = fma4(v1.y, w, a1);
        a2 = fma4(v2.y, w, a2); a3 = fma4(v3.y, w, a3);
        w = wr[2 * Q];
        a0 = fma4(v0.z, w, a0); a1 = fma4(v1.z, w, a1);
        a2 = fma4(v2.z, w, a2); a3 = fma4(v3.z, w, a3);
        w = wr[3 * Q];
        a0 = fma4(v0.w, w, a0); a1 = fma4(v1.w, w, a1);
        a2 = fma4(v2.w, w, a2); a3 = fma4(v3.w, w, a3);
    }
    float4 b4 = ((const float4*)bias)[q];
    float4 o0, o1, o2, o3;
    o0.x = fmaxf(a0.x + b4.x, 0.f); o0.y = fmaxf(a0.y + b4.y, 0.f);
    o0.z = fmaxf(a0.z + b4.z, 0.f); o0.w = fmaxf(a0.w + b4.w, 0.f);
    o1.x = fmaxf(a1.x + b4.x, 0.f); o1.y = fmaxf(a1.y + b4.y, 0.f);
    o1.z = fmaxf(a1.z + b4.z, 0.f); o1.w = fmaxf(a1.w + b4.w, 0.f);
    o2.x = fmaxf(a2.x + b4.x, 0.f); o2.y = fmaxf(a2.y + b4.y, 0.f);
    o2.z = fmaxf(a2.z + b4.z, 0.f); o2.w = fmaxf(a2.w + b4.w, 0.f);
    o3.x = fmaxf(a3.x + b4.x, 0.f); o3.y = fmaxf(a3.y + b4.y, 0.f);
    o3.z = fmaxf(a3.z + b4.z, 0.f); o3.w = fmaxf(a3.w + b4.w, 0.f);
    ((float4*)(y + (size_t)(row + 0) * FO))[q] = o0;
    ((float4*)(y + (size_t)(row + 1) * FO))[q] = o1;
    ((float4*)(y + (size_t)(row + 2) * FO))[q] = o2;
    ((float4*)(y + (size_t)(row + 3) * FO))[q] = o3;
    float4 p4 = ((const float4*)pvec)[q];
    float d0 = o0.x * p4.x + o0.y * p4.y + o0.z * p4.z + o0.w * p4.w;
    float d1 = o1.x * p4.x + o1.y * p4.y + o1.z * p4.z + o1.w * p4.w;
    float d2 = o2.x * p4.x + o2.y * p4.y + o2.z * p4.z + o2.w * p4.w;
    float d3 = o3.x * p4.x + o3.y * p4.y + o3.z * p4.z + o3.w * p4.w;
    float pn = p4.x * p4.x + p4.y * p4.y + p4.z * p4.z + p4.w * p4.w;
#pragma unroll
    for (int off = Q / 2; off > 0; off >>= 1) {
        d0 += __shfl_xor(d0, off, 64);
        d1 += __shfl_xor(d1, off, 64);
        d2 += __shfl_xor(d2, off, 64);
        d3 += __shfl_xor(d3, off, 64);
        pn += __shfl_xor(pn, off, 64);
    }
    if (q == 0) {
        float inv = rsqrtf(pn);
        score[row + 0] = d0 * inv;
        score[row + 1] = d1 * inv;
        score[row + 2] = d2 * inv;
        score[row + 3] = d3 * inv;
    }
}

// LDS-privatized 12-bit coarse histogram of score keys. grid (ceil(n/4096), NB), 256 thr.
// Scores cluster into few exponent buckets — LDS atomics absorb the contention; global
// flush is one atomic per nonzero bin per block.
__global__ void k_hist12(const float* __restrict__ score, unsigned int* __restrict__ ghist,
                         int n) {
    __shared__ unsigned int h[1 << HBITS];
    for (int i = threadIdx.x; i < (1 << HBITS); i += 256) h[i] = 0u;
    __syncthreads();
    int b = blockIdx.y;
    const float* sc = score + (size_t)b * n;
    int i0 = blockIdx.x * 4096;
    int i1 = min(n, i0 + 4096);
    for (int i = i0 + threadIdx.x; i < i1; i += 256)
        atomicAdd(&h[key32_of(sc[i]) >> (32 - HBITS)], 1u);
    __syncthreads();
    unsigned int* gh = ghist + ((size_t)b << HBITS);
    for (int i = threadIdx.x; i < (1 << HBITS); i += 256) {
        unsigned v = h[i];
        if (v) atomicAdd(&gh[i], v);
    }
}

// one block (1024 threads) per graph: exact k-th largest key64 from the 12-bit coarse
// histogram + one filtered candidate pass + in-LDS radix over the remaining 52 bits
// (passes of 8,8,8,8,8,8,4 bits). Zeroes ghist for the next layer; zeroes cnt.
__global__ void __launch_bounds__(1024) k_topk_fine(
        const float* __restrict__ score, unsigned int* __restrict__ ghist,
        unsigned long long* __restrict__ T64, int* __restrict__ cnt, int n, int k) {
    int b = blockIdx.x;
    int t = threadIdx.x;
    const float* sc = score + (size_t)b * n;
    unsigned int* gh = ghist + ((size_t)b << HBITS);
    __shared__ int chunkSum[1024];
    __shared__ int chunkScan[1024];
    __shared__ unsigned long long cand[TK_CAP];
    __shared__ unsigned int hist[256];
    __shared__ int s_P12, s_r, s_c, s_rr, s_done, s_cc;
    __shared__ unsigned long long s_prefix;

    // ---- Step A: coarse pick from 4096-bin hist (descending); 4 bins per thread ----
    {
        int base = t << 2;
        int sum = (int)gh[base] + (int)gh[base + 1] + (int)gh[base + 2] + (int)gh[base + 3];
        chunkSum[t] = sum;
        chunkScan[t] = sum;
    }
    __syncthreads();
    // suffix (from-top) inclusive scan: chunkScan[t] = sum of chunks t..1023
    for (int off = 1; off < 1024; off <<= 1) {
        int v = (t + off < 1024) ? chunkScan[t + off] : 0;
        __syncthreads();
        chunkScan[t] += v;
        __syncthreads();
    }
    {
        int cumAbove = chunkScan[t] - chunkSum[t];   // sum of chunks strictly above t
        if (cumAbove < k && chunkScan[t] >= k) {     // threshold lies in chunk t
            int cum = cumAbove;
            int base = t << 2;
            for (int j = 3; j >= 0; --j) {           // bins descending within chunk
                int cb = (int)gh[base + j];
                cum += cb;
                if (cum >= k) {
                    s_P12 = base + j;
                    s_r = k - (cum - cb);   // 1-based rank within bucket
                    s_c = cb;
                    break;
                }
            }
        }
    }
    if (t == 0) s_cc = 0;
    __syncthreads();
    int P12 = s_P12, r = s_r, c = s_c;

    // ---- Step B: collect bucket candidates into LDS ----
    if (c <= TK_CAP) {
        for (int i = t; i < n; i += 1024) {
            unsigned u = key32_of(sc[i]);
            if ((int)(u >> (32 - HBITS)) == P12) {
                int pos = atomicAdd(&s_cc, 1);
                cand[pos] = ((unsigned long long)u << 32) |
                            (unsigned long long)(~(unsigned)i);
            }
        }
    }
    if (t == 0) {
        s_prefix = ((unsigned long long)(unsigned)P12) << (64 - HBITS);
        s_rr = r;
        s_done = 0;
    }
    __syncthreads();

    // ---- Step C: radix over remaining 52 bits (8x6 then 4) ----
    const int shifts[7] = {44, 36, 28, 20, 12, 4, 0};
    const int widths[7] = {8, 8, 8, 8, 8, 8, 4};
    for (int pi = 0; pi < 7; ++pi) {
        if (s_done) break;
        int shift = shifts[pi], wd = widths[pi];
        int nbins = 1 << wd;
        unsigned mask = (unsigned)nbins - 1u;
        for (int i = t; i < nbins; i += 1024) hist[i] = 0u;
        __syncthreads();
        unsigned long long prefix = s_prefix;
        int hs = shift + wd;
        if (c <= TK_CAP) {
            int cc = s_cc;
            for (int i = t; i < cc; i += 1024) {
                unsigned long long key = cand[i];
                if ((key >> hs) == (prefix >> hs))
                    atomicAdd(&hist[(unsigned)(key >> shift) & mask], 1u);
            }
        } else {
            // fallback (pathological tie mass): radix over global data
            for (int i = t; i < n; i += 1024) {
                unsigned long long key = key64_of(sc[i], i);
                if ((key >> hs) == (prefix >> hs))
                    atomicAdd(&hist[(unsigned)(key >> shift) & mask], 1u);
            }
        }
        __syncthreads();
        if (t == 0) {
            int rr = s_rr;
            unsigned long long pfx = s_prefix;
            for (int d = nbins - 1; d >= 0; --d) {
                int cb = (int)hist[d];
                if (rr <= cb) {
                    pfx |= ((unsigned long long)d) << shift;
                    if (rr == cb) s_done = 1;
                    break;
                }
                rr -= cb;
            }
            s_prefix = pfx;
            s_rr = rr;
        }
        __syncthreads();
    }
    __syncthreads();
    if (t == 0) { T64[b] = s_prefix; cnt[b] = 0; }
    // zero this graph's hist bins for the next layer
    for (int i = t; i < (1 << HBITS); i += 1024) gh[i] = 0u;
}

// phase A: keep flag -> new index via wave-aggregated block atomic; score := tanh(score) for kept
__global__ void k_select_idx(float* __restrict__ score,
                             const unsigned long long* __restrict__ T64, int* __restrict__ cnt,
                             int* __restrict__ remap, int n, int k) {
    int b = blockIdx.y;
    int i = blockIdx.x * 256 + threadIdx.x;
    int m = b * n + i;
    bool keep = false;
    float s = 0.f;
    if (i < n) {
        s = score[m];
        keep = key64_of(s, i) >= T64[b];
    }
    unsigned long long mask = __ballot(keep);
    int lane = threadIdx.x & 63;
    int wv = threadIdx.x >> 6;
    int lp = __popcll(mask & ((1ULL << lane) - 1ULL));
    __shared__ int woff[4];
    __shared__ int blockBase;
    if (lane == 0) woff[wv] = __popcll(mask);
    __syncthreads();
    if (threadIdx.x == 0) {
        int t0 = woff[0], t1 = woff[1], t2 = woff[2], t3 = woff[3];
        woff[0] = 0; woff[1] = t0; woff[2] = t0 + t1; woff[3] = t0 + t1 + t2;
        blockBase = atomicAdd(&cnt[b], t0 + t1 + t2 + t3);
    }
    __syncthreads();
    if (i < n) {
        if (keep) {
            remap[m] = b * k + blockBase + woff[wv] + lp;
            score[m] = tanhf(s);
        } else {
            remap[m] = -1;
        }
    }
}

// phase B: coalesced float4 row copy, xout[remap[m]] = y[m] * score[m] (score holds tanh)
__global__ void k_select_copy(const float* __restrict__ y, const float* __restrict__ score,
                              const int* __restrict__ remap, float* __restrict__ xout,
                              int M, int Fo4) {
    int t = blockIdx.x * blockDim.x + threadIdx.x;
    if (t >= M * Fo4) return;
    int m = t / Fo4, c = t - m * Fo4;
    int ni = remap[m];
    if (ni < 0) return;
    float4 v = ((const float4*)y)[(size_t)m * Fo4 + c];
    float s = score[m];
    float4 o; o.x = v.x * s; o.y = v.y * s; o.z = v.z * s; o.w = v.w * s;
    ((float4*)xout)[(size_t)ni * Fo4 + c] = o;
}

// stage 1 of final pooling: grid (PCHUNKS, NB), block 128.
__global__ void k_pool_partial(const float* __restrict__ x, float* __restrict__ pmax,
                               float* __restrict__ psum, int K3, int chunk) {
    int b = blockIdx.y, c = blockIdx.x, f = threadIdx.x;
    int i0 = c * chunk;
    int i1 = min(K3, i0 + chunk);
    const float* xb = x + (size_t)b * K3 * 128;
    float mx = -FLT_MAX, sm = 0.f;
    for (int i = i0; i < i1; ++i) {
        float v = xb[(size_t)i * 128 + f];
        mx = fmaxf(mx, v);
        sm += v;
    }
    int o = (b * PCHUNKS + c) * 128 + f;
    pmax[o] = mx;
    psum[o] = sm;
}

// stage 2: one block (128 threads) per graph: combine partials + metadata conv + fc + fc2
__global__ void k_final2(const float* __restrict__ pmax, const float* __restrict__ psum,
                         const float* __restrict__ metadata,
                         const float* __restrict__ convm_w, const float* __restrict__ convm_b,
                         const float* __restrict__ fc_w, const float* __restrict__ fc_b,
                         const float* __restrict__ fc2_w, const float* __restrict__ fc2_b,
                         float* __restrict__ out, int K3) {
    int b = blockIdx.x;
    int f = threadIdx.x;   // 0..127
    __shared__ float xc[260];
    __shared__ float red[128];
    float mx = -FLT_MAX, sm = 0.f;
    for (int c = 0; c < PCHUNKS; ++c) {
        int o = (b * PCHUNKS + c) * 128 + f;
        mx = fmaxf(mx, pmax[o]);
        sm += psum[o];
    }
    xc[f] = mx;
    xc[128 + f] = sm / (float)K3;
    if (f < 4) {
        float mv = metadata[b] * convm_w[f] + convm_b[f];
        xc[256 + f] = mv > 0.f ? mv : 0.f;
    }
    __syncthreads();
    float acc = fc_b[f];
    for (int i = 0; i < 260; ++i) acc = fmaf(xc[i], fc_w[i * 128 + f], acc);
    acc = acc > 0.f ? acc : 0.f;
    red[f] = acc * fc2_w[f];
    __syncthreads();
    for (int s2 = 64; s2 > 0; s2 >>= 1) {
        if (f < s2) red[f] += red[f + s2];
        __syncthreads();
    }
    if (f == 0) out[b] = red[0] + fc2_b[0];
}

// ---------------- launch ----------------

extern "C" void kernel_launch(void* const* d_in, const int* in_sizes, int n_in,
                              void* d_out, int out_size, void* d_ws, size_t ws_size,
                              hipStream_t stream) {
    const float* x0       = (const float*)d_in[0];
    const int*   ei       = (const int*)d_in[1];
    const float* metadata = (const float*)d_in[2];
    const float* W[4]  = {(const float*)d_in[3], (const float*)d_in[6],
                          (const float*)d_in[9], (const float*)d_in[12]};
    const float* bs[4] = {(const float*)d_in[4], (const float*)d_in[7],
                          (const float*)d_in[10], (const float*)d_in[13]};
    const float* pv[4] = {(const float*)d_in[5], (const float*)d_in[8],
                          (const float*)d_in[11], (const float*)d_in[14]};
    const float* convm_w = (const float*)d_in[15];
    const float* convm_b = (const float*)d_in[16];
    const float* fc_w    = (const float*)d_in[17];
    const float* fc_b    = (const float*)d_in[18];
    const float* fc2_w   = (const float*)d_in[19];
    const float* fc2_b   = (const float*)d_in[20];

    // workspace bump allocation
    const size_t HMAX = 5243392;
    const size_t XMAX = 2621952;
    const size_t MMAX = NB * (size_t)N0;   // 163848

    char* p = (char*)d_ws;
    size_t off = 0;
    auto alloc = [&](size_t bytes) -> char* {
        char* r = p + off;
        off = (off + bytes + 255) & ~(size_t)255;
        return r;
    };
    float* ax    = (float*)alloc(HMAX * 4);
    float* y     = (float*)alloc(HMAX * 4);
    float* xb0   = (float*)alloc(XMAX * 4);
    float* xb1   = (float*)alloc(XMAX * 4);
    float* dinv  = (float*)alloc(MMAX * 4);
    float* score = (float*)alloc(MMAX * 4);
    int*   remap = (int*)alloc(MMAX * 4);
    int*   degi  = (int*)alloc(MMAX * 4);
    int*   rowptr= (int*)alloc((MMAX + 1) * 4);
    int*   cursor= (int*)alloc(MMAX * 4);
    int*   col   = (int*)alloc(E0 * 4);
    int*   bsum  = (int*)alloc(260 * 4);
    int*   esrc  = (int*)alloc(E0 * 4);
    int*   edst  = (int*)alloc(E0 * 4);
    float* ew    = (float*)alloc(E0 * 4);
    float* pmax  = (float*)alloc(NB * PCHUNKS * 128 * 4);
    float* psum  = (float*)alloc(NB * PCHUNKS * 128 * 4);
    unsigned int* ghist = (unsigned int*)alloc((size_t)NB * (1 << HBITS) * 4);
    unsigned long long* T64 = (unsigned long long*)alloc(NB * 8);
    int*   cnt   = (int*)alloc(NB * 4);
    (void)ws_size; (void)n_in; (void)in_sizes; (void)out_size;

    const int Fo[4] = {32, 64, 128, 128};
    const int Kk[4] = {20481, 10241, 5121, 2561};

    const int TB = 256;
    const int EG = (E0 + TB - 1) / TB;

    hipMemsetAsync(ghist, 0, (size_t)NB * (1 << HBITS) * 4, stream);
    hipMemsetAsync(degi, 0, MMAX * 4, stream);
    k_edges_init_count<<<EG, TB, 0, stream>>>(ei, esrc, edst, ew, degi);

    int M = NB * N0;
    const float* xin = x0;
    float* xbufs[2] = {xb0, xb1};

    for (int L = 0; L < 4; ++L) {
        int fo = Fo[L];
        int n = M / NB, kk = Kk[L];

        // ---- CSR build (degi already counted) ----
        int nb = (M + 1023) / 1024;
        k_scan1<<<nb, 256, 0, stream>>>(degi, rowptr, bsum, M);
        k_scan2<<<1, 256, 0, stream>>>(bsum, nb);
        k_scan3<<<(M + 255) / 256, 256, 0, stream>>>(rowptr, bsum, cursor, degi, dinv, M, nb);
        k_csr_fill<<<EG, TB, 0, stream>>>(esrc, edst, ew, cursor, col);

        // ---- aggregate input features (linear, so agg before matmul) ----
        if (L == 0) {
            k_gather_x4<<<(M + TB - 1) / TB, TB, 0, stream>>>(xin, rowptr, col, dinv, ax, M);
        } else if (L == 1) {
            int rpb = 8;
            k_gather_x<32><<<(M + rpb - 1) / rpb, 256, 0, stream>>>(xin, rowptr, col, dinv, ax, M);
        } else if (L == 2) {
            int rpb = 4;
            k_gather_x<64><<<(M + rpb - 1) / rpb, 256, 0, stream>>>(xin, rowptr, col, dinv, ax, M);
        } else {
            int rpb = 4;
            k_gather_x<128><<<(M + rpb - 1) / rpb, 256, 0, stream>>>(xin, rowptr, col, dinv, ax, M);
        }

        // ---- fused matmul + bias + relu + score ----
        if (L == 0) {
            int nt = (M / 4) * 8;
            k_mm<4, 32><<<(nt + 255) / 256, 256, 0, stream>>>(ax, W[L], bs[L], pv[L], y, score, M);
        } else if (L == 1) {
            int nt = (M / 4) * 16;
            k_mm<32, 64><<<(nt + 255) / 256, 256, 0, stream>>>(ax, W[L], bs[L], pv[L], y, score, M);
        } else if (L == 2) {
            int nt = (M / 4) * 32;
            k_mm<64, 128><<<(nt + 255) / 256, 256, 0, stream>>>(ax, W[L], bs[L], pv[L], y, score, M);
        } else {
            int nt = (M / 4) * 32;
            k_mm<128, 128><<<(nt + 255) / 256, 256, 0, stream>>>(ax, W[L], bs[L], pv[L], y, score, M);
        }

        // ---- top-k pooling ----
        dim3 gh((n + 4095) / 4096, NB);
        k_hist12<<<gh, 256, 0, stream>>>(score, ghist, n);
        k_topk_fine<<<NB, 1024, 0, stream>>>(score, ghist, T64, cnt, n, kk);
        dim3 gsel((n + 255) / 256, NB);
        k_select_idx<<<gsel, 256, 0, stream>>>(score, T64, cnt, remap, n, kk);
        float* xout = xbufs[L & 1];
        int ctot = M * (fo / 4);
        k_select_copy<<<(ctot + TB - 1) / TB, TB, 0, stream>>>(y, score, remap, xout,
                                                               M, fo / 4);
        if (L < 3) {
            hipMemsetAsync(degi, 0, (size_t)NB * kk * 4, stream);
            k_edge_remap_count<<<EG, TB, 0, stream>>>(esrc, edst, ew, remap, degi);
        }

        M = NB * kk;
        xin = xout;
    }

    int K3 = Kk[3];
    int chunk = (K3 + PCHUNKS - 1) / PCHUNKS;
    dim3 gpool(PCHUNKS, NB);
    k_pool_partial<<<gpool, 128, 0, stream>>>(xin, pmax, psum, K3, chunk);
    k_final2<<<NB, 128, 0, stream>>>(pmax, psum, metadata, convm_w, convm_b,
                                     fc_w, fc_b, fc2_w, fc2_b, (float*)d_out, K3);
}

// Round 10
// 623.559 us; speedup vs baseline: 2.8032x; 1.0364x over previous
//
#include <hip/hip_runtime.h>
#include <float.h>
#include <math.h>

#define NB 4            // graphs per batch
#define N0 40962        // nodes per graph at input
#define E0 983088       // total directed edges at layer 0
#define PCHUNKS 40      // stage-1 pooling blocks per graph
#define TK_CAP 6144     // candidate capacity for fine top-k select (48 KB LDS)
#define HBITS 12        // coarse histogram bits (4096 bins; LDS-privatized)

// ---------------- helpers ----------------

static __device__ __forceinline__ unsigned key32_of(float s) {
    unsigned u = __float_as_uint(s);
    return (u & 0x80000000u) ? ~u : (u | 0x80000000u);
}

static __device__ __forceinline__ unsigned long long key64_of(float s, int li) {
    unsigned u = key32_of(s);
    unsigned low = ~(unsigned)li;   // ties broken by smaller local index
    return ((unsigned long long)u << 32) | (unsigned long long)low;
}

static __device__ __forceinline__ float4 fma4(float s, float4 w, float4 a) {
    a.x = fmaf(s, w.x, a.x); a.y = fmaf(s, w.y, a.y);
    a.z = fmaf(s, w.z, a.z); a.w = fmaf(s, w.w, a.w);
    return a;
}

// ---------------- kernels ----------------

// L0: count in-degrees straight from the input edge list (degi pre-zeroed)
__global__ void k_deg_count0(const int* __restrict__ ei, int* __restrict__ degi) {
    int e = blockIdx.x * blockDim.x + threadIdx.x;
    if (e >= E0) return;
    atomicAdd(&degi[ei[E0 + e]], 1);
}

// L0: place edges into CSR buckets (arbitrary order within bucket)
__global__ void k_csr_fill0(const int* __restrict__ ei, int* __restrict__ cursor,
                            int* __restrict__ col) {
    int e = blockIdx.x * blockDim.x + threadIdx.x;
    if (e >= E0) return;
    int d = ei[E0 + e];
    int pos = atomicAdd(&cursor[d], 1);
    col[pos] = ei[e];
}

// exclusive scan, stage 1: 1024 elements per block (256 threads x 4)
__global__ void k_scan1(const int* __restrict__ in, int* __restrict__ out,
                        int* __restrict__ bsum, int M) {
    __shared__ int s[256];
    int t = threadIdx.x;
    int base = blockIdx.x * 1024 + t * 4;
    int d0 = (base + 0 < M) ? in[base + 0] : 0;
    int d1 = (base + 1 < M) ? in[base + 1] : 0;
    int d2 = (base + 2 < M) ? in[base + 2] : 0;
    int d3 = (base + 3 < M) ? in[base + 3] : 0;
    int tsum = d0 + d1 + d2 + d3;
    s[t] = tsum;
    __syncthreads();
    for (int off = 1; off < 256; off <<= 1) {
        int v = (t >= off) ? s[t - off] : 0;
        __syncthreads();
        s[t] += v;
        __syncthreads();
    }
    int texcl = s[t] - tsum;
    if (base + 0 < M) out[base + 0] = texcl;
    if (base + 1 < M) out[base + 1] = texcl + d0;
    if (base + 2 < M) out[base + 2] = texcl + d0 + d1;
    if (base + 3 < M) out[base + 3] = texcl + d0 + d1 + d2;
    if (t == 255) bsum[blockIdx.x] = s[255];
}

// stage 2: single block exclusive scan of block sums (nb <= 256); bsum[nb] = total
__global__ void k_scan2(int* __restrict__ bsum, int nb) {
    __shared__ int s[256];
    int t = threadIdx.x;
    int v = (t < nb) ? bsum[t] : 0;
    s[t] = v;
    __syncthreads();
    for (int off = 1; off < 256; off <<= 1) {
        int u = (t >= off) ? s[t - off] : 0;
        __syncthreads();
        s[t] += u;
        __syncthreads();
    }
    if (t < nb) bsum[t] = s[t] - v;
    if (t == 255) bsum[nb] = s[255];
}

// stage 3: add block offsets; init cursor; write rowptr[M]; dinv = rsqrt(deg+1)
__global__ void k_scan3(int* __restrict__ rowptr, const int* __restrict__ bsum,
                        int* __restrict__ cursor, const int* __restrict__ degi,
                        float* __restrict__ dinv, int M, int nb) {
    int i = blockIdx.x * 256 + threadIdx.x;
    if (i < M) {
        int v = rowptr[i] + bsum[i >> 10];
        rowptr[i] = v;
        cursor[i] = v;
        dinv[i] = rsqrtf((float)degi[i] + 1.0f);
    }
    if (i == 0) rowptr[M] = bsum[nb];
}

// CSR compaction pass 1: new degree per kept node (every new id written exactly once)
__global__ void k_newdeg(const int* __restrict__ remap, const int* __restrict__ rpO,
                         const int* __restrict__ colO, int* __restrict__ degN, int Mold) {
    int m = blockIdx.x * blockDim.x + threadIdx.x;
    if (m >= Mold) return;
    int nd = remap[m];
    if (nd < 0) return;
    int c = 0;
    int j0 = rpO[m], j1 = rpO[m + 1];
    for (int j = j0; j < j1; ++j) c += (remap[colO[j]] >= 0) ? 1 : 0;
    degN[nd] = c;
}

// CSR compaction pass 2: write surviving neighbors (contiguous per row; no atomics)
__global__ void k_newcol(const int* __restrict__ remap, const int* __restrict__ rpO,
                         const int* __restrict__ colO, const int* __restrict__ rpN,
                         int* __restrict__ colN, int Mold) {
    int m = blockIdx.x * blockDim.x + threadIdx.x;
    if (m >= Mold) return;
    int nd = remap[m];
    if (nd < 0) return;
    int w = rpN[nd];
    int j0 = rpO[m], j1 = rpO[m + 1];
    for (int j = j0; j < j1; ++j) {
        int rs = remap[colO[j]];
        if (rs >= 0) colN[w++] = rs;
    }
}

// aggregate input features (FI=4): one row per thread, float4 loads.
__global__ void k_gather_x4(const float* __restrict__ x, const int* __restrict__ rowptr,
                            const int* __restrict__ col, const float* __restrict__ dinv,
                            float* __restrict__ ax, int M) {
    int row = blockIdx.x * blockDim.x + threadIdx.x;
    if (row >= M) return;
    int rp0 = rowptr[row], rp1 = rowptr[row + 1];
    float dd = dinv[row];
    float invdeg = dd * dd;
    float4 xs = ((const float4*)x)[row];
    float4 acc;
    acc.x = xs.x * invdeg; acc.y = xs.y * invdeg;
    acc.z = xs.z * invdeg; acc.w = xs.w * invdeg;
    for (int j = rp0; j < rp1; ++j) {
        int s = col[j];
        float nrm = dd * dinv[s];
        float4 v = ((const float4*)x)[s];
        acc.x = fmaf(v.x, nrm, acc.x);
        acc.y = fmaf(v.y, nrm, acc.y);
        acc.z = fmaf(v.z, nrm, acc.z);
        acc.w = fmaf(v.w, nrm, acc.w);
    }
    ((float4*)ax)[row] = acc;
}

// aggregate input features (FI = 32/64/128): sub-wave per row, coalesced feature reads
template <int FI>
__global__ void k_gather_x(const float* __restrict__ x, const int* __restrict__ rowptr,
                           const int* __restrict__ col, const float* __restrict__ dinv,
                           float* __restrict__ ax, int M) {
    constexpr int LPR = (FI < 64) ? FI : 64;   // lanes per row
    constexpr int VPL = FI / LPR;              // floats per lane (1 or 2)
    constexpr int RPW = 64 / LPR;              // rows per wave
    int wave = (blockIdx.x * blockDim.x + threadIdx.x) >> 6;
    int lane = threadIdx.x & 63;
    int sub = lane / LPR;
    int f = lane % LPR;
    int row = wave * RPW + sub;
    if (row >= M) return;
    int rp0 = rowptr[row], rp1 = rowptr[row + 1];
    float dd = dinv[row];
    float invdeg = dd * dd;
    float acc[VPL];
#pragma unroll
    for (int v = 0; v < VPL; ++v)
        acc[v] = x[(size_t)row * FI + f * VPL + v] * invdeg;
    for (int j = rp0; j < rp1; ++j) {
        int s = col[j];
        float nrm = dd * dinv[s];
#pragma unroll
        for (int v = 0; v < VPL; ++v)
            acc[v] = fmaf(x[(size_t)s * FI + f * VPL + v], nrm, acc[v]);
    }
#pragma unroll
    for (int v = 0; v < VPL; ++v)
        ax[(size_t)row * FI + f * VPL + v] = acc[v];
}

// fused dense layer: y = relu(ax @ W + bias); score = dot(y, p)/|p|.
// 4 rows x 4 cols per thread; no global atomics (R8); c-loop kept rolled (R5 spill).
template <int FI, int FO>
__global__ void __launch_bounds__(256) k_mm(const float* __restrict__ ax,
                                            const float* __restrict__ W,
                                            const float* __restrict__ bias,
                                            const float* __restrict__ pvec,
                                            float* __restrict__ y,
                                            float* __restrict__ score, int M) {
    constexpr int Q = FO / 4;   // 8 / 16 / 32 lanes per row-quad
    int t = blockIdx.x * blockDim.x + threadIdx.x;
    int g = t / Q;
    int q = t % Q;
    int row = g * 4;
    if (row >= M) return;   // M divisible by 4 at every layer
    const float4* x0 = (const float4*)(ax + (size_t)(row + 0) * FI);
    const float4* x1 = (const float4*)(ax + (size_t)(row + 1) * FI);
    const float4* x2 = (const float4*)(ax + (size_t)(row + 2) * FI);
    const float4* x3 = (const float4*)(ax + (size_t)(row + 3) * FI);
    const float4* W4 = (const float4*)W;
    float4 a0 = {0.f, 0.f, 0.f, 0.f}, a1 = {0.f, 0.f, 0.f, 0.f};
    float4 a2 = {0.f, 0.f, 0.f, 0.f}, a3 = {0.f, 0.f, 0.f, 0.f};
#pragma unroll 2
    for (int c = 0; c < FI / 4; ++c) {
        float4 v0 = x0[c], v1 = x1[c], v2 = x2[c], v3 = x3[c];
        const float4* wr = W4 + (size_t)(c * 4) * Q + q;
        float4 w;
        w = wr[0 * Q];
        a0 = fma4(v0.x, w, a0); a1 = fma4(v1.x, w, a1);
        a2 = fma4(v2.x, w, a2); a3 = fma4(v3.x, w, a3);
        w = wr[1 * Q];
        a0 = fma4(v0.y, w, a0); a1 = fma4(v1.y, w, a1);
        a2 = fma4(v2.y, w, a2); a3 = fma4(v3.y, w, a3);
        w = wr[2 * Q];
        a0 = fma4(v0.z, w, a0); a1 = fma4(v1.z, w, a1);
        a2 = fma4(v2.z, w, a2); a3 = fma4(v3.z, w, a3);
        w = wr[3 * Q];
        a0 = fma4(v0.w, w, a0); a1 = fma4(v1.w, w, a1);
        a2 = fma4(v2.w, w, a2); a3 = fma4(v3.w, w, a3);
    }
    float4 b4 = ((const float4*)bias)[q];
    float4 o0, o1, o2, o3;
    o0.x = fmaxf(a0.x + b4.x, 0.f); o0.y = fmaxf(a0.y + b4.y, 0.f);
    o0.z = fmaxf(a0.z + b4.z, 0.f); o0.w = fmaxf(a0.w + b4.w, 0.f);
    o1.x = fmaxf(a1.x + b4.x, 0.f); o1.y = fmaxf(a1.y + b4.y, 0.f);
    o1.z = fmaxf(a1.z + b4.z, 0.f); o1.w = fmaxf(a1.w + b4.w, 0.f);
    o2.x = fmaxf(a2.x + b4.x, 0.f); o2.y = fmaxf(a2.y + b4.y, 0.f);
    o2.z = fmaxf(a2.z + b4.z, 0.f); o2.w = fmaxf(a2.w + b4.w, 0.f);
    o3.x = fmaxf(a3.x + b4.x, 0.f); o3.y = fmaxf(a3.y + b4.y, 0.f);
    o3.z = fmaxf(a3.z + b4.z, 0.f); o3.w = fmaxf(a3.w + b4.w, 0.f);
    ((float4*)(y + (size_t)(row + 0) * FO))[q] = o0;
    ((float4*)(y + (size_t)(row + 1) * FO))[q] = o1;
    ((float4*)(y + (size_t)(row + 2) * FO))[q] = o2;
    ((float4*)(y + (size_t)(row + 3) * FO))[q] = o3;
    float4 p4 = ((const float4*)pvec)[q];
    float d0 = o0.x * p4.x + o0.y * p4.y + o0.z * p4.z + o0.w * p4.w;
    float d1 = o1.x * p4.x + o1.y * p4.y + o1.z * p4.z + o1.w * p4.w;
    float d2 = o2.x * p4.x + o2.y * p4.y + o2.z * p4.z + o2.w * p4.w;
    float d3 = o3.x * p4.x + o3.y * p4.y + o3.z * p4.z + o3.w * p4.w;
    float pn = p4.x * p4.x + p4.y * p4.y + p4.z * p4.z + p4.w * p4.w;
#pragma unroll
    for (int off = Q / 2; off > 0; off >>= 1) {
        d0 += __shfl_xor(d0, off, 64);
        d1 += __shfl_xor(d1, off, 64);
        d2 += __shfl_xor(d2, off, 64);
        d3 += __shfl_xor(d3, off, 64);
        pn += __shfl_xor(pn, off, 64);
    }
    if (q == 0) {
        float inv = rsqrtf(pn);
        score[row + 0] = d0 * inv;
        score[row + 1] = d1 * inv;
        score[row + 2] = d2 * inv;
        score[row + 3] = d3 * inv;
    }
}

// LDS-privatized 12-bit coarse histogram of score keys. grid (ceil(n/4096), NB), 256 thr.
__global__ void k_hist12(const float* __restrict__ score, unsigned int* __restrict__ ghist,
                         int n) {
    __shared__ unsigned int h[1 << HBITS];
    for (int i = threadIdx.x; i < (1 << HBITS); i += 256) h[i] = 0u;
    __syncthreads();
    int b = blockIdx.y;
    const float* sc = score + (size_t)b * n;
    int i0 = blockIdx.x * 4096;
    int i1 = min(n, i0 + 4096);
    for (int i = i0 + threadIdx.x; i < i1; i += 256)
        atomicAdd(&h[key32_of(sc[i]) >> (32 - HBITS)], 1u);
    __syncthreads();
    unsigned int* gh = ghist + ((size_t)b << HBITS);
    for (int i = threadIdx.x; i < (1 << HBITS); i += 256) {
        unsigned v = h[i];
        if (v) atomicAdd(&gh[i], v);
    }
}

// one block (1024 threads) per graph: exact k-th largest key64 from the 12-bit coarse
// histogram + one filtered candidate pass + in-LDS radix over the remaining 52 bits.
// Zeroes ghist for the next layer; zeroes cnt.
__global__ void __launch_bounds__(1024) k_topk_fine(
        const float* __restrict__ score, unsigned int* __restrict__ ghist,
        unsigned long long* __restrict__ T64, int* __restrict__ cnt, int n, int k) {
    int b = blockIdx.x;
    int t = threadIdx.x;
    const float* sc = score + (size_t)b * n;
    unsigned int* gh = ghist + ((size_t)b << HBITS);
    __shared__ int chunkSum[1024];
    __shared__ int chunkScan[1024];
    __shared__ unsigned long long cand[TK_CAP];
    __shared__ unsigned int hist[256];
    __shared__ int s_P12, s_r, s_c, s_rr, s_done, s_cc;
    __shared__ unsigned long long s_prefix;

    // ---- Step A: coarse pick from 4096-bin hist (descending); 4 bins per thread ----
    {
        int base = t << 2;
        int sum = (int)gh[base] + (int)gh[base + 1] + (int)gh[base + 2] + (int)gh[base + 3];
        chunkSum[t] = sum;
        chunkScan[t] = sum;
    }
    __syncthreads();
    for (int off = 1; off < 1024; off <<= 1) {
        int v = (t + off < 1024) ? chunkScan[t + off] : 0;
        __syncthreads();
        chunkScan[t] += v;
        __syncthreads();
    }
    {
        int cumAbove = chunkScan[t] - chunkSum[t];
        if (cumAbove < k && chunkScan[t] >= k) {
            int cum = cumAbove;
            int base = t << 2;
            for (int j = 3; j >= 0; --j) {
                int cb = (int)gh[base + j];
                cum += cb;
                if (cum >= k) {
                    s_P12 = base + j;
                    s_r = k - (cum - cb);
                    s_c = cb;
                    break;
                }
            }
        }
    }
    if (t == 0) s_cc = 0;
    __syncthreads();
    int P12 = s_P12, r = s_r, c = s_c;

    // ---- Step B: collect bucket candidates into LDS ----
    if (c <= TK_CAP) {
        for (int i = t; i < n; i += 1024) {
            unsigned u = key32_of(sc[i]);
            if ((int)(u >> (32 - HBITS)) == P12) {
                int pos = atomicAdd(&s_cc, 1);
                cand[pos] = ((unsigned long long)u << 32) |
                            (unsigned long long)(~(unsigned)i);
            }
        }
    }
    if (t == 0) {
        s_prefix = ((unsigned long long)(unsigned)P12) << (64 - HBITS);
        s_rr = r;
        s_done = 0;
    }
    __syncthreads();

    // ---- Step C: radix over remaining 52 bits (8x6 then 4) ----
    const int shifts[7] = {44, 36, 28, 20, 12, 4, 0};
    const int widths[7] = {8, 8, 8, 8, 8, 8, 4};
    for (int pi = 0; pi < 7; ++pi) {
        if (s_done) break;
        int shift = shifts[pi], wd = widths[pi];
        int nbins = 1 << wd;
        unsigned mask = (unsigned)nbins - 1u;
        for (int i = t; i < nbins; i += 1024) hist[i] = 0u;
        __syncthreads();
        unsigned long long prefix = s_prefix;
        int hs = shift + wd;
        if (c <= TK_CAP) {
            int cc = s_cc;
            for (int i = t; i < cc; i += 1024) {
                unsigned long long key = cand[i];
                if ((key >> hs) == (prefix >> hs))
                    atomicAdd(&hist[(unsigned)(key >> shift) & mask], 1u);
            }
        } else {
            for (int i = t; i < n; i += 1024) {
                unsigned long long key = key64_of(sc[i], i);
                if ((key >> hs) == (prefix >> hs))
                    atomicAdd(&hist[(unsigned)(key >> shift) & mask], 1u);
            }
        }
        __syncthreads();
        if (t == 0) {
            int rr = s_rr;
            unsigned long long pfx = s_prefix;
            for (int d = nbins - 1; d >= 0; --d) {
                int cb = (int)hist[d];
                if (rr <= cb) {
                    pfx |= ((unsigned long long)d) << shift;
                    if (rr == cb) s_done = 1;
                    break;
                }
                rr -= cb;
            }
            s_prefix = pfx;
            s_rr = rr;
        }
        __syncthreads();
    }
    __syncthreads();
    if (t == 0) { T64[b] = s_prefix; cnt[b] = 0; }
    for (int i = t; i < (1 << HBITS); i += 1024) gh[i] = 0u;
}

// phase A: keep flag -> new index via wave-aggregated block atomic; score := tanh(score) for kept
__global__ void k_select_idx(float* __restrict__ score,
                             const unsigned long long* __restrict__ T64, int* __restrict__ cnt,
                             int* __restrict__ remap, int n, int k) {
    int b = blockIdx.y;
    int i = blockIdx.x * 256 + threadIdx.x;
    int m = b * n + i;
    bool keep = false;
    float s = 0.f;
    if (i < n) {
        s = score[m];
        keep = key64_of(s, i) >= T64[b];
    }
    unsigned long long mask = __ballot(keep);
    int lane = threadIdx.x & 63;
    int wv = threadIdx.x >> 6;
    int lp = __popcll(mask & ((1ULL << lane) - 1ULL));
    __shared__ int woff[4];
    __shared__ int blockBase;
    if (lane == 0) woff[wv] = __popcll(mask);
    __syncthreads();
    if (threadIdx.x == 0) {
        int t0 = woff[0], t1 = woff[1], t2 = woff[2], t3 = woff[3];
        woff[0] = 0; woff[1] = t0; woff[2] = t0 + t1; woff[3] = t0 + t1 + t2;
        blockBase = atomicAdd(&cnt[b], t0 + t1 + t2 + t3);
    }
    __syncthreads();
    if (i < n) {
        if (keep) {
            remap[m] = b * k + blockBase + woff[wv] + lp;
            score[m] = tanhf(s);
        } else {
            remap[m] = -1;
        }
    }
}

// phase B: coalesced float4 row copy, xout[remap[m]] = y[m] * score[m] (score holds tanh)
__global__ void k_select_copy(const float* __restrict__ y, const float* __restrict__ score,
                              const int* __restrict__ remap, float* __restrict__ xout,
                              int M, int Fo4) {
    int t = blockIdx.x * blockDim.x + threadIdx.x;
    if (t >= M * Fo4) return;
    int m = t / Fo4, c = t - m * Fo4;
    int ni = remap[m];
    if (ni < 0) return;
    float4 v = ((const float4*)y)[(size_t)m * Fo4 + c];
    float s = score[m];
    float4 o; o.x = v.x * s; o.y = v.y * s; o.z = v.z * s; o.w = v.w * s;
    ((float4*)xout)[(size_t)ni * Fo4 + c] = o;
}

// stage 1 of final pooling: grid (PCHUNKS, NB), block 128.
__global__ void k_pool_partial(const float* __restrict__ x, float* __restrict__ pmax,
                               float* __restrict__ psum, int K3, int chunk) {
    int b = blockIdx.y, c = blockIdx.x, f = threadIdx.x;
    int i0 = c * chunk;
    int i1 = min(K3, i0 + chunk);
    const float* xb = x + (size_t)b * K3 * 128;
    float mx = -FLT_MAX, sm = 0.f;
    for (int i = i0; i < i1; ++i) {
        float v = xb[(size_t)i * 128 + f];
        mx = fmaxf(mx, v);
        sm += v;
    }
    int o = (b * PCHUNKS + c) * 128 + f;
    pmax[o] = mx;
    psum[o] = sm;
}

// stage 2: one block (128 threads) per graph: combine partials + metadata conv + fc + fc2
__global__ void k_final2(const float* __restrict__ pmax, const float* __restrict__ psum,
                         const float* __restrict__ metadata,
                         const float* __restrict__ convm_w, const float* __restrict__ convm_b,
                         const float* __restrict__ fc_w, const float* __restrict__ fc_b,
                         const float* __restrict__ fc2_w, const float* __restrict__ fc2_b,
                         float* __restrict__ out, int K3) {
    int b = blockIdx.x;
    int f = threadIdx.x;   // 0..127
    __shared__ float xc[260];
    __shared__ float red[128];
    float mx = -FLT_MAX, sm = 0.f;
    for (int c = 0; c < PCHUNKS; ++c) {
        int o = (b * PCHUNKS + c) * 128 + f;
        mx = fmaxf(mx, pmax[o]);
        sm += psum[o];
    }
    xc[f] = mx;
    xc[128 + f] = sm / (float)K3;
    if (f < 4) {
        float mv = metadata[b] * convm_w[f] + convm_b[f];
        xc[256 + f] = mv > 0.f ? mv : 0.f;
    }
    __syncthreads();
    float acc = fc_b[f];
    for (int i = 0; i < 260; ++i) acc = fmaf(xc[i], fc_w[i * 128 + f], acc);
    acc = acc > 0.f ? acc : 0.f;
    red[f] = acc * fc2_w[f];
    __syncthreads();
    for (int s2 = 64; s2 > 0; s2 >>= 1) {
        if (f < s2) red[f] += red[f + s2];
        __syncthreads();
    }
    if (f == 0) out[b] = red[0] + fc2_b[0];
}

// ---------------- launch ----------------

extern "C" void kernel_launch(void* const* d_in, const int* in_sizes, int n_in,
                              void* d_out, int out_size, void* d_ws, size_t ws_size,
                              hipStream_t stream) {
    const float* x0       = (const float*)d_in[0];
    const int*   ei       = (const int*)d_in[1];
    const float* metadata = (const float*)d_in[2];
    const float* W[4]  = {(const float*)d_in[3], (const float*)d_in[6],
                          (const float*)d_in[9], (const float*)d_in[12]};
    const float* bs[4] = {(const float*)d_in[4], (const float*)d_in[7],
                          (const float*)d_in[10], (const float*)d_in[13]};
    const float* pv[4] = {(const float*)d_in[5], (const float*)d_in[8],
                          (const float*)d_in[11], (const float*)d_in[14]};
    const float* convm_w = (const float*)d_in[15];
    const float* convm_b = (const float*)d_in[16];
    const float* fc_w    = (const float*)d_in[17];
    const float* fc_b    = (const float*)d_in[18];
    const float* fc2_w   = (const float*)d_in[19];
    const float* fc2_b   = (const float*)d_in[20];

    // workspace bump allocation
    const size_t HMAX = 5243392;
    const size_t XMAX = 2621952;
    const size_t MMAX = NB * (size_t)N0;   // 163848

    char* p = (char*)d_ws;
    size_t off = 0;
    auto alloc = [&](size_t bytes) -> char* {
        char* r = p + off;
        off = (off + bytes + 255) & ~(size_t)255;
        return r;
    };
    float* ax     = (float*)alloc(HMAX * 4);
    float* y      = (float*)alloc(HMAX * 4);
    float* xb0    = (float*)alloc(XMAX * 4);
    float* xb1    = (float*)alloc(XMAX * 4);
    float* dinv   = (float*)alloc(MMAX * 4);
    float* score  = (float*)alloc(MMAX * 4);
    int*   remap  = (int*)alloc(MMAX * 4);
    int*   degi   = (int*)alloc(MMAX * 4);
    int*   rowptrA= (int*)alloc((MMAX + 1) * 4);
    int*   rowptrB= (int*)alloc((MMAX + 1) * 4);
    int*   cursor = (int*)alloc(MMAX * 4);
    int*   colA   = (int*)alloc(E0 * 4);
    int*   colB   = (int*)alloc(E0 * 4);
    int*   bsum   = (int*)alloc(260 * 4);
    float* pmax   = (float*)alloc(NB * PCHUNKS * 128 * 4);
    float* psum   = (float*)alloc(NB * PCHUNKS * 128 * 4);
    unsigned int* ghist = (unsigned int*)alloc((size_t)NB * (1 << HBITS) * 4);
    unsigned long long* T64 = (unsigned long long*)alloc(NB * 8);
    int*   cnt    = (int*)alloc(NB * 4);
    (void)ws_size; (void)n_in; (void)in_sizes; (void)out_size;

    const int Fo[4] = {32, 64, 128, 128};
    const int Kk[4] = {20481, 10241, 5121, 2561};

    const int TB = 256;
    const int EG = (E0 + TB - 1) / TB;

    hipMemsetAsync(ghist, 0, (size_t)NB * (1 << HBITS) * 4, stream);
    hipMemsetAsync(degi, 0, MMAX * 4, stream);

    // ---- L0 CSR build straight from ei ----
    int M = NB * N0;
    {
        k_deg_count0<<<EG, TB, 0, stream>>>(ei, degi);
        int nb = (M + 1023) / 1024;
        k_scan1<<<nb, 256, 0, stream>>>(degi, rowptrA, bsum, M);
        k_scan2<<<1, 256, 0, stream>>>(bsum, nb);
        k_scan3<<<(M + 255) / 256, 256, 0, stream>>>(rowptrA, bsum, cursor, degi, dinv, M, nb);
        k_csr_fill0<<<EG, TB, 0, stream>>>(ei, cursor, colA);
    }

    const float* xin = x0;
    float* xbufs[2] = {xb0, xb1};

    for (int L = 0; L < 4; ++L) {
        int fo = Fo[L];
        int n = M / NB, kk = Kk[L];

        // ---- aggregate input features (linear, so agg before matmul) ----
        if (L == 0) {
            k_gather_x4<<<(M + TB - 1) / TB, TB, 0, stream>>>(xin, rowptrA, colA, dinv, ax, M);
        } else if (L == 1) {
            int rpb = 8;
            k_gather_x<32><<<(M + rpb - 1) / rpb, 256, 0, stream>>>(xin, rowptrA, colA, dinv, ax, M);
        } else if (L == 2) {
            int rpb = 4;
            k_gather_x<64><<<(M + rpb - 1) / rpb, 256, 0, stream>>>(xin, rowptrA, colA, dinv, ax, M);
        } else {
            int rpb = 4;
            k_gather_x<128><<<(M + rpb - 1) / rpb, 256, 0, stream>>>(xin, rowptrA, colA, dinv, ax, M);
        }

        // ---- fused matmul + bias + relu + score ----
        if (L == 0) {
            int nt = (M / 4) * 8;
            k_mm<4, 32><<<(nt + 255) / 256, 256, 0, stream>>>(ax, W[L], bs[L], pv[L], y, score, M);
        } else if (L == 1) {
            int nt = (M / 4) * 16;
            k_mm<32, 64><<<(nt + 255) / 256, 256, 0, stream>>>(ax, W[L], bs[L], pv[L], y, score, M);
        } else if (L == 2) {
            int nt = (M / 4) * 32;
            k_mm<64, 128><<<(nt + 255) / 256, 256, 0, stream>>>(ax, W[L], bs[L], pv[L], y, score, M);
        } else {
            int nt = (M / 4) * 32;
            k_mm<128, 128><<<(nt + 255) / 256, 256, 0, stream>>>(ax, W[L], bs[L], pv[L], y, score, M);
        }

        // ---- top-k pooling ----
        dim3 gh((n + 4095) / 4096, NB);
        k_hist12<<<gh, 256, 0, stream>>>(score, ghist, n);
        k_topk_fine<<<NB, 1024, 0, stream>>>(score, ghist, T64, cnt, n, kk);
        dim3 gsel((n + 255) / 256, NB);
        k_select_idx<<<gsel, 256, 0, stream>>>(score, T64, cnt, remap, n, kk);
        float* xout = xbufs[L & 1];
        int ctot = M * (fo / 4);
        k_select_copy<<<(ctot + TB - 1) / TB, TB, 0, stream>>>(y, score, remap, xout,
                                                               M, fo / 4);

        // ---- CSR compaction for next layer (no flat edge list, no scatter) ----
        if (L < 3) {
            int Mnew = NB * kk;
            k_newdeg<<<(M + TB - 1) / TB, TB, 0, stream>>>(remap, rowptrA, colA, degi, M);
            int nb2 = (Mnew + 1023) / 1024;
            k_scan1<<<nb2, 256, 0, stream>>>(degi, rowptrB, bsum, Mnew);
            k_scan2<<<1, 256, 0, stream>>>(bsum, nb2);
            k_scan3<<<(Mnew + 255) / 256, 256, 0, stream>>>(rowptrB, bsum, cursor, degi,
                                                            dinv, Mnew, nb2);
            k_newcol<<<(M + TB - 1) / TB, TB, 0, stream>>>(remap, rowptrA, colA,
                                                           rowptrB, colB, M);
            int* tr = rowptrA; rowptrA = rowptrB; rowptrB = tr;
            int* tc = colA; colA = colB; colB = tc;
        }

        M = NB * kk;
        xin = xout;
    }

    int K3 = Kk[3];
    int chunk = (K3 + PCHUNKS - 1) / PCHUNKS;
    dim3 gpool(PCHUNKS, NB);
    k_pool_partial<<<gpool, 128, 0, stream>>>(xin, pmax, psum, K3, chunk);
    k_final2<<<NB, 128, 0, stream>>>(pmax, psum, metadata, convm_w, convm_b,
                                     fc_w, fc_b, fc2_w, fc2_b, (float*)d_out, K3);
}

// Round 11
// 570.753 us; speedup vs baseline: 3.0625x; 1.0925x over previous
//
#include <hip/hip_runtime.h>
#include <float.h>
#include <math.h>

#define NB 4            // graphs per batch
#define N0 40962        // nodes per graph at input
#define E0 983088       // total directed edges at layer 0
#define PCHUNKS 40      // stage-1 pooling blocks per graph
#define TK_CAP 6144     // candidate capacity for fine top-k select (48 KB LDS)
#define HBITS 12        // coarse histogram bits (4096 bins; LDS-privatized)
#define EB 128          // edge-chunk blocks for bucketed CSR build
#define BSHIFT 11       // 2048 dst nodes per bucket
#define BKNODES (1 << BSHIFT)
#define NBKT 81         // ceil(163848 / 2048)

// ---------------- helpers ----------------

static __device__ __forceinline__ unsigned key32_of(float s) {
    unsigned u = __float_as_uint(s);
    return (u & 0x80000000u) ? ~u : (u | 0x80000000u);
}

static __device__ __forceinline__ unsigned long long key64_of(float s, int li) {
    unsigned u = key32_of(s);
    unsigned low = ~(unsigned)li;   // ties broken by smaller local index
    return ((unsigned long long)u << 32) | (unsigned long long)low;
}

static __device__ __forceinline__ float4 fma4(float s, float4 w, float4 a) {
    a.x = fmaf(s, w.x, a.x); a.y = fmaf(s, w.y, a.y);
    a.z = fmaf(s, w.z, a.z); a.w = fmaf(s, w.w, a.w);
    return a;
}

// ---------------- L0 bucketed CSR build (no global atomics, locality-confined writes) --

// A: per-(bucket, block) edge counts via LDS histogram
__global__ void k_bucket_count(const int* __restrict__ ei, int* __restrict__ bcnt) {
    __shared__ unsigned int h[NBKT];
    for (int i = threadIdx.x; i < NBKT; i += 256) h[i] = 0u;
    __syncthreads();
    const int chunk = (E0 + EB - 1) / EB;
    int i0 = blockIdx.x * chunk;
    int i1 = min(E0, i0 + chunk);
    for (int i = i0 + threadIdx.x; i < i1; i += 256)
        atomicAdd(&h[ei[E0 + i] >> BSHIFT], 1u);
    __syncthreads();
    for (int b = threadIdx.x; b < NBKT; b += 256)
        bcnt[b * EB + blockIdx.x] = (int)h[b];
}

// B: scatter (src,dst) pairs into bucketed buffer via LDS cursors
__global__ void k_bucket_scatter(const int* __restrict__ ei, const int* __restrict__ boff,
                                 int2* __restrict__ ebuf) {
    __shared__ int cur[NBKT];
    for (int i = threadIdx.x; i < NBKT; i += 256) cur[i] = boff[i * EB + blockIdx.x];
    __syncthreads();
    const int chunk = (E0 + EB - 1) / EB;
    int i0 = blockIdx.x * chunk;
    int i1 = min(E0, i0 + chunk);
    for (int i = i0 + threadIdx.x; i < i1; i += 256) {
        int s = ei[i], d = ei[E0 + i];
        int pos = atomicAdd(&cur[d >> BSHIFT], 1);
        ebuf[pos] = make_int2(s, d);
    }
}

// C1: per bucket, per-node in-degrees via LDS histogram -> coalesced degi writes
__global__ void __launch_bounds__(1024) k_bucket_deg(const int2* __restrict__ ebuf,
                                                     const int* __restrict__ boff,
                                                     int* __restrict__ degi, int M) {
    __shared__ unsigned int h[BKNODES];
    int b = blockIdx.x;
    int base = b << BSHIFT;
    int range = min(BKNODES, M - base);
    for (int i = threadIdx.x; i < range; i += 1024) h[i] = 0u;
    __syncthreads();
    int e0 = boff[b * EB];
    int e1 = (b + 1 < NBKT) ? boff[(b + 1) * EB] : E0;
    for (int i = e0 + threadIdx.x; i < e1; i += 1024)
        atomicAdd(&h[ebuf[i].y - base], 1u);
    __syncthreads();
    for (int i = threadIdx.x; i < range; i += 1024) degi[base + i] = (int)h[i];
}

// C2: per bucket, place edges into CSR via LDS cursors (col writes confined per bucket)
__global__ void __launch_bounds__(1024) k_bucket_place(const int2* __restrict__ ebuf,
                                                       const int* __restrict__ boff,
                                                       const int* __restrict__ rowptr,
                                                       int* __restrict__ col, int M) {
    __shared__ int cur[BKNODES];
    int b = blockIdx.x;
    int base = b << BSHIFT;
    int range = min(BKNODES, M - base);
    for (int i = threadIdx.x; i < range; i += 1024) cur[i] = rowptr[base + i];
    __syncthreads();
    int e0 = boff[b * EB];
    int e1 = (b + 1 < NBKT) ? boff[(b + 1) * EB] : E0;
    for (int i = e0 + threadIdx.x; i < e1; i += 1024) {
        int2 sd = ebuf[i];
        int pos = atomicAdd(&cur[sd.y - base], 1);
        col[pos] = sd.x;
    }
}

// ---------------- scans ----------------

// exclusive scan, stage 1: 1024 elements per block (256 threads x 4)
__global__ void k_scan1(const int* __restrict__ in, int* __restrict__ out,
                        int* __restrict__ bsum, int M) {
    __shared__ int s[256];
    int t = threadIdx.x;
    int base = blockIdx.x * 1024 + t * 4;
    int d0 = (base + 0 < M) ? in[base + 0] : 0;
    int d1 = (base + 1 < M) ? in[base + 1] : 0;
    int d2 = (base + 2 < M) ? in[base + 2] : 0;
    int d3 = (base + 3 < M) ? in[base + 3] : 0;
    int tsum = d0 + d1 + d2 + d3;
    s[t] = tsum;
    __syncthreads();
    for (int off = 1; off < 256; off <<= 1) {
        int v = (t >= off) ? s[t - off] : 0;
        __syncthreads();
        s[t] += v;
        __syncthreads();
    }
    int texcl = s[t] - tsum;
    if (base + 0 < M) out[base + 0] = texcl;
    if (base + 1 < M) out[base + 1] = texcl + d0;
    if (base + 2 < M) out[base + 2] = texcl + d0 + d1;
    if (base + 3 < M) out[base + 3] = texcl + d0 + d1 + d2;
    if (t == 255) bsum[blockIdx.x] = s[255];
}

// stage 2: single block exclusive scan of block sums (nb <= 256); bsum[nb] = total
__global__ void k_scan2(int* __restrict__ bsum, int nb) {
    __shared__ int s[256];
    int t = threadIdx.x;
    int v = (t < nb) ? bsum[t] : 0;
    s[t] = v;
    __syncthreads();
    for (int off = 1; off < 256; off <<= 1) {
        int u = (t >= off) ? s[t - off] : 0;
        __syncthreads();
        s[t] += u;
        __syncthreads();
    }
    if (t < nb) bsum[t] = s[t] - v;
    if (t == 255) bsum[nb] = s[255];
}

// generic: add block offsets only
__global__ void k_scan_add(int* __restrict__ arr, const int* __restrict__ bsum, int n) {
    int i = blockIdx.x * 256 + threadIdx.x;
    if (i < n) arr[i] += bsum[i >> 10];
}

// node variant: add block offsets; write rowptr[M]; dinv = rsqrt(deg+1)
__global__ void k_scan3(int* __restrict__ rowptr, const int* __restrict__ bsum,
                        const int* __restrict__ degi, float* __restrict__ dinv,
                        int M, int nb) {
    int i = blockIdx.x * 256 + threadIdx.x;
    if (i < M) {
        rowptr[i] += bsum[i >> 10];
        dinv[i] = rsqrtf((float)degi[i] + 1.0f);
    }
    if (i == 0) rowptr[M] = bsum[nb];
}

// ---------------- CSR compaction (layers 1..3) ----------------

// pass 1: new degree per kept node (every new id written exactly once)
__global__ void k_newdeg(const int* __restrict__ remap, const int* __restrict__ rpO,
                         const int* __restrict__ colO, int* __restrict__ degN, int Mold) {
    int m = blockIdx.x * blockDim.x + threadIdx.x;
    if (m >= Mold) return;
    int nd = remap[m];
    if (nd < 0) return;
    int c = 0;
    int j0 = rpO[m], j1 = rpO[m + 1];
    for (int j = j0; j < j1; ++j) c += (remap[colO[j]] >= 0) ? 1 : 0;
    degN[nd] = c;
}

// pass 2: write surviving neighbors (contiguous per row; no atomics)
__global__ void k_newcol(const int* __restrict__ remap, const int* __restrict__ rpO,
                         const int* __restrict__ colO, const int* __restrict__ rpN,
                         int* __restrict__ colN, int Mold) {
    int m = blockIdx.x * blockDim.x + threadIdx.x;
    if (m >= Mold) return;
    int nd = remap[m];
    if (nd < 0) return;
    int w = rpN[nd];
    int j0 = rpO[m], j1 = rpO[m + 1];
    for (int j = j0; j < j1; ++j) {
        int rs = remap[colO[j]];
        if (rs >= 0) colN[w++] = rs;
    }
}

// ---------------- GCN compute ----------------

// aggregate input features (FI=4): one row per thread, float4 loads.
__global__ void k_gather_x4(const float* __restrict__ x, const int* __restrict__ rowptr,
                            const int* __restrict__ col, const float* __restrict__ dinv,
                            float* __restrict__ ax, int M) {
    int row = blockIdx.x * blockDim.x + threadIdx.x;
    if (row >= M) return;
    int rp0 = rowptr[row], rp1 = rowptr[row + 1];
    float dd = dinv[row];
    float invdeg = dd * dd;
    float4 xs = ((const float4*)x)[row];
    float4 acc;
    acc.x = xs.x * invdeg; acc.y = xs.y * invdeg;
    acc.z = xs.z * invdeg; acc.w = xs.w * invdeg;
    for (int j = rp0; j < rp1; ++j) {
        int s = col[j];
        float nrm = dd * dinv[s];
        float4 v = ((const float4*)x)[s];
        acc.x = fmaf(v.x, nrm, acc.x);
        acc.y = fmaf(v.y, nrm, acc.y);
        acc.z = fmaf(v.z, nrm, acc.z);
        acc.w = fmaf(v.w, nrm, acc.w);
    }
    ((float4*)ax)[row] = acc;
}

// aggregate input features (FI = 32/64/128): sub-wave per row, coalesced feature reads
template <int FI>
__global__ void k_gather_x(const float* __restrict__ x, const int* __restrict__ rowptr,
                           const int* __restrict__ col, const float* __restrict__ dinv,
                           float* __restrict__ ax, int M) {
    constexpr int LPR = (FI < 64) ? FI : 64;   // lanes per row
    constexpr int VPL = FI / LPR;              // floats per lane (1 or 2)
    constexpr int RPW = 64 / LPR;              // rows per wave
    int wave = (blockIdx.x * blockDim.x + threadIdx.x) >> 6;
    int lane = threadIdx.x & 63;
    int sub = lane / LPR;
    int f = lane % LPR;
    int row = wave * RPW + sub;
    if (row >= M) return;
    int rp0 = rowptr[row], rp1 = rowptr[row + 1];
    float dd = dinv[row];
    float invdeg = dd * dd;
    float acc[VPL];
#pragma unroll
    for (int v = 0; v < VPL; ++v)
        acc[v] = x[(size_t)row * FI + f * VPL + v] * invdeg;
    for (int j = rp0; j < rp1; ++j) {
        int s = col[j];
        float nrm = dd * dinv[s];
#pragma unroll
        for (int v = 0; v < VPL; ++v)
            acc[v] = fmaf(x[(size_t)s * FI + f * VPL + v], nrm, acc[v]);
    }
#pragma unroll
    for (int v = 0; v < VPL; ++v)
        ax[(size_t)row * FI + f * VPL + v] = acc[v];
}

// fused dense layer: y = relu(ax @ W + bias); score = dot(y, p)/|p|.
// 4 rows x 4 cols per thread; no global atomics (R8); c-loop kept rolled (R5 spill).
template <int FI, int FO>
__global__ void __launch_bounds__(256) k_mm(const float* __restrict__ ax,
                                            const float* __restrict__ W,
                                            const float* __restrict__ bias,
                                            const float* __restrict__ pvec,
                                            float* __restrict__ y,
                                            float* __restrict__ score, int M) {
    constexpr int Q = FO / 4;   // 8 / 16 / 32 lanes per row-quad
    int t = blockIdx.x * blockDim.x + threadIdx.x;
    int g = t / Q;
    int q = t % Q;
    int row = g * 4;
    if (row >= M) return;   // M divisible by 4 at every layer
    const float4* x0 = (const float4*)(ax + (size_t)(row + 0) * FI);
    const float4* x1 = (const float4*)(ax + (size_t)(row + 1) * FI);
    const float4* x2 = (const float4*)(ax + (size_t)(row + 2) * FI);
    const float4* x3 = (const float4*)(ax + (size_t)(row + 3) * FI);
    const float4* W4 = (const float4*)W;
    float4 a0 = {0.f, 0.f, 0.f, 0.f}, a1 = {0.f, 0.f, 0.f, 0.f};
    float4 a2 = {0.f, 0.f, 0.f, 0.f}, a3 = {0.f, 0.f, 0.f, 0.f};
#pragma unroll 2
    for (int c = 0; c < FI / 4; ++c) {
        float4 v0 = x0[c], v1 = x1[c], v2 = x2[c], v3 = x3[c];
        const float4* wr = W4 + (size_t)(c * 4) * Q + q;
        float4 w;
        w = wr[0 * Q];
        a0 = fma4(v0.x, w, a0); a1 = fma4(v1.x, w, a1);
        a2 = fma4(v2.x, w, a2); a3 = fma4(v3.x, w, a3);
        w = wr[1 * Q];
        a0 = fma4(v0.y, w, a0); a1 = fma4(v1.y, w, a1);
        a2 = fma4(v2.y, w, a2); a3 = fma4(v3.y, w, a3);
        w = wr[2 * Q];
        a0 = fma4(v0.z, w, a0); a1 = fma4(v1.z, w, a1);
        a2 = fma4(v2.z, w, a2); a3 = fma4(v3.z, w, a3);
        w = wr[3 * Q];
        a0 = fma4(v0.w, w, a0); a1 = fma4(v1.w, w, a1);
        a2 = fma4(v2.w, w, a2); a3 = fma4(v3.w, w, a3);
    }
    float4 b4 = ((const float4*)bias)[q];
    float4 o0, o1, o2, o3;
    o0.x = fmaxf(a0.x + b4.x, 0.f); o0.y = fmaxf(a0.y + b4.y, 0.f);
    o0.z = fmaxf(a0.z + b4.z, 0.f); o0.w = fmaxf(a0.w + b4.w, 0.f);
    o1.x = fmaxf(a1.x + b4.x, 0.f); o1.y = fmaxf(a1.y + b4.y, 0.f);
    o1.z = fmaxf(a1.z + b4.z, 0.f); o1.w = fmaxf(a1.w + b4.w, 0.f);
    o2.x = fmaxf(a2.x + b4.x, 0.f); o2.y = fmaxf(a2.y + b4.y, 0.f);
    o2.z = fmaxf(a2.z + b4.z, 0.f); o2.w = fmaxf(a2.w + b4.w, 0.f);
    o3.x = fmaxf(a3.x + b4.x, 0.f); o3.y = fmaxf(a3.y + b4.y, 0.f);
    o3.z = fmaxf(a3.z + b4.z, 0.f); o3.w = fmaxf(a3.w + b4.w, 0.f);
    ((float4*)(y + (size_t)(row + 0) * FO))[q] = o0;
    ((float4*)(y + (size_t)(row + 1) * FO))[q] = o1;
    ((float4*)(y + (size_t)(row + 2) * FO))[q] = o2;
    ((float4*)(y + (size_t)(row + 3) * FO))[q] = o3;
    float4 p4 = ((const float4*)pvec)[q];
    float d0 = o0.x * p4.x + o0.y * p4.y + o0.z * p4.z + o0.w * p4.w;
    float d1 = o1.x * p4.x + o1.y * p4.y + o1.z * p4.z + o1.w * p4.w;
    float d2 = o2.x * p4.x + o2.y * p4.y + o2.z * p4.z + o2.w * p4.w;
    float d3 = o3.x * p4.x + o3.y * p4.y + o3.z * p4.z + o3.w * p4.w;
    float pn = p4.x * p4.x + p4.y * p4.y + p4.z * p4.z + p4.w * p4.w;
#pragma unroll
    for (int off = Q / 2; off > 0; off >>= 1) {
        d0 += __shfl_xor(d0, off, 64);
        d1 += __shfl_xor(d1, off, 64);
        d2 += __shfl_xor(d2, off, 64);
        d3 += __shfl_xor(d3, off, 64);
        pn += __shfl_xor(pn, off, 64);
    }
    if (q == 0) {
        float inv = rsqrtf(pn);
        score[row + 0] = d0 * inv;
        score[row + 1] = d1 * inv;
        score[row + 2] = d2 * inv;
        score[row + 3] = d3 * inv;
    }
}

// ---------------- top-k ----------------

// LDS-privatized 12-bit coarse histogram of score keys. grid (ceil(n/4096), NB), 256 thr.
__global__ void k_hist12(const float* __restrict__ score, unsigned int* __restrict__ ghist,
                         int n) {
    __shared__ unsigned int h[1 << HBITS];
    for (int i = threadIdx.x; i < (1 << HBITS); i += 256) h[i] = 0u;
    __syncthreads();
    int b = blockIdx.y;
    const float* sc = score + (size_t)b * n;
    int i0 = blockIdx.x * 4096;
    int i1 = min(n, i0 + 4096);
    for (int i = i0 + threadIdx.x; i < i1; i += 256)
        atomicAdd(&h[key32_of(sc[i]) >> (32 - HBITS)], 1u);
    __syncthreads();
    unsigned int* gh = ghist + ((size_t)b << HBITS);
    for (int i = threadIdx.x; i < (1 << HBITS); i += 256) {
        unsigned v = h[i];
        if (v) atomicAdd(&gh[i], v);
    }
}

// one block (1024 threads) per graph: exact k-th largest key64 from the coarse histogram
// + one filtered candidate pass + in-LDS radix over the remaining 52 bits.
__global__ void __launch_bounds__(1024) k_topk_fine(
        const float* __restrict__ score, unsigned int* __restrict__ ghist,
        unsigned long long* __restrict__ T64, int* __restrict__ cnt, int n, int k) {
    int b = blockIdx.x;
    int t = threadIdx.x;
    const float* sc = score + (size_t)b * n;
    unsigned int* gh = ghist + ((size_t)b << HBITS);
    __shared__ int chunkSum[1024];
    __shared__ int chunkScan[1024];
    __shared__ unsigned long long cand[TK_CAP];
    __shared__ unsigned int hist[256];
    __shared__ int s_P12, s_r, s_c, s_rr, s_done, s_cc;
    __shared__ unsigned long long s_prefix;

    {
        int base = t << 2;
        int sum = (int)gh[base] + (int)gh[base + 1] + (int)gh[base + 2] + (int)gh[base + 3];
        chunkSum[t] = sum;
        chunkScan[t] = sum;
    }
    __syncthreads();
    for (int off = 1; off < 1024; off <<= 1) {
        int v = (t + off < 1024) ? chunkScan[t + off] : 0;
        __syncthreads();
        chunkScan[t] += v;
        __syncthreads();
    }
    {
        int cumAbove = chunkScan[t] - chunkSum[t];
        if (cumAbove < k && chunkScan[t] >= k) {
            int cum = cumAbove;
            int base = t << 2;
            for (int j = 3; j >= 0; --j) {
                int cb = (int)gh[base + j];
                cum += cb;
                if (cum >= k) {
                    s_P12 = base + j;
                    s_r = k - (cum - cb);
                    s_c = cb;
                    break;
                }
            }
        }
    }
    if (t == 0) s_cc = 0;
    __syncthreads();
    int P12 = s_P12, r = s_r, c = s_c;

    if (c <= TK_CAP) {
        for (int i = t; i < n; i += 1024) {
            unsigned u = key32_of(sc[i]);
            if ((int)(u >> (32 - HBITS)) == P12) {
                int pos = atomicAdd(&s_cc, 1);
                cand[pos] = ((unsigned long long)u << 32) |
                            (unsigned long long)(~(unsigned)i);
            }
        }
    }
    if (t == 0) {
        s_prefix = ((unsigned long long)(unsigned)P12) << (64 - HBITS);
        s_rr = r;
        s_done = 0;
    }
    __syncthreads();

    const int shifts[7] = {44, 36, 28, 20, 12, 4, 0};
    const int widths[7] = {8, 8, 8, 8, 8, 8, 4};
    for (int pi = 0; pi < 7; ++pi) {
        if (s_done) break;
        int shift = shifts[pi], wd = widths[pi];
        int nbins = 1 << wd;
        unsigned mask = (unsigned)nbins - 1u;
        for (int i = t; i < nbins; i += 1024) hist[i] = 0u;
        __syncthreads();
        unsigned long long prefix = s_prefix;
        int hs = shift + wd;
        if (c <= TK_CAP) {
            int cc = s_cc;
            for (int i = t; i < cc; i += 1024) {
                unsigned long long key = cand[i];
                if ((key >> hs) == (prefix >> hs))
                    atomicAdd(&hist[(unsigned)(key >> shift) & mask], 1u);
            }
        } else {
            for (int i = t; i < n; i += 1024) {
                unsigned long long key = key64_of(sc[i], i);
                if ((key >> hs) == (prefix >> hs))
                    atomicAdd(&hist[(unsigned)(key >> shift) & mask], 1u);
            }
        }
        __syncthreads();
        if (t == 0) {
            int rr = s_rr;
            unsigned long long pfx = s_prefix;
            for (int d = nbins - 1; d >= 0; --d) {
                int cb = (int)hist[d];
                if (rr <= cb) {
                    pfx |= ((unsigned long long)d) << shift;
                    if (rr == cb) s_done = 1;
                    break;
                }
                rr -= cb;
            }
            s_prefix = pfx;
            s_rr = rr;
        }
        __syncthreads();
    }
    __syncthreads();
    if (t == 0) { T64[b] = s_prefix; cnt[b] = 0; }
    for (int i = t; i < (1 << HBITS); i += 1024) gh[i] = 0u;
}

// phase A: keep flag -> new index via wave-aggregated block atomic; score := tanh(score) for kept
__global__ void k_select_idx(float* __restrict__ score,
                             const unsigned long long* __restrict__ T64, int* __restrict__ cnt,
                             int* __restrict__ remap, int n, int k) {
    int b = blockIdx.y;
    int i = blockIdx.x * 256 + threadIdx.x;
    int m = b * n + i;
    bool keep = false;
    float s = 0.f;
    if (i < n) {
        s = score[m];
        keep = key64_of(s, i) >= T64[b];
    }
    unsigned long long mask = __ballot(keep);
    int lane = threadIdx.x & 63;
    int wv = threadIdx.x >> 6;
    int lp = __popcll(mask & ((1ULL << lane) - 1ULL));
    __shared__ int woff[4];
    __shared__ int blockBase;
    if (lane == 0) woff[wv] = __popcll(mask);
    __syncthreads();
    if (threadIdx.x == 0) {
        int t0 = woff[0], t1 = woff[1], t2 = woff[2], t3 = woff[3];
        woff[0] = 0; woff[1] = t0; woff[2] = t0 + t1; woff[3] = t0 + t1 + t2;
        blockBase = atomicAdd(&cnt[b], t0 + t1 + t2 + t3);
    }
    __syncthreads();
    if (i < n) {
        if (keep) {
            remap[m] = b * k + blockBase + woff[wv] + lp;
            score[m] = tanhf(s);
        } else {
            remap[m] = -1;
        }
    }
}

// phase B: coalesced float4 row copy, xout[remap[m]] = y[m] * score[m] (score holds tanh)
__global__ void k_select_copy(const float* __restrict__ y, const float* __restrict__ score,
                              const int* __restrict__ remap, float* __restrict__ xout,
                              int M, int Fo4) {
    int t = blockIdx.x * blockDim.x + threadIdx.x;
    if (t >= M * Fo4) return;
    int m = t / Fo4, c = t - m * Fo4;
    int ni = remap[m];
    if (ni < 0) return;
    float4 v = ((const float4*)y)[(size_t)m * Fo4 + c];
    float s = score[m];
    float4 o; o.x = v.x * s; o.y = v.y * s; o.z = v.z * s; o.w = v.w * s;
    ((float4*)xout)[(size_t)ni * Fo4 + c] = o;
}

// stage 1 of final pooling: grid (PCHUNKS, NB), block 128.
__global__ void k_pool_partial(const float* __restrict__ x, float* __restrict__ pmax,
                               float* __restrict__ psum, int K3, int chunk) {
    int b = blockIdx.y, c = blockIdx.x, f = threadIdx.x;
    int i0 = c * chunk;
    int i1 = min(K3, i0 + chunk);
    const float* xb = x + (size_t)b * K3 * 128;
    float mx = -FLT_MAX, sm = 0.f;
    for (int i = i0; i < i1; ++i) {
        float v = xb[(size_t)i * 128 + f];
        mx = fmaxf(mx, v);
        sm += v;
    }
    int o = (b * PCHUNKS + c) * 128 + f;
    pmax[o] = mx;
    psum[o] = sm;
}

// stage 2: one block (128 threads) per graph: combine partials + metadata conv + fc + fc2
__global__ void k_final2(const float* __restrict__ pmax, const float* __restrict__ psum,
                         const float* __restrict__ metadata,
                         const float* __restrict__ convm_w, const float* __restrict__ convm_b,
                         const float* __restrict__ fc_w, const float* __restrict__ fc_b,
                         const float* __restrict__ fc2_w, const float* __restrict__ fc2_b,
                         float* __restrict__ out, int K3) {
    int b = blockIdx.x;
    int f = threadIdx.x;   // 0..127
    __shared__ float xc[260];
    __shared__ float red[128];
    float mx = -FLT_MAX, sm = 0.f;
    for (int c = 0; c < PCHUNKS; ++c) {
        int o = (b * PCHUNKS + c) * 128 + f;
        mx = fmaxf(mx, pmax[o]);
        sm += psum[o];
    }
    xc[f] = mx;
    xc[128 + f] = sm / (float)K3;
    if (f < 4) {
        float mv = metadata[b] * convm_w[f] + convm_b[f];
        xc[256 + f] = mv > 0.f ? mv : 0.f;
    }
    __syncthreads();
    float acc = fc_b[f];
    for (int i = 0; i < 260; ++i) acc = fmaf(xc[i], fc_w[i * 128 + f], acc);
    acc = acc > 0.f ? acc : 0.f;
    red[f] = acc * fc2_w[f];
    __syncthreads();
    for (int s2 = 64; s2 > 0; s2 >>= 1) {
        if (f < s2) red[f] += red[f + s2];
        __syncthreads();
    }
    if (f == 0) out[b] = red[0] + fc2_b[0];
}

// ---------------- launch ----------------

extern "C" void kernel_launch(void* const* d_in, const int* in_sizes, int n_in,
                              void* d_out, int out_size, void* d_ws, size_t ws_size,
                              hipStream_t stream) {
    const float* x0       = (const float*)d_in[0];
    const int*   ei       = (const int*)d_in[1];
    const float* metadata = (const float*)d_in[2];
    const float* W[4]  = {(const float*)d_in[3], (const float*)d_in[6],
                          (const float*)d_in[9], (const float*)d_in[12]};
    const float* bs[4] = {(const float*)d_in[4], (const float*)d_in[7],
                          (const float*)d_in[10], (const float*)d_in[13]};
    const float* pv[4] = {(const float*)d_in[5], (const float*)d_in[8],
                          (const float*)d_in[11], (const float*)d_in[14]};
    const float* convm_w = (const float*)d_in[15];
    const float* convm_b = (const float*)d_in[16];
    const float* fc_w    = (const float*)d_in[17];
    const float* fc_b    = (const float*)d_in[18];
    const float* fc2_w   = (const float*)d_in[19];
    const float* fc2_b   = (const float*)d_in[20];

    // workspace bump allocation
    const size_t HMAX = 5243392;
    const size_t XMAX = 2621952;
    const size_t MMAX = NB * (size_t)N0;   // 163848
    const int    NSCAN = NBKT * EB;        // 10368

    char* p = (char*)d_ws;
    size_t off = 0;
    auto alloc = [&](size_t bytes) -> char* {
        char* r = p + off;
        off = (off + bytes + 255) & ~(size_t)255;
        return r;
    };
    float* ax     = (float*)alloc(HMAX * 4);
    float* y      = (float*)alloc(HMAX * 4);
    float* xb0    = (float*)alloc(XMAX * 4);
    float* xb1    = (float*)alloc(XMAX * 4);
    float* dinv   = (float*)alloc(MMAX * 4);
    float* score  = (float*)alloc(MMAX * 4);
    int*   remap  = (int*)alloc(MMAX * 4);
    int*   degi   = (int*)alloc(MMAX * 4);
    int*   rowptrA= (int*)alloc((MMAX + 1) * 4);
    int*   rowptrB= (int*)alloc((MMAX + 1) * 4);
    int*   colA   = (int*)alloc(E0 * 4);
    int*   colB   = (int*)alloc(E0 * 4);
    int2*  ebuf   = (int2*)alloc((size_t)E0 * 8);
    int*   bcnt   = (int*)alloc(NSCAN * 4);
    int*   boff   = (int*)alloc(NSCAN * 4);
    int*   bsum   = (int*)alloc(260 * 4);
    float* pmax   = (float*)alloc(NB * PCHUNKS * 128 * 4);
    float* psum   = (float*)alloc(NB * PCHUNKS * 128 * 4);
    unsigned int* ghist = (unsigned int*)alloc((size_t)NB * (1 << HBITS) * 4);
    unsigned long long* T64 = (unsigned long long*)alloc(NB * 8);
    int*   cnt    = (int*)alloc(NB * 4);
    (void)ws_size; (void)n_in; (void)in_sizes; (void)out_size;

    const int Fo[4] = {32, 64, 128, 128};
    const int Kk[4] = {20481, 10241, 5121, 2561};

    const int TB = 256;

    hipMemsetAsync(ghist, 0, (size_t)NB * (1 << HBITS) * 4, stream);

    // ---- L0 CSR build: bucketed, no global atomics, locality-confined writes ----
    int M = NB * N0;
    {
        k_bucket_count<<<EB, 256, 0, stream>>>(ei, bcnt);
        int nb0 = (NSCAN + 1023) / 1024;   // 11
        k_scan1<<<nb0, 256, 0, stream>>>(bcnt, boff, bsum, NSCAN);
        k_scan2<<<1, 256, 0, stream>>>(bsum, nb0);
        k_scan_add<<<(NSCAN + 255) / 256, 256, 0, stream>>>(boff, bsum, NSCAN);
        k_bucket_scatter<<<EB, 256, 0, stream>>>(ei, boff, ebuf);
        k_bucket_deg<<<NBKT, 1024, 0, stream>>>(ebuf, boff, degi, M);
        int nb = (M + 1023) / 1024;
        k_scan1<<<nb, 256, 0, stream>>>(degi, rowptrA, bsum, M);
        k_scan2<<<1, 256, 0, stream>>>(bsum, nb);
        k_scan3<<<(M + 255) / 256, 256, 0, stream>>>(rowptrA, bsum, degi, dinv, M, nb);
        k_bucket_place<<<NBKT, 1024, 0, stream>>>(ebuf, boff, rowptrA, colA, M);
    }

    const float* xin = x0;
    float* xbufs[2] = {xb0, xb1};

    for (int L = 0; L < 4; ++L) {
        int fo = Fo[L];
        int n = M / NB, kk = Kk[L];

        // ---- aggregate input features (linear, so agg before matmul) ----
        if (L == 0) {
            k_gather_x4<<<(M + TB - 1) / TB, TB, 0, stream>>>(xin, rowptrA, colA, dinv, ax, M);
        } else if (L == 1) {
            int rpb = 8;
            k_gather_x<32><<<(M + rpb - 1) / rpb, 256, 0, stream>>>(xin, rowptrA, colA, dinv, ax, M);
        } else if (L == 2) {
            int rpb = 4;
            k_gather_x<64><<<(M + rpb - 1) / rpb, 256, 0, stream>>>(xin, rowptrA, colA, dinv, ax, M);
        } else {
            int rpb = 4;
            k_gather_x<128><<<(M + rpb - 1) / rpb, 256, 0, stream>>>(xin, rowptrA, colA, dinv, ax, M);
        }

        // ---- fused matmul + bias + relu + score ----
        if (L == 0) {
            int nt = (M / 4) * 8;
            k_mm<4, 32><<<(nt + 255) / 256, 256, 0, stream>>>(ax, W[L], bs[L], pv[L], y, score, M);
        } else if (L == 1) {
            int nt = (M / 4) * 16;
            k_mm<32, 64><<<(nt + 255) / 256, 256, 0, stream>>>(ax, W[L], bs[L], pv[L], y, score, M);
        } else if (L == 2) {
            int nt = (M / 4) * 32;
            k_mm<64, 128><<<(nt + 255) / 256, 256, 0, stream>>>(ax, W[L], bs[L], pv[L], y, score, M);
        } else {
            int nt = (M / 4) * 32;
            k_mm<128, 128><<<(nt + 255) / 256, 256, 0, stream>>>(ax, W[L], bs[L], pv[L], y, score, M);
        }

        // ---- top-k pooling ----
        dim3 gh((n + 4095) / 4096, NB);
        k_hist12<<<gh, 256, 0, stream>>>(score, ghist, n);
        k_topk_fine<<<NB, 1024, 0, stream>>>(score, ghist, T64, cnt, n, kk);
        dim3 gsel((n + 255) / 256, NB);
        k_select_idx<<<gsel, 256, 0, stream>>>(score, T64, cnt, remap, n, kk);
        float* xout = xbufs[L & 1];
        int ctot = M * (fo / 4);
        k_select_copy<<<(ctot + TB - 1) / TB, TB, 0, stream>>>(y, score, remap, xout,
                                                               M, fo / 4);

        // ---- CSR compaction for next layer (no flat edge list, no scatter) ----
        if (L < 3) {
            int Mnew = NB * kk;
            k_newdeg<<<(M + TB - 1) / TB, TB, 0, stream>>>(remap, rowptrA, colA, degi, M);
            int nb2 = (Mnew + 1023) / 1024;
            k_scan1<<<nb2, 256, 0, stream>>>(degi, rowptrB, bsum, Mnew);
            k_scan2<<<1, 256, 0, stream>>>(bsum, nb2);
            k_scan3<<<(Mnew + 255) / 256, 256, 0, stream>>>(rowptrB, bsum, degi,
                                                            dinv, Mnew, nb2);
            k_newcol<<<(M + TB - 1) / TB, TB, 0, stream>>>(remap, rowptrA, colA,
                                                           rowptrB, colB, M);
            int* tr = rowptrA; rowptrA = rowptrB; rowptrB = tr;
            int* tc = colA; colA = colB; colB = tc;
        }

        M = NB * kk;
        xin = xout;
    }

    int K3 = Kk[3];
    int chunk = (K3 + PCHUNKS - 1) / PCHUNKS;
    dim3 gpool(PCHUNKS, NB);
    k_pool_partial<<<gpool, 128, 0, stream>>>(xin, pmax, psum, K3, chunk);
    k_final2<<<NB, 128, 0, stream>>>(pmax, psum, metadata, convm_w, convm_b,
                                     fc_w, fc_b, fc2_w, fc2_b, (float*)d_out, K3);
}